// Round 1
// baseline (141.313 us; speedup 1.0000x reference)
//
#include <hip/hip_runtime.h>
#include <stdint.h>

#define VPn 8
#define BBn 2
#define CCn 512
#define NHn 8
#define HDn 64
#define Tn  2048
#define Mn  4096      // BBn*Tn
#define N1n 1536
#define Kn  512
#define L2E 1.4426950408889634f

typedef __attribute__((ext_vector_type(8))) short bf16x8;
typedef __attribute__((ext_vector_type(4))) float f32x4;
typedef unsigned short u16;
typedef unsigned int   u32;

__device__ __forceinline__ u16 f2bf(float f) {
  u32 u = __builtin_bit_cast(u32, f);
  u32 r = (u + 0x7fffu + ((u >> 16) & 1u)) >> 16;
  return (u16)r;
}
__device__ __forceinline__ float bf2f(u16 h) {
  u32 u = ((u32)h) << 16;
  return __builtin_bit_cast(float, u);
}
__device__ __forceinline__ void gload16(const void* g, void* l) {
  __builtin_amdgcn_global_load_lds(
      (const __attribute__((address_space(1))) u32*)g,
      (__attribute__((address_space(3))) u32*)l, 16, 0, 0);
}

// ---------- x (VP,B,C,H,W) f32 -> A_bf16 [4096][512], A[(b*2048+v*256+hw)][c] ----------
__global__ __launch_bounds__(256) void conv_x(const float* __restrict__ x, u16* __restrict__ A) {
  int bi = blockIdx.x;           // 16 vb * 8 ct * 4 ht = 512
  int vb = bi >> 5;
  int ct = (bi >> 2) & 7;
  int ht = bi & 3;
  int v = vb >> 1, b = vb & 1;
  __shared__ float t[64][65];
  int tid = threadIdx.x, col = tid & 63, r4 = tid >> 6;
  const float* src = x + ((size_t)vb * CCn + ct * 64) * 256 + ht * 64;
#pragma unroll
  for (int i = 0; i < 16; ++i) {
    int row = i * 4 + r4;                 // c within tile
    t[row][col] = src[row * 256 + col];   // col = hw within tile
  }
  __syncthreads();
  u16* dst = A + ((size_t)(b * Tn + v * 256 + ht * 64)) * Kn + ct * 64;
#pragma unroll
  for (int i = 0; i < 16; ++i) {
    int row = i * 4 + r4;                 // hw within tile
    dst[row * Kn + col] = f2bf(t[col][row]);
  }
}

// ---------- W [R][C] f32 -> Wt [C][R] bf16 ----------
__global__ __launch_bounds__(256) void convw(const float* __restrict__ Win, u16* __restrict__ Wt,
                                             int R, int Cc) {
  int tpr = Cc >> 6;
  int rt = blockIdx.x / tpr, ct = blockIdx.x % tpr;
  __shared__ float t[64][65];
  int tid = threadIdx.x, col = tid & 63, r4 = tid >> 6;
  const float* src = Win + (size_t)(rt * 64) * Cc + ct * 64;
#pragma unroll
  for (int i = 0; i < 16; ++i) {
    int row = i * 4 + r4;
    t[row][col] = src[row * Cc + col];
  }
  __syncthreads();
  u16* dst = Wt + (size_t)(ct * 64) * R + rt * 64;
#pragma unroll
  for (int i = 0; i < 16; ++i) {
    int row = i * 4 + r4;
    dst[row * R + col] = f2bf(t[col][row]);
  }
}

// ---------- GEMM1: A[4096][512] x WqkvT[1536][512] -> Q,K,V [b][h][t][d] bf16 (+bias) ----------
__global__ __launch_bounds__(256, 2) void gemm_qkv(
    const u16* __restrict__ A, const u16* __restrict__ Bt, const float* __restrict__ bias,
    u16* __restrict__ Qo, u16* __restrict__ Ko, u16* __restrict__ Vo) {
  const int nt = N1n / 128;  // 12
  int m0 = (blockIdx.x / nt) * 128;
  int n0 = (blockIdx.x % nt) * 128;
  __shared__ __align__(16) u16 As[128 * 64];
  __shared__ __align__(16) u16 Bs[128 * 64];
  int tid = threadIdx.x, lane = tid & 63, w = tid >> 6;
  int wr = w >> 1, wc = w & 1;
  int li = lane & 15, g = lane >> 4;
  int rsub = lane >> 3, slot = lane & 7;
  int srcslot = slot ^ rsub;  // pre-swizzled global source (LDS dest stays linear)
  f32x4 acc[4][4] = {};
  for (int k0 = 0; k0 < Kn; k0 += 64) {
    __syncthreads();
#pragma unroll
    for (int i = 0; i < 4; ++i) {
      int ci = w * 4 + i;
      int row = ci * 8 + rsub;
      gload16(A  + (size_t)(m0 + row) * Kn + k0 + srcslot * 8, (char*)As + ci * 1024);
      gload16(Bt + (size_t)(n0 + row) * Kn + k0 + srcslot * 8, (char*)Bs + ci * 1024);
    }
    __syncthreads();
#pragma unroll
    for (int kk = 0; kk < 2; ++kk) {
      bf16x8 af[4], bfr[4];
#pragma unroll
      for (int mi = 0; mi < 4; ++mi) {
        int row = wr * 64 + mi * 16 + li;
        int sw = ((kk * 4 + g) ^ (row & 7)) * 8;
        af[mi] = *(const bf16x8*)(As + row * 64 + sw);
      }
#pragma unroll
      for (int ni = 0; ni < 4; ++ni) {
        int row = wc * 64 + ni * 16 + li;
        int sw = ((kk * 4 + g) ^ (row & 7)) * 8;
        bfr[ni] = *(const bf16x8*)(Bs + row * 64 + sw);
      }
#pragma unroll
      for (int mi = 0; mi < 4; ++mi)
#pragma unroll
        for (int ni = 0; ni < 4; ++ni)
          acc[mi][ni] = __builtin_amdgcn_mfma_f32_16x16x32_bf16(af[mi], bfr[ni], acc[mi][ni], 0, 0, 0);
    }
  }
#pragma unroll
  for (int ni = 0; ni < 4; ++ni) {
    int n = n0 + wc * 64 + ni * 16 + li;
    float bn = bias[n];
    int sel = n >> 9, c = n & 511, hh = c >> 6, d = c & 63;
    u16* dst = (sel == 0) ? Qo : (sel == 1) ? Ko : Vo;
#pragma unroll
    for (int mi = 0; mi < 4; ++mi) {
#pragma unroll
      for (int r = 0; r < 4; ++r) {
        int m = m0 + wr * 64 + mi * 16 + g * 4 + r;
        int b = m >> 11, t = m & 2047;
        dst[((size_t)((b * NHn + hh) * Tn + t)) * HDn + d] = f2bf(acc[mi][ni][r] + bn);
      }
    }
  }
}

// ---------- V [bh][t][d] -> VT [bh][d][t] (bf16) ----------
__global__ __launch_bounds__(256) void vtrans(const u16* __restrict__ V, u16* __restrict__ VT) {
  int bi = blockIdx.x;           // 16 bh * 32 t-tiles
  int bh = bi >> 5, tt = bi & 31;
  __shared__ u32 t[64][65];
  int tid = threadIdx.x, col = tid & 63, r4 = tid >> 6;
  const u16* src = V + (size_t)bh * Tn * HDn + (size_t)(tt * 64) * HDn;
#pragma unroll
  for (int i = 0; i < 16; ++i) {
    int row = i * 4 + r4;              // t within tile
    t[row][col] = src[row * HDn + col];  // col = d
  }
  __syncthreads();
  u16* dst = VT + (size_t)bh * HDn * Tn + tt * 64;
#pragma unroll
  for (int i = 0; i < 16; ++i) {
    int row = i * 4 + r4;              // d
    dst[(size_t)row * Tn + col] = (u16)t[col][row];
  }
}

// ---------- flash attention, block-causal ----------
__global__ __launch_bounds__(256, 2) void attn(
    const u16* __restrict__ Q, const u16* __restrict__ K, const u16* __restrict__ VT,
    u16* __restrict__ Y) {
  int idx = blockIdx.x;            // 512 = 32 qtiles * 16 bh, heavy qtiles first
  int rq = idx >> 4, bh = idx & 15;
  int qtile = 31 - rq;
  int b = bh >> 3, h = bh & 7;
  int qrow0 = qtile << 6;
  int nkeys = ((qrow0 >> 8) + 1) << 8;
  int tid = threadIdx.x, lane = tid & 63, w = tid >> 6;
  int li = lane & 15, g = lane >> 4;
  int qbase = qrow0 + w * 16;
  const u16* Qb = Q + ((size_t)(bh * Tn + qbase)) * HDn;
  const u16* Kb = K + (size_t)bh * Tn * HDn;
  const u16* Vb = VT + (size_t)bh * HDn * Tn;

  bf16x8 qf0, qf1;
  {
    const u16* qp = Qb + li * HDn + g * 8;
    bf16x8 a = *(const bf16x8*)qp;
    bf16x8 c = *(const bf16x8*)(qp + 32);
#pragma unroll
    for (int j = 0; j < 8; ++j) {
      qf0[j] = (short)f2bf(bf2f((u16)a[j]) * 0.125f);  // fold softmax scale (exact)
      qf1[j] = (short)f2bf(bf2f((u16)c[j]) * 0.125f);
    }
  }

  float mrun[4], lrun[4];
  f32x4 oacc[4] = {};
#pragma unroll
  for (int r = 0; r < 4; ++r) { mrun[r] = -1e30f; lrun[r] = 0.f; }

  __shared__ __align__(16) u16 P[4][16][40];  // per-wave, padded (stride 80B)

  for (int k0 = 0; k0 < nkeys; k0 += 32) {
    f32x4 s0 = {0, 0, 0, 0}, s1 = {0, 0, 0, 0};
    const u16* kp0 = Kb + (size_t)(k0 + li) * HDn + g * 8;
    const u16* kp1 = kp0 + 16 * HDn;
    bf16x8 k00 = *(const bf16x8*)kp0;
    bf16x8 k01 = *(const bf16x8*)(kp0 + 32);
    bf16x8 k10 = *(const bf16x8*)kp1;
    bf16x8 k11 = *(const bf16x8*)(kp1 + 32);
    s0 = __builtin_amdgcn_mfma_f32_16x16x32_bf16(qf0, k00, s0, 0, 0, 0);
    s0 = __builtin_amdgcn_mfma_f32_16x16x32_bf16(qf1, k01, s0, 0, 0, 0);
    s1 = __builtin_amdgcn_mfma_f32_16x16x32_bf16(qf0, k10, s1, 0, 0, 0);
    s1 = __builtin_amdgcn_mfma_f32_16x16x32_bf16(qf1, k11, s1, 0, 0, 0);

    float tm[4], p0[4], p1[4], rs[4], fc[4];
#pragma unroll
    for (int r = 0; r < 4; ++r) tm[r] = fmaxf(s0[r], s1[r]);
#pragma unroll
    for (int off = 1; off <= 8; off <<= 1)
#pragma unroll
      for (int r = 0; r < 4; ++r) tm[r] = fmaxf(tm[r], __shfl_xor(tm[r], off));
#pragma unroll
    for (int r = 0; r < 4; ++r) {
      float mnew = fmaxf(mrun[r], tm[r]);
      fc[r] = exp2f((mrun[r] - mnew) * L2E);
      p0[r] = exp2f((s0[r] - mnew) * L2E);
      p1[r] = exp2f((s1[r] - mnew) * L2E);
      rs[r] = p0[r] + p1[r];
      mrun[r] = mnew;
    }
#pragma unroll
    for (int off = 1; off <= 8; off <<= 1)
#pragma unroll
      for (int r = 0; r < 4; ++r) rs[r] += __shfl_xor(rs[r], off);
#pragma unroll
    for (int r = 0; r < 4; ++r) lrun[r] = lrun[r] * fc[r] + rs[r];
#pragma unroll
    for (int dc = 0; dc < 4; ++dc)
#pragma unroll
      for (int r = 0; r < 4; ++r) oacc[dc][r] *= fc[r];

    // P (C-layout) -> LDS -> A-layout fragment
#pragma unroll
    for (int r = 0; r < 4; ++r) {
      P[w][g * 4 + r][li]      = f2bf(p0[r]);
      P[w][g * 4 + r][16 + li] = f2bf(p1[r]);
    }
    bf16x8 pf = *(const bf16x8*)&P[w][li][g * 8];
#pragma unroll
    for (int dc = 0; dc < 4; ++dc) {
      bf16x8 vf = *(const bf16x8*)(Vb + (size_t)(dc * 16 + li) * Tn + k0 + g * 8);
      oacc[dc] = __builtin_amdgcn_mfma_f32_16x16x32_bf16(pf, vf, oacc[dc], 0, 0, 0);
    }
  }

  u16* Yb = Y + ((size_t)(b * Tn + qbase)) * CCn + h * HDn;
#pragma unroll
  for (int dc = 0; dc < 4; ++dc)
#pragma unroll
    for (int r = 0; r < 4; ++r) {
      float o = oacc[dc][r] / lrun[r];
      Yb[(size_t)(g * 4 + r) * CCn + dc * 16 + li] = f2bf(o);
    }
}

// ---------- GEMM2: Y[4096][512] x WoT[512][512] -> Y2 f32 [4096][512] (+bias) ----------
__global__ __launch_bounds__(256, 2) void gemm_out(
    const u16* __restrict__ A, const u16* __restrict__ Bt, const float* __restrict__ bias,
    float* __restrict__ Y2) {
  const int nt = 4;
  int m0 = (blockIdx.x / nt) * 128;
  int n0 = (blockIdx.x % nt) * 128;
  __shared__ __align__(16) u16 As[128 * 64];
  __shared__ __align__(16) u16 Bs[128 * 64];
  int tid = threadIdx.x, lane = tid & 63, w = tid >> 6;
  int wr = w >> 1, wc = w & 1;
  int li = lane & 15, g = lane >> 4;
  int rsub = lane >> 3, slot = lane & 7;
  int srcslot = slot ^ rsub;
  f32x4 acc[4][4] = {};
  for (int k0 = 0; k0 < Kn; k0 += 64) {
    __syncthreads();
#pragma unroll
    for (int i = 0; i < 4; ++i) {
      int ci = w * 4 + i;
      int row = ci * 8 + rsub;
      gload16(A  + (size_t)(m0 + row) * Kn + k0 + srcslot * 8, (char*)As + ci * 1024);
      gload16(Bt + (size_t)(n0 + row) * Kn + k0 + srcslot * 8, (char*)Bs + ci * 1024);
    }
    __syncthreads();
#pragma unroll
    for (int kk = 0; kk < 2; ++kk) {
      bf16x8 af[4], bfr[4];
#pragma unroll
      for (int mi = 0; mi < 4; ++mi) {
        int row = wr * 64 + mi * 16 + li;
        int sw = ((kk * 4 + g) ^ (row & 7)) * 8;
        af[mi] = *(const bf16x8*)(As + row * 64 + sw);
      }
#pragma unroll
      for (int ni = 0; ni < 4; ++ni) {
        int row = wc * 64 + ni * 16 + li;
        int sw = ((kk * 4 + g) ^ (row & 7)) * 8;
        bfr[ni] = *(const bf16x8*)(Bs + row * 64 + sw);
      }
#pragma unroll
      for (int mi = 0; mi < 4; ++mi)
#pragma unroll
        for (int ni = 0; ni < 4; ++ni)
          acc[mi][ni] = __builtin_amdgcn_mfma_f32_16x16x32_bf16(af[mi], bfr[ni], acc[mi][ni], 0, 0, 0);
    }
  }
#pragma unroll
  for (int ni = 0; ni < 4; ++ni) {
    int n = n0 + wc * 64 + ni * 16 + li;
    float bn = bias[n];
#pragma unroll
    for (int mi = 0; mi < 4; ++mi) {
#pragma unroll
      for (int r = 0; r < 4; ++r) {
        int m = m0 + wr * 64 + mi * 16 + g * 4 + r;
        Y2[(size_t)m * CCn + n] = acc[mi][ni][r] + bn;
      }
    }
  }
}

// ---------- Y2 [4096][512] f32 -> out (v,b,c,h,w) f32 ----------
__global__ __launch_bounds__(256) void otrans(const float* __restrict__ Y2, float* __restrict__ out) {
  int bi = blockIdx.x;           // 16 vb * 4 ht * 8 ct = 512
  int vb = bi >> 5;
  int ht = (bi >> 3) & 3;
  int ct = bi & 7;
  int v = vb >> 1, b = vb & 1;
  __shared__ float t[64][65];
  int tid = threadIdx.x, col = tid & 63, r4 = tid >> 6;
  const float* src = Y2 + (size_t)(b * Tn + v * 256 + ht * 64) * CCn + ct * 64;
#pragma unroll
  for (int i = 0; i < 16; ++i) {
    int row = i * 4 + r4;                // hw within tile
    t[row][col] = src[(size_t)row * CCn + col];  // col = c
  }
  __syncthreads();
  float* dst = out + ((size_t)vb * CCn + ct * 64) * 256 + ht * 64;
#pragma unroll
  for (int i = 0; i < 16; ++i) {
    int row = i * 4 + r4;                // c within tile
    dst[(size_t)row * 256 + col] = t[col][row];
  }
}

extern "C" void kernel_launch(void* const* d_in, const int* in_sizes, int n_in,
                              void* d_out, int out_size, void* d_ws, size_t ws_size,
                              hipStream_t stream) {
  (void)in_sizes; (void)n_in; (void)out_size; (void)ws_size;
  const float* x    = (const float*)d_in[0];
  const float* Wqkv = (const float*)d_in[1];
  const float* bqkv = (const float*)d_in[2];
  const float* Wo   = (const float*)d_in[3];
  const float* bo   = (const float*)d_in[4];
  float* out = (float*)d_out;
  char* ws = (char*)d_ws;
  const size_t MB = 1ull << 20;
  u16*   Abf   = (u16*)(ws + 0);         // 4MB; reused as Y (bf16) after gemm_qkv
  u16*   WqkvT = (u16*)(ws + 4 * MB);    // 1.5MB
  u16*   WoT   = (u16*)(ws + 6 * MB);    // 0.5MB
  u16*   Qb    = (u16*)(ws + 7 * MB);    // 4MB
  u16*   Kb    = (u16*)(ws + 11 * MB);   // 4MB
  u16*   Vb    = (u16*)(ws + 15 * MB);   // 4MB
  u16*   VTb   = (u16*)(ws + 19 * MB);   // 4MB   -> peak 23MB
  float* Y2    = (float*)(ws + 7 * MB);  // 8MB, overlays Q/K (dead after attn)

  conv_x<<<512, 256, 0, stream>>>(x, Abf);
  convw<<<192, 256, 0, stream>>>(Wqkv, WqkvT, Kn, N1n);
  convw<<<64, 256, 0, stream>>>(Wo, WoT, Kn, CCn);
  gemm_qkv<<<32 * 12, 256, 0, stream>>>(Abf, WqkvT, bqkv, Qb, Kb, Vb);
  vtrans<<<512, 256, 0, stream>>>(Vb, VTb);
  attn<<<512, 256, 0, stream>>>(Qb, Kb, VTb, Abf);
  gemm_out<<<32 * 4, 256, 0, stream>>>(Abf, WoT, bo, Y2);
  otrans<<<512, 256, 0, stream>>>(Y2, out);
}

// Round 2
// 122.332 us; speedup vs baseline: 1.1552x; 1.1552x over previous
//
#include <hip/hip_runtime.h>
#include <stdint.h>

#define VPn 8
#define BBn 2
#define CCn 512
#define NHn 8
#define HDn 64
#define Tn  2048
#define Mn  4096      // BBn*Tn
#define N1n 1536
#define Kn  512
#define L2E 1.4426950408889634f

typedef __attribute__((ext_vector_type(8))) short bf16x8;
typedef __attribute__((ext_vector_type(4))) short s16x4;
typedef __attribute__((ext_vector_type(4))) float f32x4;
typedef unsigned short u16;
typedef unsigned int   u32;

__device__ __forceinline__ u16 f2bf(float f) {
  u32 u = __builtin_bit_cast(u32, f);
  u32 r = (u + 0x7fffu + ((u >> 16) & 1u)) >> 16;
  return (u16)r;
}
__device__ __forceinline__ void gload16(const void* g, void* l) {
  __builtin_amdgcn_global_load_lds(
      (const __attribute__((address_space(1))) u32*)g,
      (__attribute__((address_space(3))) u32*)l, 16, 0, 0);
}

// ---------- x (VP,B,C,H,W) f32 -> A_bf16 [4096][512], A[(b*2048+v*256+hw)][c] ----------
__global__ __launch_bounds__(256) void conv_x(const float* __restrict__ x, u16* __restrict__ A) {
  int bi = blockIdx.x;           // 16 vb * 8 ct * 4 ht = 512
  int vb = bi >> 5;
  int ct = (bi >> 2) & 7;
  int ht = bi & 3;
  int v = vb >> 1, b = vb & 1;
  __shared__ float t[64][65];
  int tid = threadIdx.x, col = tid & 63, r4 = tid >> 6;
  const float* src = x + ((size_t)vb * CCn + ct * 64) * 256 + ht * 64;
#pragma unroll
  for (int i = 0; i < 16; ++i) {
    int row = i * 4 + r4;                 // c within tile
    t[row][col] = src[row * 256 + col];   // col = hw within tile
  }
  __syncthreads();
  u16* dst = A + ((size_t)(b * Tn + v * 256 + ht * 64)) * Kn + ct * 64;
#pragma unroll
  for (int i = 0; i < 16; ++i) {
    int row = i * 4 + r4;                 // hw within tile
    dst[row * Kn + col] = f2bf(t[col][row]);
  }
}

// ---------- W [R][C] f32 -> Wt [C][R] bf16 ----------
__global__ __launch_bounds__(256) void convw(const float* __restrict__ Win, u16* __restrict__ Wt,
                                             int R, int Cc) {
  int tpr = Cc >> 6;
  int rt = blockIdx.x / tpr, ct = blockIdx.x % tpr;
  __shared__ float t[64][65];
  int tid = threadIdx.x, col = tid & 63, r4 = tid >> 6;
  const float* src = Win + (size_t)(rt * 64) * Cc + ct * 64;
#pragma unroll
  for (int i = 0; i < 16; ++i) {
    int row = i * 4 + r4;
    t[row][col] = src[row * Cc + col];
  }
  __syncthreads();
  u16* dst = Wt + (size_t)(ct * 64) * R + rt * 64;
#pragma unroll
  for (int i = 0; i < 16; ++i) {
    int row = i * 4 + r4;
    dst[row * R + col] = f2bf(t[col][row]);
  }
}

// ---------- GEMM1: A x WqkvT -> Q(scaled 1/8),K [bh][t][d], V -> VT [bh][d][t] ----------
__global__ __launch_bounds__(256, 2) void gemm_qkv(
    const u16* __restrict__ A, const u16* __restrict__ Bt, const float* __restrict__ bias,
    u16* __restrict__ Qo, u16* __restrict__ Ko, u16* __restrict__ VTo) {
  const int nt = N1n / 128;  // 12
  int m0 = (blockIdx.x / nt) * 128;
  int n0 = (blockIdx.x % nt) * 128;
  __shared__ __align__(16) u16 As[128 * 64];
  __shared__ __align__(16) u16 Bs[128 * 64];
  int tid = threadIdx.x, lane = tid & 63, w = tid >> 6;
  int wr = w >> 1, wc = w & 1;
  int li = lane & 15, g = lane >> 4;
  int rsub = lane >> 3, slot = lane & 7;
  int srcslot = slot ^ rsub;  // pre-swizzled global source (LDS dest stays linear)
  f32x4 acc[4][4] = {};
  for (int k0 = 0; k0 < Kn; k0 += 64) {
    __syncthreads();
#pragma unroll
    for (int i = 0; i < 4; ++i) {
      int ci = w * 4 + i;
      int row = ci * 8 + rsub;
      gload16(A  + (size_t)(m0 + row) * Kn + k0 + srcslot * 8, (char*)As + ci * 1024);
      gload16(Bt + (size_t)(n0 + row) * Kn + k0 + srcslot * 8, (char*)Bs + ci * 1024);
    }
    __syncthreads();
#pragma unroll
    for (int kk = 0; kk < 2; ++kk) {
      bf16x8 af[4], bfr[4];
#pragma unroll
      for (int mi = 0; mi < 4; ++mi) {
        int row = wr * 64 + mi * 16 + li;
        int sw = ((kk * 4 + g) ^ (row & 7)) * 8;
        af[mi] = *(const bf16x8*)(As + row * 64 + sw);
      }
#pragma unroll
      for (int ni = 0; ni < 4; ++ni) {
        int row = wc * 64 + ni * 16 + li;
        int sw = ((kk * 4 + g) ^ (row & 7)) * 8;
        bfr[ni] = *(const bf16x8*)(Bs + row * 64 + sw);
      }
#pragma unroll
      for (int mi = 0; mi < 4; ++mi)
#pragma unroll
        for (int ni = 0; ni < 4; ++ni)
          acc[mi][ni] = __builtin_amdgcn_mfma_f32_16x16x32_bf16(af[mi], bfr[ni], acc[mi][ni], 0, 0, 0);
    }
  }
#pragma unroll
  for (int ni = 0; ni < 4; ++ni) {
    int n = n0 + wc * 64 + ni * 16 + li;
    float bn = bias[n];
    int sel = n >> 9, c = n & 511, hh = c >> 6, d = c & 63;
    if (sel < 2) {
      u16* dst = sel ? Ko : Qo;
      float sc = sel ? 1.0f : 0.125f;  // fold softmax scale into Q (exact)
#pragma unroll
      for (int mi = 0; mi < 4; ++mi) {
#pragma unroll
        for (int r = 0; r < 4; ++r) {
          int m = m0 + wr * 64 + mi * 16 + g * 4 + r;
          int bq = m >> 11, t = m & 2047;
          dst[((size_t)((bq * NHn + hh) * Tn + t)) * HDn + d] = f2bf((acc[mi][ni][r] + bn) * sc);
        }
      }
    } else {  // V: store transposed [bh][d][t], t-contiguous packed
#pragma unroll
      for (int mi = 0; mi < 4; ++mi) {
        int mb = m0 + wr * 64 + mi * 16 + g * 4;
        int bq = mb >> 11, t = mb & 2047;
        s16x4 ov;
#pragma unroll
        for (int r = 0; r < 4; ++r) ov[r] = (short)f2bf(acc[mi][ni][r] + bn);
        *(s16x4*)(VTo + ((size_t)((bq * NHn + hh) * HDn + d)) * Tn + t) = ov;
      }
    }
  }
}

// ---------- flash attention, block-causal, swapped-operand lane-local softmax ----------
__global__ __launch_bounds__(64) void attn(
    const u16* __restrict__ Q, const u16* __restrict__ K, const u16* __restrict__ VT,
    u16* __restrict__ Y) {
  int idx = blockIdx.x;            // 2048 = 32 qtiles(heavy first) * 4 sub * 16 bh
  int qtile = 31 - (idx >> 6);
  int sub = (idx >> 4) & 3;
  int bh = idx & 15;
  int b = bh >> 3, h = bh & 7;
  int qrow0 = (qtile << 6) + (sub << 4);
  int nkeys = ((qtile >> 2) + 1) << 8;
  int lane = threadIdx.x & 63;
  int li = lane & 15, g = lane >> 4;
  const u16* Qb = Q + ((size_t)(bh * Tn + qrow0)) * HDn;
  const u16* Kb = K + (size_t)bh * Tn * HDn;
  const u16* Vb = VT + (size_t)bh * HDn * Tn;

  // Q as B-operand: lane (li,g) holds Q[q=li][d = 8g+j] (+32 for hi half)
  bf16x8 qf0 = *(const bf16x8*)(Qb + li * HDn + g * 8);
  bf16x8 qf1 = *(const bf16x8*)(Qb + li * HDn + 32 + g * 8);

  // K rows permuted: sigma0(x) = 8*(x>>2)+(x&3) so D rows land as keys 8g+r
  const u16* krA = Kb + (size_t)(((li >> 2) << 3) + (li & 3)) * HDn + g * 8;
  const u16* krB = krA + 4 * HDn;

  float mrun = -1e30f, lrun = 0.f;
  f32x4 oacc[4] = {};

  bf16x8 kc0 = *(const bf16x8*)(krA);
  bf16x8 kc1 = *(const bf16x8*)(krA + 32);
  bf16x8 kc2 = *(const bf16x8*)(krB);
  bf16x8 kc3 = *(const bf16x8*)(krB + 32);

  for (int k0 = 0; k0 < nkeys; k0 += 32) {
    // prefetch next K tile
    int kn = (k0 + 32 < nkeys) ? (k0 + 32) : k0;
    const u16* pa = krA + (size_t)kn * HDn;
    const u16* pb = krB + (size_t)kn * HDn;
    bf16x8 n0 = *(const bf16x8*)(pa);
    bf16x8 n1 = *(const bf16x8*)(pa + 32);
    bf16x8 n2 = *(const bf16x8*)(pb);
    bf16x8 n3 = *(const bf16x8*)(pb + 32);
    // V^T fragments for this tile (issued early; consumed after softmax)
    const u16* vp = Vb + (size_t)li * Tn + k0 + g * 8;
    bf16x8 vt0 = *(const bf16x8*)(vp);
    bf16x8 vt1 = *(const bf16x8*)(vp + 16 * Tn);
    bf16x8 vt2 = *(const bf16x8*)(vp + 32 * Tn);
    bf16x8 vt3 = *(const bf16x8*)(vp + 48 * Tn);

    // S^T = K.Q : lane holds S[q=li][k0+8g+j], j=0..7 via s0/s1
    f32x4 s0 = {0, 0, 0, 0}, s1 = {0, 0, 0, 0};
    s0 = __builtin_amdgcn_mfma_f32_16x16x32_bf16(kc0, qf0, s0, 0, 0, 0);
    s0 = __builtin_amdgcn_mfma_f32_16x16x32_bf16(kc1, qf1, s0, 0, 0, 0);
    s1 = __builtin_amdgcn_mfma_f32_16x16x32_bf16(kc2, qf0, s1, 0, 0, 0);
    s1 = __builtin_amdgcn_mfma_f32_16x16x32_bf16(kc3, qf1, s1, 0, 0, 0);

    // lane-local row softmax: in-lane 8-max + 2 shfl steps across the 4 g-copies
    float m8 = fmaxf(fmaxf(fmaxf(s0[0], s0[1]), fmaxf(s0[2], s0[3])),
                     fmaxf(fmaxf(s1[0], s1[1]), fmaxf(s1[2], s1[3])));
    m8 = fmaxf(m8, __shfl_xor(m8, 16));
    m8 = fmaxf(m8, __shfl_xor(m8, 32));
    float mnew = fmaxf(mrun, m8);
    float fc = exp2f((mrun - mnew) * L2E);
    float p[8];
#pragma unroll
    for (int j = 0; j < 8; ++j) {
      float sv = (j < 4) ? s0[j] : s1[j - 4];
      p[j] = exp2f((sv - mnew) * L2E);
    }
    float rs = ((p[0] + p[1]) + (p[2] + p[3])) + ((p[4] + p[5]) + (p[6] + p[7]));
    rs += __shfl_xor(rs, 16);
    rs += __shfl_xor(rs, 32);
    mrun = mnew;
    lrun = lrun * fc + rs;
    bf16x8 pf;
#pragma unroll
    for (int j = 0; j < 8; ++j) pf[j] = (short)f2bf(p[j]);
#pragma unroll
    for (int dc = 0; dc < 4; ++dc)
#pragma unroll
      for (int r = 0; r < 4; ++r) oacc[dc][r] *= fc;
    // O^T += V^T . P^T : D col=q=li (lane-local l,m), rows d = dc*16+g*4+r
    oacc[0] = __builtin_amdgcn_mfma_f32_16x16x32_bf16(vt0, pf, oacc[0], 0, 0, 0);
    oacc[1] = __builtin_amdgcn_mfma_f32_16x16x32_bf16(vt1, pf, oacc[1], 0, 0, 0);
    oacc[2] = __builtin_amdgcn_mfma_f32_16x16x32_bf16(vt2, pf, oacc[2], 0, 0, 0);
    oacc[3] = __builtin_amdgcn_mfma_f32_16x16x32_bf16(vt3, pf, oacc[3], 0, 0, 0);
    kc0 = n0; kc1 = n1; kc2 = n2; kc3 = n3;
  }

  float inv = 1.0f / lrun;
  u16* Yb = Y + ((size_t)(b * Tn + qrow0 + li)) * CCn + h * HDn + g * 4;
#pragma unroll
  for (int dc = 0; dc < 4; ++dc) {
    s16x4 ov;
#pragma unroll
    for (int r = 0; r < 4; ++r) ov[r] = (short)f2bf(oacc[dc][r] * inv);
    *(s16x4*)(Yb + dc * 16) = ov;
  }
}

// ---------- GEMM2: Y[4096][512] x WoT[512][512] -> Y2 f32 [4096][512] (+bias) ----------
__global__ __launch_bounds__(256, 2) void gemm_out(
    const u16* __restrict__ A, const u16* __restrict__ Bt, const float* __restrict__ bias,
    float* __restrict__ Y2) {
  const int nt = 4;
  int m0 = (blockIdx.x / nt) * 128;
  int n0 = (blockIdx.x % nt) * 128;
  __shared__ __align__(16) u16 As[128 * 64];
  __shared__ __align__(16) u16 Bs[128 * 64];
  int tid = threadIdx.x, lane = tid & 63, w = tid >> 6;
  int wr = w >> 1, wc = w & 1;
  int li = lane & 15, g = lane >> 4;
  int rsub = lane >> 3, slot = lane & 7;
  int srcslot = slot ^ rsub;
  f32x4 acc[4][4] = {};
  for (int k0 = 0; k0 < Kn; k0 += 64) {
    __syncthreads();
#pragma unroll
    for (int i = 0; i < 4; ++i) {
      int ci = w * 4 + i;
      int row = ci * 8 + rsub;
      gload16(A  + (size_t)(m0 + row) * Kn + k0 + srcslot * 8, (char*)As + ci * 1024);
      gload16(Bt + (size_t)(n0 + row) * Kn + k0 + srcslot * 8, (char*)Bs + ci * 1024);
    }
    __syncthreads();
#pragma unroll
    for (int kk = 0; kk < 2; ++kk) {
      bf16x8 af[4], bfr[4];
#pragma unroll
      for (int mi = 0; mi < 4; ++mi) {
        int row = wr * 64 + mi * 16 + li;
        int sw = ((kk * 4 + g) ^ (row & 7)) * 8;
        af[mi] = *(const bf16x8*)(As + row * 64 + sw);
      }
#pragma unroll
      for (int ni = 0; ni < 4; ++ni) {
        int row = wc * 64 + ni * 16 + li;
        int sw = ((kk * 4 + g) ^ (row & 7)) * 8;
        bfr[ni] = *(const bf16x8*)(Bs + row * 64 + sw);
      }
#pragma unroll
      for (int mi = 0; mi < 4; ++mi)
#pragma unroll
        for (int ni = 0; ni < 4; ++ni)
          acc[mi][ni] = __builtin_amdgcn_mfma_f32_16x16x32_bf16(af[mi], bfr[ni], acc[mi][ni], 0, 0, 0);
    }
  }
#pragma unroll
  for (int ni = 0; ni < 4; ++ni) {
    int n = n0 + wc * 64 + ni * 16 + li;
    float bn = bias[n];
#pragma unroll
    for (int mi = 0; mi < 4; ++mi) {
#pragma unroll
      for (int r = 0; r < 4; ++r) {
        int m = m0 + wr * 64 + mi * 16 + g * 4 + r;
        Y2[(size_t)m * CCn + n] = acc[mi][ni][r] + bn;
      }
    }
  }
}

// ---------- Y2 [4096][512] f32 -> out (v,b,c,h,w) f32 ----------
__global__ __launch_bounds__(256) void otrans(const float* __restrict__ Y2, float* __restrict__ out) {
  int bi = blockIdx.x;           // 16 vb * 4 ht * 8 ct = 512
  int vb = bi >> 5;
  int ht = (bi >> 3) & 3;
  int ct = bi & 7;
  int v = vb >> 1, b = vb & 1;
  __shared__ float t[64][65];
  int tid = threadIdx.x, col = tid & 63, r4 = tid >> 6;
  const float* src = Y2 + (size_t)(b * Tn + v * 256 + ht * 64) * CCn + ct * 64;
#pragma unroll
  for (int i = 0; i < 16; ++i) {
    int row = i * 4 + r4;                // hw within tile
    t[row][col] = src[(size_t)row * CCn + col];  // col = c
  }
  __syncthreads();
  float* dst = out + ((size_t)vb * CCn + ct * 64) * 256 + ht * 64;
#pragma unroll
  for (int i = 0; i < 16; ++i) {
    int row = i * 4 + r4;                // c within tile
    dst[(size_t)row * 256 + col] = t[col][row];
  }
}

extern "C" void kernel_launch(void* const* d_in, const int* in_sizes, int n_in,
                              void* d_out, int out_size, void* d_ws, size_t ws_size,
                              hipStream_t stream) {
  (void)in_sizes; (void)n_in; (void)out_size; (void)ws_size;
  const float* x    = (const float*)d_in[0];
  const float* Wqkv = (const float*)d_in[1];
  const float* bqkv = (const float*)d_in[2];
  const float* Wo   = (const float*)d_in[3];
  const float* bo   = (const float*)d_in[4];
  float* out = (float*)d_out;
  char* ws = (char*)d_ws;
  const size_t MB = 1ull << 20;
  u16*   Abf   = (u16*)(ws + 0);         // 4MB; reused as Y (bf16) after attn
  u16*   WqkvT = (u16*)(ws + 4 * MB);    // 1.5MB
  u16*   WoT   = (u16*)(ws + 6 * MB);    // 0.5MB
  u16*   Qb    = (u16*)(ws + 7 * MB);    // 4MB
  u16*   Kb    = (u16*)(ws + 11 * MB);   // 4MB
  u16*   VTb   = (u16*)(ws + 15 * MB);   // 4MB  -> peak 19MB
  float* Y2    = (float*)(ws + 7 * MB);  // 8MB, overlays Q/K (dead after attn)

  conv_x<<<512, 256, 0, stream>>>(x, Abf);
  convw<<<192, 256, 0, stream>>>(Wqkv, WqkvT, Kn, N1n);
  convw<<<64, 256, 0, stream>>>(Wo, WoT, Kn, CCn);
  gemm_qkv<<<32 * 12, 256, 0, stream>>>(Abf, WqkvT, bqkv, Qb, Kb, VTb);
  attn<<<2048, 64, 0, stream>>>(Qb, Kb, VTb, Abf);
  gemm_out<<<32 * 4, 256, 0, stream>>>(Abf, WoT, bo, Y2);
  otrans<<<512, 256, 0, stream>>>(Y2, out);
}

// Round 3
// 121.824 us; speedup vs baseline: 1.1600x; 1.0042x over previous
//
#include <hip/hip_runtime.h>
#include <hip/hip_bf16.h>
#include <stdint.h>

#define VPn 8
#define BBn 2
#define CCn 512
#define NHn 8
#define HDn 64
#define Tn  2048
#define Mn  4096      // BBn*Tn
#define N1n 1536
#define Kn  512
#define QSC 0.180336880111120425f   // 0.125 * log2(e): softmax in exp2 domain

typedef __attribute__((ext_vector_type(8))) short bf16x8;
typedef __attribute__((ext_vector_type(4))) short s16x4;
typedef __attribute__((ext_vector_type(4))) float f32x4;
typedef unsigned short u16;
typedef unsigned int   u32;

__device__ __forceinline__ u16 f2bf(float f) {
  return __builtin_bit_cast(u16, __float2bfloat16(f));
}
__device__ __forceinline__ void gload16(const void* g, void* l) {
  __builtin_amdgcn_global_load_lds(
      (const __attribute__((address_space(1))) u32*)g,
      (__attribute__((address_space(3))) u32*)l, 16, 0, 0);
}

// ---------- x (VP,B,C,H,W) f32 -> A_bf16 [4096][512], A[(b*2048+v*256+hw)][c] ----------
__global__ __launch_bounds__(256) void conv_x(const float* __restrict__ x, u16* __restrict__ A) {
  int bi = blockIdx.x;           // 16 vb * 8 ct * 4 ht = 512
  int vb = bi >> 5;
  int ct = (bi >> 2) & 7;
  int ht = bi & 3;
  int v = vb >> 1, b = vb & 1;
  __shared__ float t[64][65];
  int tid = threadIdx.x, col = tid & 63, r4 = tid >> 6;
  const float* src = x + ((size_t)vb * CCn + ct * 64) * 256 + ht * 64;
#pragma unroll
  for (int i = 0; i < 16; ++i) {
    int row = i * 4 + r4;                 // c within tile
    t[row][col] = src[row * 256 + col];   // col = hw within tile
  }
  __syncthreads();
  u16* dst = A + ((size_t)(b * Tn + v * 256 + ht * 64)) * Kn + ct * 64;
#pragma unroll
  for (int i = 0; i < 16; ++i) {
    int row = i * 4 + r4;                 // hw within tile
    dst[row * Kn + col] = f2bf(t[col][row]);
  }
}

// ---------- W [R][C] f32 -> Wt [C][R] bf16 ----------
__global__ __launch_bounds__(256) void convw(const float* __restrict__ Win, u16* __restrict__ Wt,
                                             int R, int Cc) {
  int tpr = Cc >> 6;
  int rt = blockIdx.x / tpr, ct = blockIdx.x % tpr;
  __shared__ float t[64][65];
  int tid = threadIdx.x, col = tid & 63, r4 = tid >> 6;
  const float* src = Win + (size_t)(rt * 64) * Cc + ct * 64;
#pragma unroll
  for (int i = 0; i < 16; ++i) {
    int row = i * 4 + r4;
    t[row][col] = src[row * Cc + col];
  }
  __syncthreads();
  u16* dst = Wt + (size_t)(ct * 64) * R + rt * 64;
#pragma unroll
  for (int i = 0; i < 16; ++i) {
    int row = i * 4 + r4;
    dst[row * R + col] = f2bf(t[col][row]);
  }
}

// ---------- GEMM1: A x WqkvT -> Q(scaled),K [bh][t][d], V -> VT [bh][d][t] ----------
__global__ __launch_bounds__(256, 2) void gemm_qkv(
    const u16* __restrict__ A, const u16* __restrict__ Bt, const float* __restrict__ bias,
    u16* __restrict__ Qo, u16* __restrict__ Ko, u16* __restrict__ VTo) {
  const int nt = N1n / 128;  // 12
  int m0 = (blockIdx.x / nt) * 128;
  int n0 = (blockIdx.x % nt) * 128;
  __shared__ __align__(16) u16 As[128 * 64];
  __shared__ __align__(16) u16 Bs[128 * 64];
  int tid = threadIdx.x, lane = tid & 63, w = tid >> 6;
  int wr = w >> 1, wc = w & 1;
  int li = lane & 15, g = lane >> 4;
  int rsub = lane >> 3, slot = lane & 7;
  int srcslot = slot ^ rsub;  // pre-swizzled global source (LDS dest stays linear)
  f32x4 acc[4][4] = {};
  for (int k0 = 0; k0 < Kn; k0 += 64) {
    __syncthreads();
#pragma unroll
    for (int i = 0; i < 4; ++i) {
      int ci = w * 4 + i;
      int row = ci * 8 + rsub;
      gload16(A  + (size_t)(m0 + row) * Kn + k0 + srcslot * 8, (char*)As + ci * 1024);
      gload16(Bt + (size_t)(n0 + row) * Kn + k0 + srcslot * 8, (char*)Bs + ci * 1024);
    }
    __syncthreads();
#pragma unroll
    for (int kk = 0; kk < 2; ++kk) {
      bf16x8 af[4], bfr[4];
#pragma unroll
      for (int mi = 0; mi < 4; ++mi) {
        int row = wr * 64 + mi * 16 + li;
        int sw = ((kk * 4 + g) ^ (row & 7)) * 8;
        af[mi] = *(const bf16x8*)(As + row * 64 + sw);
      }
#pragma unroll
      for (int ni = 0; ni < 4; ++ni) {
        int row = wc * 64 + ni * 16 + li;
        int sw = ((kk * 4 + g) ^ (row & 7)) * 8;
        bfr[ni] = *(const bf16x8*)(Bs + row * 64 + sw);
      }
#pragma unroll
      for (int mi = 0; mi < 4; ++mi)
#pragma unroll
        for (int ni = 0; ni < 4; ++ni)
          acc[mi][ni] = __builtin_amdgcn_mfma_f32_16x16x32_bf16(af[mi], bfr[ni], acc[mi][ni], 0, 0, 0);
    }
  }
#pragma unroll
  for (int ni = 0; ni < 4; ++ni) {
    int n = n0 + wc * 64 + ni * 16 + li;
    float bn = bias[n];
    int sel = n >> 9, c = n & 511, hh = c >> 6, d = c & 63;
    if (sel < 2) {
      u16* dst = sel ? Ko : Qo;
      float sc = sel ? 1.0f : QSC;  // fold softmax scale + log2e into Q
#pragma unroll
      for (int mi = 0; mi < 4; ++mi) {
#pragma unroll
        for (int r = 0; r < 4; ++r) {
          int m = m0 + wr * 64 + mi * 16 + g * 4 + r;
          int bq = m >> 11, t = m & 2047;
          dst[((size_t)((bq * NHn + hh) * Tn + t)) * HDn + d] = f2bf((acc[mi][ni][r] + bn) * sc);
        }
      }
    } else {  // V: store transposed [bh][d][t], t-contiguous packed
#pragma unroll
      for (int mi = 0; mi < 4; ++mi) {
        int mb = m0 + wr * 64 + mi * 16 + g * 4;
        int bq = mb >> 11, t = mb & 2047;
        s16x4 ov;
#pragma unroll
        for (int r = 0; r < 4; ++r) ov[r] = (short)f2bf(acc[mi][ni][r] + bn);
        *(s16x4*)(VTo + ((size_t)((bq * NHn + hh) * HDn + d)) * Tn + t) = ov;
      }
    }
  }
}

// ---------- flash attention, block-causal, key-split x2, partials out ----------
__global__ __launch_bounds__(64) void attn(
    const u16* __restrict__ Q, const u16* __restrict__ K, const u16* __restrict__ VT,
    float* __restrict__ Op, float* __restrict__ mp, float* __restrict__ lp) {
  int idx = blockIdx.x;            // 4096 = 32 qtiles(heavy first) * 4 sub * 2 seg * 16 bh
  int qtile = 31 - (idx >> 7);
  int sub = (idx >> 5) & 3;
  int seg = (idx >> 4) & 1;
  int bh = idx & 15;
  int qrow0 = (qtile << 6) + (sub << 4);
  int nkeys = ((qtile >> 2) + 1) << 8;
  int half = nkeys >> 1;           // multiple of 128
  int kbeg = seg * half, kend = kbeg + half;
  int lane = threadIdx.x & 63;
  int li = lane & 15, g = lane >> 4;
  const u16* Qb = Q + ((size_t)(bh * Tn + qrow0)) * HDn;
  const u16* Kb = K + (size_t)bh * Tn * HDn;
  const u16* Vb = VT + (size_t)bh * HDn * Tn;

  // Q as B-operand: lane (li,g) holds Q[q=li][d = 8g+j] (+32 for hi half)
  bf16x8 qf0 = *(const bf16x8*)(Qb + li * HDn + g * 8);
  bf16x8 qf1 = *(const bf16x8*)(Qb + li * HDn + 32 + g * 8);

  // K rows permuted: sigma0(x) = 8*(x>>2)+(x&3) so D rows land as keys 8g+j
  const u16* krA = Kb + (size_t)(((li >> 2) << 3) + (li & 3)) * HDn + g * 8;
  const u16* krB = krA + 4 * HDn;

  float mrun = -1e30f, lrun = 0.f;   // lrun: per-lane partial (reduced at end)
  f32x4 oacc[4] = {};

  bf16x8 kc0 = *(const bf16x8*)(krA + (size_t)kbeg * HDn);
  bf16x8 kc1 = *(const bf16x8*)(krA + (size_t)kbeg * HDn + 32);
  bf16x8 kc2 = *(const bf16x8*)(krB + (size_t)kbeg * HDn);
  bf16x8 kc3 = *(const bf16x8*)(krB + (size_t)kbeg * HDn + 32);

  for (int k0 = kbeg; k0 < kend; k0 += 32) {
    // prefetch next K tile
    int kn = (k0 + 32 < kend) ? (k0 + 32) : k0;
    const u16* pa = krA + (size_t)kn * HDn;
    const u16* pb = krB + (size_t)kn * HDn;
    bf16x8 n0 = *(const bf16x8*)(pa);
    bf16x8 n1 = *(const bf16x8*)(pa + 32);
    bf16x8 n2 = *(const bf16x8*)(pb);
    bf16x8 n3 = *(const bf16x8*)(pb + 32);
    // V^T fragments for this tile (issued early; consumed after softmax)
    const u16* vp = Vb + (size_t)li * Tn + k0 + g * 8;
    bf16x8 vt0 = *(const bf16x8*)(vp);
    bf16x8 vt1 = *(const bf16x8*)(vp + 16 * Tn);
    bf16x8 vt2 = *(const bf16x8*)(vp + 32 * Tn);
    bf16x8 vt3 = *(const bf16x8*)(vp + 48 * Tn);

    // S^T = K.Q : lane holds S[q=li][k0+8g+j] in log2 units
    f32x4 s0 = {0, 0, 0, 0}, s1 = {0, 0, 0, 0};
    s0 = __builtin_amdgcn_mfma_f32_16x16x32_bf16(kc0, qf0, s0, 0, 0, 0);
    s0 = __builtin_amdgcn_mfma_f32_16x16x32_bf16(kc1, qf1, s0, 0, 0, 0);
    s1 = __builtin_amdgcn_mfma_f32_16x16x32_bf16(kc2, qf0, s1, 0, 0, 0);
    s1 = __builtin_amdgcn_mfma_f32_16x16x32_bf16(kc3, qf1, s1, 0, 0, 0);

    // row max over this 32-key tile: in-lane tree + 2 shfl (across g copies)
    float m8 = fmaxf(fmaxf(fmaxf(s0[0], s0[1]), fmaxf(s0[2], s0[3])),
                     fmaxf(fmaxf(s1[0], s1[1]), fmaxf(s1[2], s1[3])));
    m8 = fmaxf(m8, __shfl_xor(m8, 16));
    m8 = fmaxf(m8, __shfl_xor(m8, 32));
    // defer-max: only rescale when max grew by > 8 (exp2 units) somewhere
    if (!__all(m8 <= mrun + 8.0f)) {
      float mnew = fmaxf(mrun, m8);
      float fc = exp2f(mrun - mnew);
      mrun = mnew;
      lrun *= fc;
#pragma unroll
      for (int dc = 0; dc < 4; ++dc)
#pragma unroll
        for (int r = 0; r < 4; ++r) oacc[dc][r] *= fc;
    }
    float p[8];
#pragma unroll
    for (int j = 0; j < 8; ++j) {
      float sv = (j < 4) ? s0[j] : s1[j - 4];
      p[j] = exp2f(sv - mrun);
    }
    lrun += ((p[0] + p[1]) + (p[2] + p[3])) + ((p[4] + p[5]) + (p[6] + p[7]));
    bf16x8 pf;
#pragma unroll
    for (int j = 0; j < 8; ++j) pf[j] = (short)f2bf(p[j]);
    // O^T += V^T . P^T : col=q=li, rows d = dc*16+g*4+r
    oacc[0] = __builtin_amdgcn_mfma_f32_16x16x32_bf16(vt0, pf, oacc[0], 0, 0, 0);
    oacc[1] = __builtin_amdgcn_mfma_f32_16x16x32_bf16(vt1, pf, oacc[1], 0, 0, 0);
    oacc[2] = __builtin_amdgcn_mfma_f32_16x16x32_bf16(vt2, pf, oacc[2], 0, 0, 0);
    oacc[3] = __builtin_amdgcn_mfma_f32_16x16x32_bf16(vt3, pf, oacc[3], 0, 0, 0);
    kc0 = n0; kc1 = n1; kc2 = n2; kc3 = n3;
  }

  // reduce l across the 4 g-copies (deferred out of the loop)
  lrun += __shfl_xor(lrun, 16);
  lrun += __shfl_xor(lrun, 32);

  size_t row = (size_t)((seg << 4) + bh) * Tn + qrow0 + li;
  float* ob = Op + row * 64 + g * 4;
#pragma unroll
  for (int dc = 0; dc < 4; ++dc) *(f32x4*)(ob + dc * 16) = oacc[dc];
  if (g == 0) { mp[row] = mrun; lp[row] = lrun; }
}

// ---------- combine 2 key-split partials -> Y bf16 [b][t][c] ----------
__global__ __launch_bounds__(256) void attn_combine(
    const float* __restrict__ Op, const float* __restrict__ mp, const float* __restrict__ lp,
    u16* __restrict__ Y) {
  int G = blockIdx.x * 256 + threadIdx.x;   // 524288 = 16bh * 2048t * 16quads
  int quad = G & 15;
  int t = (G >> 4) & 2047;
  int bh = G >> 15;
  int b = bh >> 3, h = bh & 7;
  size_t r0 = (size_t)bh * Tn + t;
  size_t r1 = r0 + (size_t)16 * Tn;
  float m0 = mp[r0], m1 = mp[r1];
  float l0 = lp[r0], l1 = lp[r1];
  float ms = fmaxf(m0, m1);
  float w0 = exp2f(m0 - ms), w1 = exp2f(m1 - ms);
  float inv = 1.0f / (l0 * w0 + l1 * w1);
  f32x4 o0 = *(const f32x4*)(Op + r0 * 64 + quad * 4);
  f32x4 o1 = *(const f32x4*)(Op + r1 * 64 + quad * 4);
  s16x4 y;
#pragma unroll
  for (int r = 0; r < 4; ++r) y[r] = (short)f2bf((o0[r] * w0 + o1[r] * w1) * inv);
  *(s16x4*)(Y + ((size_t)(b * Tn + t)) * CCn + h * HDn + quad * 4) = y;
}

// ---------- GEMM2: Y[4096][512] x WoT[512][512] -> Y2 f32 [4096][512] (+bias) ----------
__global__ __launch_bounds__(256, 2) void gemm_out(
    const u16* __restrict__ A, const u16* __restrict__ Bt, const float* __restrict__ bias,
    float* __restrict__ Y2) {
  const int nt = 4;
  int m0 = (blockIdx.x / nt) * 128;
  int n0 = (blockIdx.x % nt) * 128;
  __shared__ __align__(16) u16 As[128 * 64];
  __shared__ __align__(16) u16 Bs[128 * 64];
  int tid = threadIdx.x, lane = tid & 63, w = tid >> 6;
  int wr = w >> 1, wc = w & 1;
  int li = lane & 15, g = lane >> 4;
  int rsub = lane >> 3, slot = lane & 7;
  int srcslot = slot ^ rsub;
  f32x4 acc[4][4] = {};
  for (int k0 = 0; k0 < Kn; k0 += 64) {
    __syncthreads();
#pragma unroll
    for (int i = 0; i < 4; ++i) {
      int ci = w * 4 + i;
      int row = ci * 8 + rsub;
      gload16(A  + (size_t)(m0 + row) * Kn + k0 + srcslot * 8, (char*)As + ci * 1024);
      gload16(Bt + (size_t)(n0 + row) * Kn + k0 + srcslot * 8, (char*)Bs + ci * 1024);
    }
    __syncthreads();
#pragma unroll
    for (int kk = 0; kk < 2; ++kk) {
      bf16x8 af[4], bfr[4];
#pragma unroll
      for (int mi = 0; mi < 4; ++mi) {
        int row = wr * 64 + mi * 16 + li;
        int sw = ((kk * 4 + g) ^ (row & 7)) * 8;
        af[mi] = *(const bf16x8*)(As + row * 64 + sw);
      }
#pragma unroll
      for (int ni = 0; ni < 4; ++ni) {
        int row = wc * 64 + ni * 16 + li;
        int sw = ((kk * 4 + g) ^ (row & 7)) * 8;
        bfr[ni] = *(const bf16x8*)(Bs + row * 64 + sw);
      }
#pragma unroll
      for (int mi = 0; mi < 4; ++mi)
#pragma unroll
        for (int ni = 0; ni < 4; ++ni)
          acc[mi][ni] = __builtin_amdgcn_mfma_f32_16x16x32_bf16(af[mi], bfr[ni], acc[mi][ni], 0, 0, 0);
    }
  }
#pragma unroll
  for (int ni = 0; ni < 4; ++ni) {
    int n = n0 + wc * 64 + ni * 16 + li;
    float bn = bias[n];
#pragma unroll
    for (int mi = 0; mi < 4; ++mi) {
#pragma unroll
      for (int r = 0; r < 4; ++r) {
        int m = m0 + wr * 64 + mi * 16 + g * 4 + r;
        Y2[(size_t)m * CCn + n] = acc[mi][ni][r] + bn;
      }
    }
  }
}

// ---------- Y2 [4096][512] f32 -> out (v,b,c,h,w) f32 ----------
__global__ __launch_bounds__(256) void otrans(const float* __restrict__ Y2, float* __restrict__ out) {
  int bi = blockIdx.x;           // 16 vb * 4 ht * 8 ct = 512
  int vb = bi >> 5;
  int ht = (bi >> 3) & 3;
  int ct = bi & 7;
  int v = vb >> 1, b = vb & 1;
  __shared__ float t[64][65];
  int tid = threadIdx.x, col = tid & 63, r4 = tid >> 6;
  const float* src = Y2 + (size_t)(b * Tn + v * 256 + ht * 64) * CCn + ct * 64;
#pragma unroll
  for (int i = 0; i < 16; ++i) {
    int row = i * 4 + r4;                // hw within tile
    t[row][col] = src[(size_t)row * CCn + col];  // col = c
  }
  __syncthreads();
  float* dst = out + ((size_t)vb * CCn + ct * 64) * 256 + ht * 64;
#pragma unroll
  for (int i = 0; i < 16; ++i) {
    int row = i * 4 + r4;                // c within tile
    dst[(size_t)row * 256 + col] = t[col][row];
  }
}

extern "C" void kernel_launch(void* const* d_in, const int* in_sizes, int n_in,
                              void* d_out, int out_size, void* d_ws, size_t ws_size,
                              hipStream_t stream) {
  (void)in_sizes; (void)n_in; (void)out_size; (void)ws_size;
  const float* x    = (const float*)d_in[0];
  const float* Wqkv = (const float*)d_in[1];
  const float* bqkv = (const float*)d_in[2];
  const float* Wo   = (const float*)d_in[3];
  const float* bo   = (const float*)d_in[4];
  float* out = (float*)d_out;
  char* ws = (char*)d_ws;
  const size_t MB = 1ull << 20;
  u16*   Abf   = (u16*)(ws + 0);          // 4MB; reused as Y (bf16) after attn_combine
  u16*   WqkvT = (u16*)(ws + 4 * MB);     // 1.5MB
  u16*   WoT   = (u16*)(ws + 5 * MB + 512 * 1024);  // 0.5MB
  u16*   Qb    = (u16*)(ws + 6 * MB);     // 4MB
  u16*   Kb    = (u16*)(ws + 10 * MB);    // 4MB
  u16*   VTb   = (u16*)(ws + 14 * MB);    // 4MB
  float* Opart = (float*)(ws + 18 * MB);  // 16MB (2 segs x 16 bh x 2048 x 64 f32)
  float* mpart = (float*)(ws + 34 * MB);  // 0.25MB
  float* lpart = (float*)(ws + 34 * MB + 256 * 1024);  // 0.25MB  -> peak 34.5MB
  float* Y2    = (float*)(ws + 18 * MB);  // 8MB, overlays Opart (dead after combine)

  conv_x<<<512, 256, 0, stream>>>(x, Abf);
  convw<<<192, 256, 0, stream>>>(Wqkv, WqkvT, Kn, N1n);
  convw<<<64, 256, 0, stream>>>(Wo, WoT, Kn, CCn);
  gemm_qkv<<<32 * 12, 256, 0, stream>>>(Abf, WqkvT, bqkv, Qb, Kb, VTb);
  attn<<<4096, 64, 0, stream>>>(Qb, Kb, VTb, Opart, mpart, lpart);
  attn_combine<<<2048, 256, 0, stream>>>(Opart, mpart, lpart, Abf);
  gemm_out<<<32 * 4, 256, 0, stream>>>(Abf, WoT, bo, Y2);
  otrans<<<512, 256, 0, stream>>>(Y2, out);
}

// Round 5
// 107.278 us; speedup vs baseline: 1.3173x; 1.1356x over previous
//
#include <hip/hip_runtime.h>
#include <hip/hip_bf16.h>
#include <stdint.h>

#define VPn 8
#define BBn 2
#define CCn 512
#define NHn 8
#define HDn 64
#define Tn  2048
#define Mn  4096      // BBn*Tn
#define N1n 1536
#define Kn  512
#define QSC 0.180336880111120425f   // 0.125 * log2(e): softmax in exp2 domain

typedef __attribute__((ext_vector_type(8))) short bf16x8;
typedef __attribute__((ext_vector_type(4))) short s16x4;
typedef __attribute__((ext_vector_type(4))) float f32x4;
typedef __attribute__((ext_vector_type(16))) float f32x16;
typedef __attribute__((ext_vector_type(4))) int i32x4;
typedef unsigned short u16;
typedef unsigned int   u32;

__device__ __forceinline__ u16 f2bf(float f) {
  return __builtin_bit_cast(u16, __float2bfloat16(f));
}
__device__ __forceinline__ void gload16(const void* g, void* l) {
  __builtin_amdgcn_global_load_lds(
      (const __attribute__((address_space(1))) u32*)g,
      (__attribute__((address_space(3))) u32*)l, 16, 0, 0);
}

// ---------- x (VP,B,C,H,W) f32 -> A_bf16 [4096][512], A[(b*2048+v*256+hw)][c] ----------
__global__ __launch_bounds__(256) void conv_x(const float* __restrict__ x, u16* __restrict__ A) {
  int bi = blockIdx.x;           // 16 vb * 8 ct * 4 ht = 512
  int vb = bi >> 5;
  int ct = (bi >> 2) & 7;
  int ht = bi & 3;
  int v = vb >> 1, b = vb & 1;
  __shared__ float t[64][65];
  int tid = threadIdx.x, col = tid & 63, r4 = tid >> 6;
  const float* src = x + ((size_t)vb * CCn + ct * 64) * 256 + ht * 64;
#pragma unroll
  for (int i = 0; i < 16; ++i) {
    int row = i * 4 + r4;                 // c within tile
    t[row][col] = src[row * 256 + col];   // col = hw within tile
  }
  __syncthreads();
  u16* dst = A + ((size_t)(b * Tn + v * 256 + ht * 64)) * Kn + ct * 64;
#pragma unroll
  for (int i = 0; i < 16; ++i) {
    int row = i * 4 + r4;                 // hw within tile
    dst[row * Kn + col] = f2bf(t[col][row]);
  }
}

// ---------- W [R][C] f32 -> Wt [C][R] bf16 ----------
__global__ __launch_bounds__(256) void convw(const float* __restrict__ Win, u16* __restrict__ Wt,
                                             int R, int Cc) {
  int tpr = Cc >> 6;
  int rt = blockIdx.x / tpr, ct = blockIdx.x % tpr;
  __shared__ float t[64][65];
  int tid = threadIdx.x, col = tid & 63, r4 = tid >> 6;
  const float* src = Win + (size_t)(rt * 64) * Cc + ct * 64;
#pragma unroll
  for (int i = 0; i < 16; ++i) {
    int row = i * 4 + r4;
    t[row][col] = src[row * Cc + col];
  }
  __syncthreads();
  u16* dst = Wt + (size_t)(ct * 64) * R + rt * 64;
#pragma unroll
  for (int i = 0; i < 16; ++i) {
    int row = i * 4 + r4;
    dst[row * R + col] = f2bf(t[col][row]);
  }
}

// ---------- GEMM1: A x WqkvT -> Q(scaled),K [bh][t][d], V -> VT [bh][d][t] ----------
__global__ __launch_bounds__(256, 2) void gemm_qkv(
    const u16* __restrict__ A, const u16* __restrict__ Bt, const float* __restrict__ bias,
    u16* __restrict__ Qo, u16* __restrict__ Ko, u16* __restrict__ VTo) {
  const int nt = N1n / 128;  // 12
  int m0 = (blockIdx.x / nt) * 128;
  int n0 = (blockIdx.x % nt) * 128;
  __shared__ __align__(16) u16 As[128 * 64];
  __shared__ __align__(16) u16 Bs[128 * 64];
  int tid = threadIdx.x, lane = tid & 63, w = tid >> 6;
  int wr = w >> 1, wc = w & 1;
  int li = lane & 15, g = lane >> 4;
  int rsub = lane >> 3, slot = lane & 7;
  int srcslot = slot ^ rsub;  // pre-swizzled global source (LDS dest stays linear)
  f32x4 acc[4][4] = {};
  for (int k0 = 0; k0 < Kn; k0 += 64) {
    __syncthreads();
#pragma unroll
    for (int i = 0; i < 4; ++i) {
      int ci = w * 4 + i;
      int row = ci * 8 + rsub;
      gload16(A  + (size_t)(m0 + row) * Kn + k0 + srcslot * 8, (char*)As + ci * 1024);
      gload16(Bt + (size_t)(n0 + row) * Kn + k0 + srcslot * 8, (char*)Bs + ci * 1024);
    }
    __syncthreads();
#pragma unroll
    for (int kk = 0; kk < 2; ++kk) {
      bf16x8 af[4], bfr[4];
#pragma unroll
      for (int mi = 0; mi < 4; ++mi) {
        int row = wr * 64 + mi * 16 + li;
        int sw = ((kk * 4 + g) ^ (row & 7)) * 8;
        af[mi] = *(const bf16x8*)(As + row * 64 + sw);
      }
#pragma unroll
      for (int ni = 0; ni < 4; ++ni) {
        int row = wc * 64 + ni * 16 + li;
        int sw = ((kk * 4 + g) ^ (row & 7)) * 8;
        bfr[ni] = *(const bf16x8*)(Bs + row * 64 + sw);
      }
#pragma unroll
      for (int mi = 0; mi < 4; ++mi)
#pragma unroll
        for (int ni = 0; ni < 4; ++ni)
          acc[mi][ni] = __builtin_amdgcn_mfma_f32_16x16x32_bf16(af[mi], bfr[ni], acc[mi][ni], 0, 0, 0);
    }
  }
#pragma unroll
  for (int ni = 0; ni < 4; ++ni) {
    int n = n0 + wc * 64 + ni * 16 + li;
    float bn = bias[n];
    int sel = n >> 9, c = n & 511, hh = c >> 6, d = c & 63;
    if (sel < 2) {
      u16* dst = sel ? Ko : Qo;
      float sc = sel ? 1.0f : QSC;  // fold softmax scale + log2e into Q
#pragma unroll
      for (int mi = 0; mi < 4; ++mi) {
#pragma unroll
        for (int r = 0; r < 4; ++r) {
          int m = m0 + wr * 64 + mi * 16 + g * 4 + r;
          int bq = m >> 11, t = m & 2047;
          dst[((size_t)((bq * NHn + hh) * Tn + t)) * HDn + d] = f2bf((acc[mi][ni][r] + bn) * sc);
        }
      }
    } else {  // V: store transposed [bh][d][t], t-contiguous packed
#pragma unroll
      for (int mi = 0; mi < 4; ++mi) {
        int mb = m0 + wr * 64 + mi * 16 + g * 4;
        int bq = mb >> 11, t = mb & 2047;
        s16x4 ov;
#pragma unroll
        for (int r = 0; r < 4; ++r) ov[r] = (short)f2bf(acc[mi][ni][r] + bn);
        *(s16x4*)(VTo + ((size_t)((bq * NHn + hh) * HDn + d)) * Tn + t) = ov;
      }
    }
  }
}

// ---------- flash attention, block-causal, 32x32 swapped MFMA, key-split x2 ----------
// Operand K-slot convention (consistent for P and V, so any HW layout works):
//   B/A element j of lane-half hi <-> key (j&3) + 4*hi + 8*(j>>2)  within 16-key slice.
// This is exactly where QK^T's C/D regs land (row=(r&3)+8*(r>>2)+4*hi), so P needs
// NO cross-lane redistribution; V is loaded as 2x 8B chunks per slice to match.
__global__ __launch_bounds__(64, 2) void attn(
    const u16* __restrict__ Q, const u16* __restrict__ K, const u16* __restrict__ VT,
    float* __restrict__ Op, float* __restrict__ mp, float* __restrict__ lp) {
  int idx = blockIdx.x;            // 2048 = 64 qt(heavy first) * 2 seg * 16 bh
  int qt  = 63 - (idx >> 5);
  int seg = (idx >> 4) & 1;
  int bh  = idx & 15;
  int qrow0 = qt << 5;
  int nkeys = ((qt >> 3) + 1) << 8;
  int hlf = nkeys >> 1;            // multiple of 128
  int kbeg = seg * hlf, kend = kbeg + hlf;
  int lane = threadIdx.x & 63;
  int lq = lane & 31;              // query col / K row / V d-row within tile
  int hi = lane >> 5;              // half select

  const u16* Qb = Q + ((size_t)(bh * Tn + qrow0)) * HDn;
  const u16* Kb = K + (size_t)bh * Tn * HDn;
  const u16* Vb = VT + (size_t)bh * HDn * Tn;

  // Q^T B-frags: chunk c holds B[d=c*16+hi*8+j][q=lq]
  bf16x8 qf[4];
  {
    const u16* qp = Qb + (size_t)lq * HDn + hi * 8;
#pragma unroll
    for (int c = 0; c < 4; ++c) qf[c] = *(const bf16x8*)(qp + c * 16);
  }
  const u16* kp = Kb + (size_t)lq * HDn + hi * 8;  // + key*HDn + c*16
  const u16* vq = Vb + (size_t)lq * Tn + hi * 4;   // + dh*32*Tn + key

  float mrun = -1e30f, lrun = 0.f;   // per-lane partials
  f32x16 oacc0 = {}, oacc1 = {};     // O^T d=0-31 / 32-63, col q=lq

  bf16x8 kc[4];
#pragma unroll
  for (int c = 0; c < 4; ++c) kc[c] = *(const bf16x8*)(kp + (size_t)kbeg * HDn + c * 16);

  for (int k0 = kbeg; k0 < kend; k0 += 32) {
    int kn = (k0 + 32 < kend) ? (k0 + 32) : k0;
    bf16x8 knf[4];
#pragma unroll
    for (int c = 0; c < 4; ++c) knf[c] = *(const bf16x8*)(kp + (size_t)kn * HDn + c * 16);
    // V fragments per the shared K-slot convention: 8B chunks at 4hi offsets
    s16x4 va0l = *(const s16x4*)(vq + k0);
    s16x4 va0h = *(const s16x4*)(vq + k0 + 8);
    s16x4 vb0l = *(const s16x4*)(vq + k0 + 16);
    s16x4 vb0h = *(const s16x4*)(vq + k0 + 24);
    s16x4 va1l = *(const s16x4*)(vq + 32 * Tn + k0);
    s16x4 va1h = *(const s16x4*)(vq + 32 * Tn + k0 + 8);
    s16x4 vb1l = *(const s16x4*)(vq + 32 * Tn + k0 + 16);
    s16x4 vb1h = *(const s16x4*)(vq + 32 * Tn + k0 + 24);

    // S^T[key][q] in exp2 units: col=q=lq, row=key=(r&3)+8*(r>>2)+4*hi
    f32x16 s = {};
#pragma unroll
    for (int c = 0; c < 4; ++c)
      s = __builtin_amdgcn_mfma_f32_32x32x16_bf16(kc[c], qf[c], s, 0, 0, 0);

    // column max: 15-op in-lane tree + one cross-half shuffle
    float m0 = fmaxf(fmaxf(fmaxf(fmaxf(s[0], s[1]), fmaxf(s[2], s[3])),
                           fmaxf(fmaxf(s[4], s[5]), fmaxf(s[6], s[7]))),
                     fmaxf(fmaxf(fmaxf(s[8], s[9]), fmaxf(s[10], s[11])),
                           fmaxf(fmaxf(s[12], s[13]), fmaxf(s[14], s[15]))));
    float mall = fmaxf(m0, __shfl_xor(m0, 32));
    if (!__all(mall <= mrun + 8.0f)) {
      float mnew = fmaxf(mrun, mall);
      float fc = exp2f(mrun - mnew);
      mrun = mnew;
      lrun *= fc;
#pragma unroll
      for (int j = 0; j < 16; ++j) { oacc0[j] *= fc; oacc1[j] *= fc; }
    }
    float p[16];
#pragma unroll
    for (int j = 0; j < 16; ++j) p[j] = exp2f(s[j] - mrun);
    lrun += (((p[0] + p[1]) + (p[2] + p[3])) + ((p[4] + p[5]) + (p[6] + p[7]))) +
            (((p[8] + p[9]) + (p[10] + p[11])) + ((p[12] + p[13]) + (p[14] + p[15])));

    // P -> bf16 B-frags, in-lane only (C/D layout == our B convention)
    u32 cw[8];
#pragma unroll
    for (int a = 0; a < 8; ++a)
      cw[a] = (u32)f2bf(p[2 * a]) | ((u32)f2bf(p[2 * a + 1]) << 16);
    i32x4 pa = {(int)cw[0], (int)cw[1], (int)cw[2], (int)cw[3]};   // keys 0-15
    i32x4 pb = {(int)cw[4], (int)cw[5], (int)cw[6], (int)cw[7]};   // keys 16-31
    bf16x8 pfA = __builtin_bit_cast(bf16x8, pa);
    bf16x8 pfB = __builtin_bit_cast(bf16x8, pb);

    bf16x8 va0 = __builtin_shufflevector(va0l, va0h, 0, 1, 2, 3, 4, 5, 6, 7);
    bf16x8 vb0 = __builtin_shufflevector(vb0l, vb0h, 0, 1, 2, 3, 4, 5, 6, 7);
    bf16x8 va1 = __builtin_shufflevector(va1l, va1h, 0, 1, 2, 3, 4, 5, 6, 7);
    bf16x8 vb1 = __builtin_shufflevector(vb1l, vb1h, 0, 1, 2, 3, 4, 5, 6, 7);

    // O^T += V^T . P^T
    oacc0 = __builtin_amdgcn_mfma_f32_32x32x16_bf16(va0, pfA, oacc0, 0, 0, 0);
    oacc0 = __builtin_amdgcn_mfma_f32_32x32x16_bf16(vb0, pfB, oacc0, 0, 0, 0);
    oacc1 = __builtin_amdgcn_mfma_f32_32x32x16_bf16(va1, pfA, oacc1, 0, 0, 0);
    oacc1 = __builtin_amdgcn_mfma_f32_32x32x16_bf16(vb1, pfB, oacc1, 0, 0, 0);
#pragma unroll
    for (int c = 0; c < 4; ++c) kc[c] = knf[c];
  }

  // total l per query column (cross-half), deferred out of the loop
  lrun += __shfl_xor(lrun, 32);

  size_t row = (size_t)((seg << 4) + bh) * Tn + qrow0 + lq;
  float* ob = Op + row * 64 + hi * 4;
#pragma unroll
  for (int a = 0; a < 4; ++a) {
    f32x4 v0 = {oacc0[4 * a], oacc0[4 * a + 1], oacc0[4 * a + 2], oacc0[4 * a + 3]};
    f32x4 v1 = {oacc1[4 * a], oacc1[4 * a + 1], oacc1[4 * a + 2], oacc1[4 * a + 3]};
    *(f32x4*)(ob + a * 8) = v0;
    *(f32x4*)(ob + 32 + a * 8) = v1;
  }
  if (lane < 32) { mp[row] = mrun; lp[row] = lrun; }
}

// ---------- combine 2 key-split partials -> Y bf16 [b][t][c] ----------
__global__ __launch_bounds__(256) void attn_combine(
    const float* __restrict__ Op, const float* __restrict__ mp, const float* __restrict__ lp,
    u16* __restrict__ Y) {
  int G = blockIdx.x * 256 + threadIdx.x;   // 524288 = 16bh * 2048t * 16quads
  int quad = G & 15;
  int t = (G >> 4) & 2047;
  int bh = G >> 15;
  int b = bh >> 3, h = bh & 7;
  size_t r0 = (size_t)bh * Tn + t;
  size_t r1 = r0 + (size_t)16 * Tn;
  float m0 = mp[r0], m1 = mp[r1];
  float l0 = lp[r0], l1 = lp[r1];
  float ms = fmaxf(m0, m1);
  float w0 = exp2f(m0 - ms), w1 = exp2f(m1 - ms);
  float inv = 1.0f / (l0 * w0 + l1 * w1);
  f32x4 o0 = *(const f32x4*)(Op + r0 * 64 + quad * 4);
  f32x4 o1 = *(const f32x4*)(Op + r1 * 64 + quad * 4);
  s16x4 y;
#pragma unroll
  for (int r = 0; r < 4; ++r) y[r] = (short)f2bf((o0[r] * w0 + o1[r] * w1) * inv);
  *(s16x4*)(Y + ((size_t)(b * Tn + t)) * CCn + h * HDn + quad * 4) = y;
}

// ---------- GEMM2: Y[4096][512] x WoT[512][512] -> Y2 f32 [4096][512] (+bias) ----------
__global__ __launch_bounds__(256, 2) void gemm_out(
    const u16* __restrict__ A, const u16* __restrict__ Bt, const float* __restrict__ bias,
    float* __restrict__ Y2) {
  const int nt = 4;
  int m0 = (blockIdx.x / nt) * 128;
  int n0 = (blockIdx.x % nt) * 128;
  __shared__ __align__(16) u16 As[128 * 64];
  __shared__ __align__(16) u16 Bs[128 * 64];
  int tid = threadIdx.x, lane = tid & 63, w = tid >> 6;
  int wr = w >> 1, wc = w & 1;
  int li = lane & 15, g = lane >> 4;
  int rsub = lane >> 3, slot = lane & 7;
  int srcslot = slot ^ rsub;
  f32x4 acc[4][4] = {};
  for (int k0 = 0; k0 < Kn; k0 += 64) {
    __syncthreads();
#pragma unroll
    for (int i = 0; i < 4; ++i) {
      int ci = w * 4 + i;
      int row = ci * 8 + rsub;
      gload16(A  + (size_t)(m0 + row) * Kn + k0 + srcslot * 8, (char*)As + ci * 1024);
      gload16(Bt + (size_t)(n0 + row) * Kn + k0 + srcslot * 8, (char*)Bs + ci * 1024);
    }
    __syncthreads();
#pragma unroll
    for (int kk = 0; kk < 2; ++kk) {
      bf16x8 af[4], bfr[4];
#pragma unroll
      for (int mi = 0; mi < 4; ++mi) {
        int row = wr * 64 + mi * 16 + li;
        int sw = ((kk * 4 + g) ^ (row & 7)) * 8;
        af[mi] = *(const bf16x8*)(As + row * 64 + sw);
      }
#pragma unroll
      for (int ni = 0; ni < 4; ++ni) {
        int row = wc * 64 + ni * 16 + li;
        int sw = ((kk * 4 + g) ^ (row & 7)) * 8;
        bfr[ni] = *(const bf16x8*)(Bs + row * 64 + sw);
      }
#pragma unroll
      for (int mi = 0; mi < 4; ++mi)
#pragma unroll
        for (int ni = 0; ni < 4; ++ni)
          acc[mi][ni] = __builtin_amdgcn_mfma_f32_16x16x32_bf16(af[mi], bfr[ni], acc[mi][ni], 0, 0, 0);
    }
  }
#pragma unroll
  for (int ni = 0; ni < 4; ++ni) {
    int n = n0 + wc * 64 + ni * 16 + li;
    float bn = bias[n];
#pragma unroll
    for (int mi = 0; mi < 4; ++mi) {
#pragma unroll
      for (int r = 0; r < 4; ++r) {
        int m = m0 + wr * 64 + mi * 16 + g * 4 + r;
        Y2[(size_t)m * CCn + n] = acc[mi][ni][r] + bn;
      }
    }
  }
}

// ---------- Y2 [4096][512] f32 -> out (v,b,c,h,w) f32 ----------
__global__ __launch_bounds__(256) void otrans(const float* __restrict__ Y2, float* __restrict__ out) {
  int bi = blockIdx.x;           // 16 vb * 4 ht * 8 ct = 512
  int vb = bi >> 5;
  int ht = (bi >> 3) & 3;
  int ct = bi & 7;
  int v = vb >> 1, b = vb & 1;
  __shared__ float t[64][65];
  int tid = threadIdx.x, col = tid & 63, r4 = tid >> 6;
  const float* src = Y2 + (size_t)(b * Tn + v * 256 + ht * 64) * CCn + ct * 64;
#pragma unroll
  for (int i = 0; i < 16; ++i) {
    int row = i * 4 + r4;                // hw within tile
    t[row][col] = src[(size_t)row * CCn + col];  // col = c
  }
  __syncthreads();
  float* dst = out + ((size_t)vb * CCn + ct * 64) * 256 + ht * 64;
#pragma unroll
  for (int i = 0; i < 16; ++i) {
    int row = i * 4 + r4;                // c within tile
    dst[(size_t)row * 256 + col] = t[col][row];
  }
}

extern "C" void kernel_launch(void* const* d_in, const int* in_sizes, int n_in,
                              void* d_out, int out_size, void* d_ws, size_t ws_size,
                              hipStream_t stream) {
  (void)in_sizes; (void)n_in; (void)out_size; (void)ws_size;
  const float* x    = (const float*)d_in[0];
  const float* Wqkv = (const float*)d_in[1];
  const float* bqkv = (const float*)d_in[2];
  const float* Wo   = (const float*)d_in[3];
  const float* bo   = (const float*)d_in[4];
  float* out = (float*)d_out;
  char* ws = (char*)d_ws;
  const size_t MB = 1ull << 20;
  u16*   Abf   = (u16*)(ws + 0);          // 4MB; reused as Y (bf16) after attn_combine
  u16*   WqkvT = (u16*)(ws + 4 * MB);     // 1.5MB
  u16*   WoT   = (u16*)(ws + 5 * MB + 512 * 1024);  // 0.5MB
  u16*   Qb    = (u16*)(ws + 6 * MB);     // 4MB
  u16*   Kb    = (u16*)(ws + 10 * MB);    // 4MB
  u16*   VTb   = (u16*)(ws + 14 * MB);    // 4MB
  float* Opart = (float*)(ws + 18 * MB);  // 16MB (2 segs x 16 bh x 2048 x 64 f32)
  float* mpart = (float*)(ws + 34 * MB);  // 0.25MB
  float* lpart = (float*)(ws + 34 * MB + 256 * 1024);  // 0.25MB  -> peak 34.5MB
  float* Y2    = (float*)(ws + 18 * MB);  // 8MB, overlays Opart (dead after combine)

  conv_x<<<512, 256, 0, stream>>>(x, Abf);
  convw<<<192, 256, 0, stream>>>(Wqkv, WqkvT, Kn, N1n);
  convw<<<64, 256, 0, stream>>>(Wo, WoT, Kn, CCn);
  gemm_qkv<<<32 * 12, 256, 0, stream>>>(Abf, WqkvT, bqkv, Qb, Kb, VTb);
  attn<<<2048, 64, 0, stream>>>(Qb, Kb, VTb, Opart, mpart, lpart);
  attn_combine<<<2048, 256, 0, stream>>>(Opart, mpart, lpart, Abf);
  gemm_out<<<32 * 4, 256, 0, stream>>>(Abf, WoT, bo, Y2);
  otrans<<<512, 256, 0, stream>>>(Y2, out);
}

// Round 6
// 106.462 us; speedup vs baseline: 1.3274x; 1.0077x over previous
//
#include <hip/hip_runtime.h>
#include <hip/hip_bf16.h>
#include <stdint.h>

#define VPn 8
#define BBn 2
#define CCn 512
#define NHn 8
#define HDn 64
#define Tn  2048
#define Mn  4096      // BBn*Tn
#define N1n 1536
#define Kn  512
#define QSC 0.180336880111120425f   // 0.125 * log2(e): softmax in exp2 domain

typedef __attribute__((ext_vector_type(8))) short bf16x8;
typedef __attribute__((ext_vector_type(4))) short s16x4;
typedef __attribute__((ext_vector_type(4))) float f32x4;
typedef __attribute__((ext_vector_type(16))) float f32x16;
typedef __attribute__((ext_vector_type(4))) int i32x4;
typedef unsigned short u16;
typedef unsigned int   u32;

__device__ __forceinline__ u16 f2bf(float f) {
  return __builtin_bit_cast(u16, __float2bfloat16(f));
}
__device__ __forceinline__ void gload16(const void* g, void* l) {
  __builtin_amdgcn_global_load_lds(
      (const __attribute__((address_space(1))) u32*)g,
      (__attribute__((address_space(3))) u32*)l, 16, 0, 0);
}

// ---------- x (VP,B,C,H,W) f32 -> A_bf16 [4096][512], A[(b*2048+v*256+hw)][c] ----------
__global__ __launch_bounds__(256) void conv_x(const float* __restrict__ x, u16* __restrict__ A) {
  int bi = blockIdx.x;           // 16 vb * 8 ct * 4 ht = 512
  int vb = bi >> 5;
  int ct = (bi >> 2) & 7;
  int ht = bi & 3;
  int v = vb >> 1, b = vb & 1;
  __shared__ float t[64][65];
  int tid = threadIdx.x, col = tid & 63, r4 = tid >> 6;
  const float* src = x + ((size_t)vb * CCn + ct * 64) * 256 + ht * 64;
#pragma unroll
  for (int i = 0; i < 16; ++i) {
    int row = i * 4 + r4;                 // c within tile
    t[row][col] = src[row * 256 + col];   // col = hw within tile
  }
  __syncthreads();
  u16* dst = A + ((size_t)(b * Tn + v * 256 + ht * 64)) * Kn + ct * 64;
#pragma unroll
  for (int i = 0; i < 16; ++i) {
    int row = i * 4 + r4;                 // hw within tile
    dst[row * Kn + col] = f2bf(t[col][row]);
  }
}

// ---------- W [R][C] f32 -> Wt [C][R] bf16 ----------
__global__ __launch_bounds__(256) void convw(const float* __restrict__ Win, u16* __restrict__ Wt,
                                             int R, int Cc) {
  int tpr = Cc >> 6;
  int rt = blockIdx.x / tpr, ct = blockIdx.x % tpr;
  __shared__ float t[64][65];
  int tid = threadIdx.x, col = tid & 63, r4 = tid >> 6;
  const float* src = Win + (size_t)(rt * 64) * Cc + ct * 64;
#pragma unroll
  for (int i = 0; i < 16; ++i) {
    int row = i * 4 + r4;
    t[row][col] = src[row * Cc + col];
  }
  __syncthreads();
  u16* dst = Wt + (size_t)(ct * 64) * R + rt * 64;
#pragma unroll
  for (int i = 0; i < 16; ++i) {
    int row = i * 4 + r4;
    dst[row * R + col] = f2bf(t[col][row]);
  }
}

// ---------- GEMM1: A x WqkvT -> Q(scaled),K [bh][t][d], V -> VT [bh][d][t] ----------
// 64x128 tile, grid 64*12=768
__global__ __launch_bounds__(256, 2) void gemm_qkv(
    const u16* __restrict__ A, const u16* __restrict__ Bt, const float* __restrict__ bias,
    u16* __restrict__ Qo, u16* __restrict__ Ko, u16* __restrict__ VTo) {
  const int nt = N1n / 128;  // 12
  int m0 = (blockIdx.x / nt) * 64;
  int n0 = (blockIdx.x % nt) * 128;
  __shared__ __align__(16) u16 As[64 * 64];
  __shared__ __align__(16) u16 Bs[128 * 64];
  int tid = threadIdx.x, lane = tid & 63, w = tid >> 6;
  int wr = w & 1, wc = w >> 1;
  int li = lane & 15, g = lane >> 4;
  int rsub = lane >> 3, slot = lane & 7;
  int srcslot = slot ^ rsub;  // pre-swizzled global source (LDS dest stays linear)
  f32x4 acc[2][4] = {};
  for (int k0 = 0; k0 < Kn; k0 += 64) {
    __syncthreads();
#pragma unroll
    for (int i = 0; i < 2; ++i) {
      int ci = w * 2 + i;
      int row = ci * 8 + rsub;
      gload16(A + (size_t)(m0 + row) * Kn + k0 + srcslot * 8, (char*)As + ci * 1024);
    }
#pragma unroll
    for (int i = 0; i < 4; ++i) {
      int ci = w * 4 + i;
      int row = ci * 8 + rsub;
      gload16(Bt + (size_t)(n0 + row) * Kn + k0 + srcslot * 8, (char*)Bs + ci * 1024);
    }
    __syncthreads();
#pragma unroll
    for (int kk = 0; kk < 2; ++kk) {
      bf16x8 af[2], bfr[4];
#pragma unroll
      for (int mi = 0; mi < 2; ++mi) {
        int row = wr * 32 + mi * 16 + li;
        int sw = ((kk * 4 + g) ^ (row & 7)) * 8;
        af[mi] = *(const bf16x8*)(As + row * 64 + sw);
      }
#pragma unroll
      for (int ni = 0; ni < 4; ++ni) {
        int row = wc * 64 + ni * 16 + li;
        int sw = ((kk * 4 + g) ^ (row & 7)) * 8;
        bfr[ni] = *(const bf16x8*)(Bs + row * 64 + sw);
      }
#pragma unroll
      for (int mi = 0; mi < 2; ++mi)
#pragma unroll
        for (int ni = 0; ni < 4; ++ni)
          acc[mi][ni] = __builtin_amdgcn_mfma_f32_16x16x32_bf16(af[mi], bfr[ni], acc[mi][ni], 0, 0, 0);
    }
  }
#pragma unroll
  for (int ni = 0; ni < 4; ++ni) {
    int n = n0 + wc * 64 + ni * 16 + li;
    float bn = bias[n];
    int sel = n >> 9, c = n & 511, hh = c >> 6, d = c & 63;
    if (sel < 2) {
      u16* dst = sel ? Ko : Qo;
      float sc = sel ? 1.0f : QSC;  // fold softmax scale + log2e into Q
#pragma unroll
      for (int mi = 0; mi < 2; ++mi) {
#pragma unroll
        for (int r = 0; r < 4; ++r) {
          int m = m0 + wr * 32 + mi * 16 + g * 4 + r;
          int bq = m >> 11, t = m & 2047;
          dst[((size_t)((bq * NHn + hh) * Tn + t)) * HDn + d] = f2bf((acc[mi][ni][r] + bn) * sc);
        }
      }
    } else {  // V: store transposed [bh][d][t], t-contiguous packed
#pragma unroll
      for (int mi = 0; mi < 2; ++mi) {
        int mb = m0 + wr * 32 + mi * 16 + g * 4;
        int bq = mb >> 11, t = mb & 2047;
        s16x4 ov;
#pragma unroll
        for (int r = 0; r < 4; ++r) ov[r] = (short)f2bf(acc[mi][ni][r] + bn);
        *(s16x4*)(VTo + ((size_t)((bq * NHn + hh) * HDn + d)) * Tn + t) = ov;
      }
    }
  }
}

// ---------- flash attention, block-causal, 32x32 swapped MFMA ----------
// 4 waves/block = 4 key-split segments of one 32-query tile; LDS combine.
// Operand K-slot convention (consistent for P and V, permutation-free):
//   B/A element j of lane-half hi <-> key (j&3) + 4*hi + 8*(j>>2) within 16-key slice,
//   exactly where QK^T's C/D regs land -> P needs NO cross-lane redistribution.
__global__ __launch_bounds__(256, 4) void attn(
    const u16* __restrict__ Q, const u16* __restrict__ K, const u16* __restrict__ VT,
    u16* __restrict__ Y) {
  int idx = blockIdx.x;            // 1024 = 64 qt (heavy first) * 16 bh
  int qt  = 63 - (idx >> 4);
  int bh  = idx & 15;
  int b = bh >> 3, h = bh & 7;
  int qrow0 = qt << 5;
  int nkeys = ((qt >> 3) + 1) << 8;
  int qtr = nkeys >> 2;            // per-wave key range, multiple of 64
  int tid = threadIdx.x;
  int w = tid >> 6;                // segment
  int kbeg = w * qtr, kend = kbeg + qtr;
  int lane = tid & 63;
  int lq = lane & 31;              // query col / K row / V d-row within tile
  int hi = lane >> 5;              // half select

  const u16* Qb = Q + ((size_t)(bh * Tn + qrow0)) * HDn;
  const u16* Kb = K + (size_t)bh * Tn * HDn;
  const u16* Vb = VT + (size_t)bh * HDn * Tn;

  // Q^T B-frags: chunk c holds B[d=c*16+hi*8+j][q=lq]
  bf16x8 qf[4];
  {
    const u16* qp = Qb + (size_t)lq * HDn + hi * 8;
#pragma unroll
    for (int c = 0; c < 4; ++c) qf[c] = *(const bf16x8*)(qp + c * 16);
  }
  const u16* kp = Kb + (size_t)lq * HDn + hi * 8;  // + key*HDn + c*16
  const u16* vq = Vb + (size_t)lq * Tn + hi * 4;   // + dh*32*Tn + key

  float mrun = -1e30f, lrun = 0.f;   // per-lane partials
  f32x16 oacc0 = {}, oacc1 = {};     // O^T d=0-31 / 32-63, col q=lq

  bf16x8 kc[4];
#pragma unroll
  for (int c = 0; c < 4; ++c) kc[c] = *(const bf16x8*)(kp + (size_t)kbeg * HDn + c * 16);

  for (int k0 = kbeg; k0 < kend; k0 += 32) {
    int kn = (k0 + 32 < kend) ? (k0 + 32) : k0;
    bf16x8 knf[4];
#pragma unroll
    for (int c = 0; c < 4; ++c) knf[c] = *(const bf16x8*)(kp + (size_t)kn * HDn + c * 16);
    // V fragments per the shared K-slot convention: 8B chunks at 4hi offsets
    s16x4 va0l = *(const s16x4*)(vq + k0);
    s16x4 va0h = *(const s16x4*)(vq + k0 + 8);
    s16x4 vb0l = *(const s16x4*)(vq + k0 + 16);
    s16x4 vb0h = *(const s16x4*)(vq + k0 + 24);
    s16x4 va1l = *(const s16x4*)(vq + 32 * Tn + k0);
    s16x4 va1h = *(const s16x4*)(vq + 32 * Tn + k0 + 8);
    s16x4 vb1l = *(const s16x4*)(vq + 32 * Tn + k0 + 16);
    s16x4 vb1h = *(const s16x4*)(vq + 32 * Tn + k0 + 24);

    // S^T[key][q] in exp2 units: col=q=lq, row=key=(r&3)+8*(r>>2)+4*hi
    f32x16 s = {};
#pragma unroll
    for (int c = 0; c < 4; ++c)
      s = __builtin_amdgcn_mfma_f32_32x32x16_bf16(kc[c], qf[c], s, 0, 0, 0);

    // column max: 15-op in-lane tree + one cross-half shuffle
    float m0 = fmaxf(fmaxf(fmaxf(fmaxf(s[0], s[1]), fmaxf(s[2], s[3])),
                           fmaxf(fmaxf(s[4], s[5]), fmaxf(s[6], s[7]))),
                     fmaxf(fmaxf(fmaxf(s[8], s[9]), fmaxf(s[10], s[11])),
                           fmaxf(fmaxf(s[12], s[13]), fmaxf(s[14], s[15]))));
    float mall = fmaxf(m0, __shfl_xor(m0, 32));
    if (!__all(mall <= mrun + 8.0f)) {
      float mnew = fmaxf(mrun, mall);
      float fc = exp2f(mrun - mnew);
      mrun = mnew;
      lrun *= fc;
#pragma unroll
      for (int j = 0; j < 16; ++j) { oacc0[j] *= fc; oacc1[j] *= fc; }
    }
    float p[16];
#pragma unroll
    for (int j = 0; j < 16; ++j) p[j] = exp2f(s[j] - mrun);
    lrun += (((p[0] + p[1]) + (p[2] + p[3])) + ((p[4] + p[5]) + (p[6] + p[7]))) +
            (((p[8] + p[9]) + (p[10] + p[11])) + ((p[12] + p[13]) + (p[14] + p[15])));

    // P -> bf16 B-frags, in-lane only (C/D layout == our B convention)
    u32 cw[8];
#pragma unroll
    for (int a = 0; a < 8; ++a)
      cw[a] = (u32)f2bf(p[2 * a]) | ((u32)f2bf(p[2 * a + 1]) << 16);
    i32x4 pa = {(int)cw[0], (int)cw[1], (int)cw[2], (int)cw[3]};   // keys 0-15
    i32x4 pb = {(int)cw[4], (int)cw[5], (int)cw[6], (int)cw[7]};   // keys 16-31
    bf16x8 pfA = __builtin_bit_cast(bf16x8, pa);
    bf16x8 pfB = __builtin_bit_cast(bf16x8, pb);

    bf16x8 va0 = __builtin_shufflevector(va0l, va0h, 0, 1, 2, 3, 4, 5, 6, 7);
    bf16x8 vb0 = __builtin_shufflevector(vb0l, vb0h, 0, 1, 2, 3, 4, 5, 6, 7);
    bf16x8 va1 = __builtin_shufflevector(va1l, va1h, 0, 1, 2, 3, 4, 5, 6, 7);
    bf16x8 vb1 = __builtin_shufflevector(vb1l, vb1h, 0, 1, 2, 3, 4, 5, 6, 7);

    // O^T += V^T . P^T
    oacc0 = __builtin_amdgcn_mfma_f32_32x32x16_bf16(va0, pfA, oacc0, 0, 0, 0);
    oacc0 = __builtin_amdgcn_mfma_f32_32x32x16_bf16(vb0, pfB, oacc0, 0, 0, 0);
    oacc1 = __builtin_amdgcn_mfma_f32_32x32x16_bf16(va1, pfA, oacc1, 0, 0, 0);
    oacc1 = __builtin_amdgcn_mfma_f32_32x32x16_bf16(vb1, pfB, oacc1, 0, 0, 0);
#pragma unroll
    for (int c = 0; c < 4; ++c) kc[c] = knf[c];
  }

  // total l per query column (cross-half)
  lrun += __shfl_xor(lrun, 32);

  // partials -> LDS (padded stride 68 to spread banks)
  __shared__ float Ol[4][32][68];
  __shared__ float ml[2][4][32];
  {
    float* op = &Ol[w][lq][hi * 4];
#pragma unroll
    for (int a = 0; a < 4; ++a) {
      f32x4 v0 = {oacc0[4 * a], oacc0[4 * a + 1], oacc0[4 * a + 2], oacc0[4 * a + 3]};
      f32x4 v1 = {oacc1[4 * a], oacc1[4 * a + 1], oacc1[4 * a + 2], oacc1[4 * a + 3]};
      *(f32x4*)(op + a * 8) = v0;
      *(f32x4*)(op + 32 + a * 8) = v1;
    }
    if (lane < 32) { ml[0][w][lq] = mrun; ml[1][w][lq] = lrun; }
  }
  __syncthreads();

  // in-block combine of the 4 segments; write Y bf16 [b][t][c]
#pragma unroll
  for (int task = tid; task < 512; task += 256) {
    int q = task >> 4, quad = task & 15;
    float m0v = ml[0][0][q], m1v = ml[0][1][q], m2v = ml[0][2][q], m3v = ml[0][3][q];
    float mx = fmaxf(fmaxf(m0v, m1v), fmaxf(m2v, m3v));
    float w0 = exp2f(m0v - mx), w1 = exp2f(m1v - mx);
    float w2 = exp2f(m2v - mx), w3 = exp2f(m3v - mx);
    float l = ml[1][0][q] * w0 + ml[1][1][q] * w1 + ml[1][2][q] * w2 + ml[1][3][q] * w3;
    float inv = 1.0f / l;
    f32x4 o0 = *(const f32x4*)&Ol[0][q][quad * 4];
    f32x4 o1 = *(const f32x4*)&Ol[1][q][quad * 4];
    f32x4 o2 = *(const f32x4*)&Ol[2][q][quad * 4];
    f32x4 o3 = *(const f32x4*)&Ol[3][q][quad * 4];
    s16x4 y;
#pragma unroll
    for (int r = 0; r < 4; ++r)
      y[r] = (short)f2bf((o0[r] * w0 + o1[r] * w1 + o2[r] * w2 + o3[r] * w3) * inv);
    *(s16x4*)(Y + ((size_t)(b * Tn + qrow0 + q)) * CCn + h * HDn + quad * 4) = y;
  }
}

// ---------- GEMM2: Y[4096][512] x WoT[512][512] -> Y2 f32 [4096][512] (+bias) ----------
// 64x128 tile, grid 64*4=256
__global__ __launch_bounds__(256, 2) void gemm_out(
    const u16* __restrict__ A, const u16* __restrict__ Bt, const float* __restrict__ bias,
    float* __restrict__ Y2) {
  const int nt = 4;
  int m0 = (blockIdx.x / nt) * 64;
  int n0 = (blockIdx.x % nt) * 128;
  __shared__ __align__(16) u16 As[64 * 64];
  __shared__ __align__(16) u16 Bs[128 * 64];
  int tid = threadIdx.x, lane = tid & 63, w = tid >> 6;
  int wr = w & 1, wc = w >> 1;
  int li = lane & 15, g = lane >> 4;
  int rsub = lane >> 3, slot = lane & 7;
  int srcslot = slot ^ rsub;
  f32x4 acc[2][4] = {};
  for (int k0 = 0; k0 < Kn; k0 += 64) {
    __syncthreads();
#pragma unroll
    for (int i = 0; i < 2; ++i) {
      int ci = w * 2 + i;
      int row = ci * 8 + rsub;
      gload16(A + (size_t)(m0 + row) * Kn + k0 + srcslot * 8, (char*)As + ci * 1024);
    }
#pragma unroll
    for (int i = 0; i < 4; ++i) {
      int ci = w * 4 + i;
      int row = ci * 8 + rsub;
      gload16(Bt + (size_t)(n0 + row) * Kn + k0 + srcslot * 8, (char*)Bs + ci * 1024);
    }
    __syncthreads();
#pragma unroll
    for (int kk = 0; kk < 2; ++kk) {
      bf16x8 af[2], bfr[4];
#pragma unroll
      for (int mi = 0; mi < 2; ++mi) {
        int row = wr * 32 + mi * 16 + li;
        int sw = ((kk * 4 + g) ^ (row & 7)) * 8;
        af[mi] = *(const bf16x8*)(As + row * 64 + sw);
      }
#pragma unroll
      for (int ni = 0; ni < 4; ++ni) {
        int row = wc * 64 + ni * 16 + li;
        int sw = ((kk * 4 + g) ^ (row & 7)) * 8;
        bfr[ni] = *(const bf16x8*)(Bs + row * 64 + sw);
      }
#pragma unroll
      for (int mi = 0; mi < 2; ++mi)
#pragma unroll
        for (int ni = 0; ni < 4; ++ni)
          acc[mi][ni] = __builtin_amdgcn_mfma_f32_16x16x32_bf16(af[mi], bfr[ni], acc[mi][ni], 0, 0, 0);
    }
  }
#pragma unroll
  for (int ni = 0; ni < 4; ++ni) {
    int n = n0 + wc * 64 + ni * 16 + li;
    float bn = bias[n];
#pragma unroll
    for (int mi = 0; mi < 2; ++mi) {
#pragma unroll
      for (int r = 0; r < 4; ++r) {
        int m = m0 + wr * 32 + mi * 16 + g * 4 + r;
        Y2[(size_t)m * CCn + n] = acc[mi][ni][r] + bn;
      }
    }
  }
}

// ---------- Y2 [4096][512] f32 -> out (v,b,c,h,w) f32 ----------
__global__ __launch_bounds__(256) void otrans(const float* __restrict__ Y2, float* __restrict__ out) {
  int bi = blockIdx.x;           // 16 vb * 4 ht * 8 ct = 512
  int vb = bi >> 5;
  int ht = (bi >> 3) & 3;
  int ct = bi & 7;
  int v = vb >> 1, b = vb & 1;
  __shared__ float t[64][65];
  int tid = threadIdx.x, col = tid & 63, r4 = tid >> 6;
  const float* src = Y2 + (size_t)(b * Tn + v * 256 + ht * 64) * CCn + ct * 64;
#pragma unroll
  for (int i = 0; i < 16; ++i) {
    int row = i * 4 + r4;                // hw within tile
    t[row][col] = src[(size_t)row * CCn + col];  // col = c
  }
  __syncthreads();
  float* dst = out + ((size_t)vb * CCn + ct * 64) * 256 + ht * 64;
#pragma unroll
  for (int i = 0; i < 16; ++i) {
    int row = i * 4 + r4;                // c within tile
    dst[(size_t)row * 256 + col] = t[col][row];
  }
}

extern "C" void kernel_launch(void* const* d_in, const int* in_sizes, int n_in,
                              void* d_out, int out_size, void* d_ws, size_t ws_size,
                              hipStream_t stream) {
  (void)in_sizes; (void)n_in; (void)out_size; (void)ws_size;
  const float* x    = (const float*)d_in[0];
  const float* Wqkv = (const float*)d_in[1];
  const float* bqkv = (const float*)d_in[2];
  const float* Wo   = (const float*)d_in[3];
  const float* bo   = (const float*)d_in[4];
  float* out = (float*)d_out;
  char* ws = (char*)d_ws;
  const size_t MB = 1ull << 20;
  u16*   Abf   = (u16*)(ws + 0);          // 4MB; reused as Y (bf16) after attn
  u16*   WqkvT = (u16*)(ws + 4 * MB);     // 1.5MB
  u16*   WoT   = (u16*)(ws + 5 * MB + 512 * 1024);  // 0.5MB
  u16*   Qb    = (u16*)(ws + 6 * MB);     // 4MB
  u16*   Kb    = (u16*)(ws + 10 * MB);    // 4MB
  u16*   VTb   = (u16*)(ws + 14 * MB);    // 4MB  -> peak 18MB
  float* Y2    = (float*)(ws + 6 * MB);   // 8MB, overlays Qb/Kb (dead after attn)

  conv_x<<<512, 256, 0, stream>>>(x, Abf);
  convw<<<192, 256, 0, stream>>>(Wqkv, WqkvT, Kn, N1n);
  convw<<<64, 256, 0, stream>>>(Wo, WoT, Kn, CCn);
  gemm_qkv<<<64 * 12, 256, 0, stream>>>(Abf, WqkvT, bqkv, Qb, Kb, VTb);
  attn<<<1024, 256, 0, stream>>>(Qb, Kb, VTb, Abf);
  gemm_out<<<64 * 4, 256, 0, stream>>>(Abf, WoT, bo, Y2);
  otrans<<<512, 256, 0, stream>>>(Y2, out);
}

// Round 7
// 71.902 us; speedup vs baseline: 1.9653x; 1.4806x over previous
//
#include <hip/hip_runtime.h>
#include <hip/hip_bf16.h>
#include <stdint.h>

#define VPn 8
#define BBn 2
#define CCn 512
#define NHn 8
#define HDn 64
#define Tn  2048
#define Mn  4096      // BBn*Tn
#define N1n 1536
#define Kn  512
#define QSC 0.180336880111120425f   // 0.125 * log2(e): softmax in exp2 domain

typedef __attribute__((ext_vector_type(8))) short bf16x8;
typedef __attribute__((ext_vector_type(4))) short s16x4;
typedef __attribute__((ext_vector_type(4))) float f32x4;
typedef __attribute__((ext_vector_type(16))) float f32x16;
typedef unsigned short u16;
typedef unsigned int   u32;

__device__ __forceinline__ u16 f2bf(float f) {
  return __builtin_bit_cast(u16, __float2bfloat16(f));
}
__device__ __forceinline__ void gload16(const void* g, void* l) {
  __builtin_amdgcn_global_load_lds(
      (const __attribute__((address_space(1))) u32*)g,
      (__attribute__((address_space(3))) u32*)l, 16, 0, 0);
}

// ---------- x (VP,B,C,H,W) f32 -> A_bf16 [4096][512], A[(b*2048+v*256+hw)][c] ----------
__global__ __launch_bounds__(256) void conv_x(const float* __restrict__ x, u16* __restrict__ A) {
  int bi = blockIdx.x;           // 16 vb * 8 ct * 4 ht = 512
  int vb = bi >> 5;
  int ct = (bi >> 2) & 7;
  int ht = bi & 3;
  int v = vb >> 1, b = vb & 1;
  __shared__ float t[64][65];
  int tid = threadIdx.x, col = tid & 63, r4 = tid >> 6;
  const float* src = x + ((size_t)vb * CCn + ct * 64) * 256 + ht * 64;
#pragma unroll
  for (int i = 0; i < 16; ++i) {
    int row = i * 4 + r4;                 // c within tile
    t[row][col] = src[row * 256 + col];   // col = hw within tile
  }
  __syncthreads();
  u16* dst = A + ((size_t)(b * Tn + v * 256 + ht * 64)) * Kn + ct * 64;
#pragma unroll
  for (int i = 0; i < 16; ++i) {
    int row = i * 4 + r4;                 // hw within tile
    dst[row * Kn + col] = f2bf(t[col][row]);
  }
}

// ---------- W [R][C] f32 -> Wt [C][R] bf16 ----------
__global__ __launch_bounds__(256) void convw(const float* __restrict__ Win, u16* __restrict__ Wt,
                                             int R, int Cc) {
  int tpr = Cc >> 6;
  int rt = blockIdx.x / tpr, ct = blockIdx.x % tpr;
  __shared__ float t[64][65];
  int tid = threadIdx.x, col = tid & 63, r4 = tid >> 6;
  const float* src = Win + (size_t)(rt * 64) * Cc + ct * 64;
#pragma unroll
  for (int i = 0; i < 16; ++i) {
    int row = i * 4 + r4;
    t[row][col] = src[row * Cc + col];
  }
  __syncthreads();
  u16* dst = Wt + (size_t)(ct * 64) * R + rt * 64;
#pragma unroll
  for (int i = 0; i < 16; ++i) {
    int row = i * 4 + r4;
    dst[row * R + col] = f2bf(t[col][row]);
  }
}

// K' layout: [bh][kt][c][hi][lq][j]  (u16), flat = bh*131072 + kt*2048 + c*512 + hi*256 + lq*8 + j
//   holds K[key=kt*32+lq][d=c*16+hi*8+j]  -> attn chunk-c load is 1KB contiguous per wave
// V' layout: [bh][kt][dh][ks][lq][pos] (u16), flat = bh*131072 + kt*2048 + dh*1024 + ks*512 + lq*16 + pos
//   pos = ((key>>2)&1)*8 + ((key&3) | (((key>>3)&1)<<2)), key within 32-tile; d = dh*32+lq
//   -> attn (dh,ks) load is 1KB contiguous; element j of lane-half hi <-> key (j&3)+4hi+8(j>>2)+16ks

// ---------- GEMM1: A x WqkvT -> Q [bh][t][d] (scaled), K' , V' ----------
__global__ __launch_bounds__(256, 2) void gemm_qkv(
    const u16* __restrict__ A, const u16* __restrict__ Bt, const float* __restrict__ bias,
    u16* __restrict__ Qo, u16* __restrict__ Kp, u16* __restrict__ Vp) {
  const int nt = N1n / 128;  // 12
  int m0 = (blockIdx.x / nt) * 64;
  int n0 = (blockIdx.x % nt) * 128;
  __shared__ __align__(16) u16 As[64 * 64];
  __shared__ __align__(16) u16 Bs[128 * 64];
  int tid = threadIdx.x, lane = tid & 63, w = tid >> 6;
  int wr = w & 1, wc = w >> 1;
  int li = lane & 15, g = lane >> 4;
  int rsub = lane >> 3, slot = lane & 7;
  int srcslot = slot ^ rsub;  // pre-swizzled global source (LDS dest stays linear)
  f32x4 acc[2][4] = {};
  for (int k0 = 0; k0 < Kn; k0 += 64) {
    __syncthreads();
#pragma unroll
    for (int i = 0; i < 2; ++i) {
      int ci = w * 2 + i;
      int row = ci * 8 + rsub;
      gload16(A + (size_t)(m0 + row) * Kn + k0 + srcslot * 8, (char*)As + ci * 1024);
    }
#pragma unroll
    for (int i = 0; i < 4; ++i) {
      int ci = w * 4 + i;
      int row = ci * 8 + rsub;
      gload16(Bt + (size_t)(n0 + row) * Kn + k0 + srcslot * 8, (char*)Bs + ci * 1024);
    }
    __syncthreads();
#pragma unroll
    for (int kk = 0; kk < 2; ++kk) {
      bf16x8 af[2], bfr[4];
#pragma unroll
      for (int mi = 0; mi < 2; ++mi) {
        int row = wr * 32 + mi * 16 + li;
        int sw = ((kk * 4 + g) ^ (row & 7)) * 8;
        af[mi] = *(const bf16x8*)(As + row * 64 + sw);
      }
#pragma unroll
      for (int ni = 0; ni < 4; ++ni) {
        int row = wc * 64 + ni * 16 + li;
        int sw = ((kk * 4 + g) ^ (row & 7)) * 8;
        bfr[ni] = *(const bf16x8*)(Bs + row * 64 + sw);
      }
#pragma unroll
      for (int mi = 0; mi < 2; ++mi)
#pragma unroll
        for (int ni = 0; ni < 4; ++ni)
          acc[mi][ni] = __builtin_amdgcn_mfma_f32_16x16x32_bf16(af[mi], bfr[ni], acc[mi][ni], 0, 0, 0);
    }
  }
#pragma unroll
  for (int ni = 0; ni < 4; ++ni) {
    int n = n0 + wc * 64 + ni * 16 + li;
    float bn = bias[n];
    int sel = n >> 9, c = n & 511, hh = c >> 6, d = c & 63;
    if (sel == 0) {        // Q: [bh][t][d], scaled
#pragma unroll
      for (int mi = 0; mi < 2; ++mi) {
#pragma unroll
        for (int r = 0; r < 4; ++r) {
          int m = m0 + wr * 32 + mi * 16 + g * 4 + r;
          int bq = m >> 11, t = m & 2047;
          Qo[((size_t)((bq * NHn + hh) * Tn + t)) * HDn + d] = f2bf((acc[mi][ni][r] + bn) * QSC);
        }
      }
    } else if (sel == 1) {  // K': tiled fragment layout
      int kc = d >> 4, khi = (d >> 3) & 1, kj = d & 7;
#pragma unroll
      for (int mi = 0; mi < 2; ++mi) {
#pragma unroll
        for (int r = 0; r < 4; ++r) {
          int m = m0 + wr * 32 + mi * 16 + g * 4 + r;
          int bq = m >> 11, t = m & 2047;
          size_t off = (size_t)(bq * NHn + hh) * 131072 + (size_t)(t >> 5) * 2048 +
                       kc * 512 + khi * 256 + (t & 31) * 8 + kj;
          Kp[off] = f2bf(acc[mi][ni][r] + bn);
        }
      }
    } else {                // V': tiled slot layout, 4 consecutive keys pack to 8B
      int dh = d >> 5, lqd = d & 31;
#pragma unroll
      for (int mi = 0; mi < 2; ++mi) {
        int mb = m0 + wr * 32 + mi * 16 + g * 4;
        int bq = mb >> 11, t0 = mb & 2047;
        size_t off = (size_t)(bq * NHn + hh) * 131072 + (size_t)(t0 >> 5) * 2048 +
                     dh * 1024 + ((t0 >> 4) & 1) * 512 + lqd * 16 +
                     ((t0 >> 2) & 1) * 8 + ((t0 >> 3) & 1) * 4;
        s16x4 ov;
#pragma unroll
        for (int r = 0; r < 4; ++r) ov[r] = (short)f2bf(acc[mi][ni][r] + bn);
        *(s16x4*)(Vp + off) = ov;
      }
    }
  }
}

// ---------- flash attention, block-causal, 32x32 swapped MFMA ----------
// 4 waves/block = 4 key-split segments of one 32-query tile; LDS combine.
// XCD-pinned: bh = (idx&7) | ((idx>>3)&1)<<3 keeps 2 bh per XCD (1MB K+V in local L2).
__global__ __launch_bounds__(256, 4) void attn(
    const u16* __restrict__ Q, const u16* __restrict__ Kp, const u16* __restrict__ Vp,
    u16* __restrict__ Y) {
  int idx = blockIdx.x;            // 1024
  int bh = (idx & 7) | (((idx >> 3) & 1) << 3);
  int qt = 63 - (idx >> 4);        // heavy first
  int b = bh >> 3, h = bh & 7;
  int qrow0 = qt << 5;
  int nkeys = ((qt >> 3) + 1) << 8;
  int qtr = nkeys >> 2;            // per-wave key range, multiple of 64
  int tid = threadIdx.x;
  int w = tid >> 6;                // segment
  int kbeg = w * qtr, kend = kbeg + qtr;
  int lane = tid & 63;
  int lq = lane & 31;              // query col / K row / V d-row within tile
  int hi = lane >> 5;              // half select

  const u16* Qb = Q + ((size_t)(bh * Tn + qrow0)) * HDn;
  const u16* Kb = Kp + (size_t)bh * 131072;
  const u16* Vb = Vp + (size_t)bh * 131072;
  int kof = hi * 256 + lq * 8;     // K lane offset (u16)
  int vof = lq * 16 + hi * 8;      // V lane offset (u16)

  // Q^T B-frags: chunk c holds B[d=c*16+hi*8+j][q=lq]
  bf16x8 qf[4];
  {
    const u16* qp = Qb + (size_t)lq * HDn + hi * 8;
#pragma unroll
    for (int c = 0; c < 4; ++c) qf[c] = *(const bf16x8*)(qp + c * 16);
  }

  float mrun = -1e30f, lrun = 0.f;   // per-lane partials
  f32x16 oacc0 = {}, oacc1 = {};     // O^T d=0-31 / 32-63, col q=lq

  bf16x8 kc[4];
#pragma unroll
  for (int c = 0; c < 4; ++c)
    kc[c] = *(const bf16x8*)(Kb + (size_t)(kbeg >> 5) * 2048 + c * 512 + kof);

  for (int k0 = kbeg; k0 < kend; k0 += 32) {
    int kt = k0 >> 5;
    int ktn = (k0 + 32 < kend) ? (kt + 1) : kt;
    bf16x8 knf[4];
#pragma unroll
    for (int c = 0; c < 4; ++c)
      knf[c] = *(const bf16x8*)(Kb + (size_t)ktn * 2048 + c * 512 + kof);
    const u16* vt = Vb + (size_t)kt * 2048 + vof;
    bf16x8 va0 = *(const bf16x8*)(vt);           // dh0 ks0
    bf16x8 vb0 = *(const bf16x8*)(vt + 512);     // dh0 ks1
    bf16x8 va1 = *(const bf16x8*)(vt + 1024);    // dh1 ks0
    bf16x8 vb1 = *(const bf16x8*)(vt + 1536);    // dh1 ks1

    // S^T[key][q] in exp2 units: col=q=lq, row=key=(r&3)+8*(r>>2)+4*hi
    f32x16 s = {};
    __builtin_amdgcn_s_setprio(1);
#pragma unroll
    for (int c = 0; c < 4; ++c)
      s = __builtin_amdgcn_mfma_f32_32x32x16_bf16(kc[c], qf[c], s, 0, 0, 0);
    __builtin_amdgcn_s_setprio(0);

    // column max: 15-op in-lane tree + one cross-half shuffle
    float m0 = fmaxf(fmaxf(fmaxf(fmaxf(s[0], s[1]), fmaxf(s[2], s[3])),
                           fmaxf(fmaxf(s[4], s[5]), fmaxf(s[6], s[7]))),
                     fmaxf(fmaxf(fmaxf(s[8], s[9]), fmaxf(s[10], s[11])),
                           fmaxf(fmaxf(s[12], s[13]), fmaxf(s[14], s[15]))));
    float mall = fmaxf(m0, __shfl_xor(m0, 32));
    if (!__all(mall <= mrun + 8.0f)) {
      float mnew = fmaxf(mrun, mall);
      float fc = exp2f(mrun - mnew);
      mrun = mnew;
      lrun *= fc;
#pragma unroll
      for (int j = 0; j < 16; ++j) { oacc0[j] *= fc; oacc1[j] *= fc; }
    }
    float p[16];
#pragma unroll
    for (int j = 0; j < 16; ++j) p[j] = exp2f(s[j] - mrun);
    lrun += (((p[0] + p[1]) + (p[2] + p[3])) + ((p[4] + p[5]) + (p[6] + p[7]))) +
            (((p[8] + p[9]) + (p[10] + p[11])) + ((p[12] + p[13]) + (p[14] + p[15])));

    // P -> bf16 B-frags, in-lane only (C/D layout == our B/V convention)
    u32 cw[8];
#pragma unroll
    for (int a = 0; a < 8; ++a)
      cw[a] = (u32)f2bf(p[2 * a]) | ((u32)f2bf(p[2 * a + 1]) << 16);
    bf16x8 pfA, pfB;
    {
      __attribute__((ext_vector_type(4))) int pa = {(int)cw[0], (int)cw[1], (int)cw[2], (int)cw[3]};
      __attribute__((ext_vector_type(4))) int pb = {(int)cw[4], (int)cw[5], (int)cw[6], (int)cw[7]};
      pfA = __builtin_bit_cast(bf16x8, pa);
      pfB = __builtin_bit_cast(bf16x8, pb);
    }

    // O^T += V^T . P^T
    __builtin_amdgcn_s_setprio(1);
    oacc0 = __builtin_amdgcn_mfma_f32_32x32x16_bf16(va0, pfA, oacc0, 0, 0, 0);
    oacc0 = __builtin_amdgcn_mfma_f32_32x32x16_bf16(vb0, pfB, oacc0, 0, 0, 0);
    oacc1 = __builtin_amdgcn_mfma_f32_32x32x16_bf16(va1, pfA, oacc1, 0, 0, 0);
    oacc1 = __builtin_amdgcn_mfma_f32_32x32x16_bf16(vb1, pfB, oacc1, 0, 0, 0);
    __builtin_amdgcn_s_setprio(0);
#pragma unroll
    for (int c = 0; c < 4; ++c) kc[c] = knf[c];
  }

  // total l per query column (cross-half)
  lrun += __shfl_xor(lrun, 32);

  // partials -> LDS
  __shared__ float Ol[4][32][68];
  __shared__ float ml[2][4][32];
  {
    float* op = &Ol[w][lq][hi * 4];
#pragma unroll
    for (int a = 0; a < 4; ++a) {
      f32x4 v0 = {oacc0[4 * a], oacc0[4 * a + 1], oacc0[4 * a + 2], oacc0[4 * a + 3]};
      f32x4 v1 = {oacc1[4 * a], oacc1[4 * a + 1], oacc1[4 * a + 2], oacc1[4 * a + 3]};
      *(f32x4*)(op + a * 8) = v0;
      *(f32x4*)(op + 32 + a * 8) = v1;
    }
    if (lane < 32) { ml[0][w][lq] = mrun; ml[1][w][lq] = lrun; }
  }
  __syncthreads();

  // in-block combine of the 4 segments; write Y bf16 [b][t][c]
#pragma unroll
  for (int task = tid; task < 512; task += 256) {
    int q = task >> 4, quad = task & 15;
    float m0v = ml[0][0][q], m1v = ml[0][1][q], m2v = ml[0][2][q], m3v = ml[0][3][q];
    float mx = fmaxf(fmaxf(m0v, m1v), fmaxf(m2v, m3v));
    float w0 = exp2f(m0v - mx), w1 = exp2f(m1v - mx);
    float w2 = exp2f(m2v - mx), w3 = exp2f(m3v - mx);
    float l = ml[1][0][q] * w0 + ml[1][1][q] * w1 + ml[1][2][q] * w2 + ml[1][3][q] * w3;
    float inv = 1.0f / l;
    f32x4 o0 = *(const f32x4*)&Ol[0][q][quad * 4];
    f32x4 o1 = *(const f32x4*)&Ol[1][q][quad * 4];
    f32x4 o2 = *(const f32x4*)&Ol[2][q][quad * 4];
    f32x4 o3 = *(const f32x4*)&Ol[3][q][quad * 4];
    s16x4 y;
#pragma unroll
    for (int r = 0; r < 4; ++r)
      y[r] = (short)f2bf((o0[r] * w0 + o1[r] * w1 + o2[r] * w2 + o3[r] * w3) * inv);
    *(s16x4*)(Y + ((size_t)(b * Tn + qrow0 + q)) * CCn + h * HDn + quad * 4) = y;
  }
}

// ---------- GEMM2: Y[4096][512] x WoT[512][512] -> Y2 f32 [4096][512] (+bias) ----------
__global__ __launch_bounds__(256, 2) void gemm_out(
    const u16* __restrict__ A, const u16* __restrict__ Bt, const float* __restrict__ bias,
    float* __restrict__ Y2) {
  const int nt = 4;
  int m0 = (blockIdx.x / nt) * 64;
  int n0 = (blockIdx.x % nt) * 128;
  __shared__ __align__(16) u16 As[64 * 64];
  __shared__ __align__(16) u16 Bs[128 * 64];
  int tid = threadIdx.x, lane = tid & 63, w = tid >> 6;
  int wr = w & 1, wc = w >> 1;
  int li = lane & 15, g = lane >> 4;
  int rsub = lane >> 3, slot = lane & 7;
  int srcslot = slot ^ rsub;
  f32x4 acc[2][4] = {};
  for (int k0 = 0; k0 < Kn; k0 += 64) {
    __syncthreads();
#pragma unroll
    for (int i = 0; i < 2; ++i) {
      int ci = w * 2 + i;
      int row = ci * 8 + rsub;
      gload16(A + (size_t)(m0 + row) * Kn + k0 + srcslot * 8, (char*)As + ci * 1024);
    }
#pragma unroll
    for (int i = 0; i < 4; ++i) {
      int ci = w * 4 + i;
      int row = ci * 8 + rsub;
      gload16(Bt + (size_t)(n0 + row) * Kn + k0 + srcslot * 8, (char*)Bs + ci * 1024);
    }
    __syncthreads();
#pragma unroll
    for (int kk = 0; kk < 2; ++kk) {
      bf16x8 af[2], bfr[4];
#pragma unroll
      for (int mi = 0; mi < 2; ++mi) {
        int row = wr * 32 + mi * 16 + li;
        int sw = ((kk * 4 + g) ^ (row & 7)) * 8;
        af[mi] = *(const bf16x8*)(As + row * 64 + sw);
      }
#pragma unroll
      for (int ni = 0; ni < 4; ++ni) {
        int row = wc * 64 + ni * 16 + li;
        int sw = ((kk * 4 + g) ^ (row & 7)) * 8;
        bfr[ni] = *(const bf16x8*)(Bs + row * 64 + sw);
      }
#pragma unroll
      for (int mi = 0; mi < 2; ++mi)
#pragma unroll
        for (int ni = 0; ni < 4; ++ni)
          acc[mi][ni] = __builtin_amdgcn_mfma_f32_16x16x32_bf16(af[mi], bfr[ni], acc[mi][ni], 0, 0, 0);
    }
  }
#pragma unroll
  for (int ni = 0; ni < 4; ++ni) {
    int n = n0 + wc * 64 + ni * 16 + li;
    float bn = bias[n];
#pragma unroll
    for (int mi = 0; mi < 2; ++mi) {
#pragma unroll
      for (int r = 0; r < 4; ++r) {
        int m = m0 + wr * 32 + mi * 16 + g * 4 + r;
        Y2[(size_t)m * CCn + n] = acc[mi][ni][r] + bn;
      }
    }
  }
}

// ---------- Y2 [4096][512] f32 -> out (v,b,c,h,w) f32 ----------
__global__ __launch_bounds__(256) void otrans(const float* __restrict__ Y2, float* __restrict__ out) {
  int bi = blockIdx.x;           // 16 vb * 4 ht * 8 ct = 512
  int vb = bi >> 5;
  int ht = (bi >> 3) & 3;
  int ct = bi & 7;
  int v = vb >> 1, b = vb & 1;
  __shared__ float t[64][65];
  int tid = threadIdx.x, col = tid & 63, r4 = tid >> 6;
  const float* src = Y2 + (size_t)(b * Tn + v * 256 + ht * 64) * CCn + ct * 64;
#pragma unroll
  for (int i = 0; i < 16; ++i) {
    int row = i * 4 + r4;                // hw within tile
    t[row][col] = src[(size_t)row * CCn + col];  // col = c
  }
  __syncthreads();
  float* dst = out + ((size_t)vb * CCn + ct * 64) * 256 + ht * 64;
#pragma unroll
  for (int i = 0; i < 16; ++i) {
    int row = i * 4 + r4;                // c within tile
    dst[(size_t)row * 256 + col] = t[col][row];
  }
}

extern "C" void kernel_launch(void* const* d_in, const int* in_sizes, int n_in,
                              void* d_out, int out_size, void* d_ws, size_t ws_size,
                              hipStream_t stream) {
  (void)in_sizes; (void)n_in; (void)out_size; (void)ws_size;
  const float* x    = (const float*)d_in[0];
  const float* Wqkv = (const float*)d_in[1];
  const float* bqkv = (const float*)d_in[2];
  const float* Wo   = (const float*)d_in[3];
  const float* bo   = (const float*)d_in[4];
  float* out = (float*)d_out;
  char* ws = (char*)d_ws;
  const size_t MB = 1ull << 20;
  u16*   Abf   = (u16*)(ws + 0);          // 4MB; reused as Y (bf16) after attn
  u16*   WqkvT = (u16*)(ws + 4 * MB);     // 1.5MB
  u16*   WoT   = (u16*)(ws + 5 * MB + 512 * 1024);  // 0.5MB
  u16*   Qb    = (u16*)(ws + 6 * MB);     // 4MB
  u16*   Kb    = (u16*)(ws + 10 * MB);    // 4MB (K' tiled)
  u16*   VTb   = (u16*)(ws + 14 * MB);    // 4MB (V' tiled)  -> peak 18MB
  float* Y2    = (float*)(ws + 6 * MB);   // 8MB, overlays Qb/Kb (dead after attn)

  conv_x<<<512, 256, 0, stream>>>(x, Abf);
  convw<<<192, 256, 0, stream>>>(Wqkv, WqkvT, Kn, N1n);
  convw<<<64, 256, 0, stream>>>(Wo, WoT, Kn, CCn);
  gemm_qkv<<<64 * 12, 256, 0, stream>>>(Abf, WqkvT, bqkv, Qb, Kb, VTb);
  attn<<<1024, 256, 0, stream>>>(Qb, Kb, VTb, Abf);
  gemm_out<<<64 * 4, 256, 0, stream>>>(Abf, WoT, bo, Y2);
  otrans<<<512, 256, 0, stream>>>(Y2, out);
}

// Round 8
// 62.222 us; speedup vs baseline: 2.2711x; 1.1556x over previous
//
#include <hip/hip_runtime.h>
#include <hip/hip_bf16.h>
#include <stdint.h>

#define VPn 8
#define BBn 2
#define CCn 512
#define NHn 8
#define HDn 64
#define Tn  2048
#define Mn  4096      // BBn*Tn
#define N1n 1536
#define Kn  512
#define QSC 0.180336880111120425f   // 0.125 * log2(e): softmax in exp2 domain

typedef __attribute__((ext_vector_type(8))) short bf16x8;
typedef __attribute__((ext_vector_type(4))) short s16x4;
typedef __attribute__((ext_vector_type(4))) float f32x4;
typedef __attribute__((ext_vector_type(16))) float f32x16;
typedef __attribute__((ext_vector_type(2))) unsigned int u32x2;
typedef unsigned short u16;
typedef unsigned int   u32;

__device__ __forceinline__ u16 f2bf(float f) {
  return __builtin_bit_cast(u16, __float2bfloat16(f));
}
// packed RNE f32x2 -> bf16x2 (same rounding as __float2bfloat16, 1 instr for 2 values)
__device__ __forceinline__ u32 cvtpk(float lo, float hi) {
  u32 r;
  asm("v_cvt_pk_bf16_f32 %0, %1, %2" : "=v"(r) : "v"(lo), "v"(hi));
  return r;
}
__device__ __forceinline__ void gload16(const void* g, void* l) {
  __builtin_amdgcn_global_load_lds(
      (const __attribute__((address_space(1))) u32*)g,
      (__attribute__((address_space(3))) u32*)l, 16, 0, 0);
}

// ---------- x (VP,B,C,H,W) f32 -> A_bf16 [4096][512], A[(b*2048+v*256+hw)][c] ----------
__global__ __launch_bounds__(256) void conv_x(const float* __restrict__ x, u16* __restrict__ A) {
  int bi = blockIdx.x;           // 16 vb * 8 ct * 4 ht = 512
  int vb = bi >> 5;
  int ct = (bi >> 2) & 7;
  int ht = bi & 3;
  int v = vb >> 1, b = vb & 1;
  __shared__ float t[64][65];
  int tid = threadIdx.x, col = tid & 63, r4 = tid >> 6;
  const float* src = x + ((size_t)vb * CCn + ct * 64) * 256 + ht * 64;
#pragma unroll
  for (int i = 0; i < 16; ++i) {
    int row = i * 4 + r4;                 // c within tile
    t[row][col] = src[row * 256 + col];   // col = hw within tile
  }
  __syncthreads();
  u16* dst = A + ((size_t)(b * Tn + v * 256 + ht * 64)) * Kn + ct * 64;
#pragma unroll
  for (int i = 0; i < 16; ++i) {
    int row = i * 4 + r4;                 // hw within tile
    dst[row * Kn + col] = f2bf(t[col][row]);
  }
}

// ---------- W [R][C] f32 -> Wt [C][R] bf16 ----------
__global__ __launch_bounds__(256) void convw(const float* __restrict__ Win, u16* __restrict__ Wt,
                                             int R, int Cc) {
  int tpr = Cc >> 6;
  int rt = blockIdx.x / tpr, ct = blockIdx.x % tpr;
  __shared__ float t[64][65];
  int tid = threadIdx.x, col = tid & 63, r4 = tid >> 6;
  const float* src = Win + (size_t)(rt * 64) * Cc + ct * 64;
#pragma unroll
  for (int i = 0; i < 16; ++i) {
    int row = i * 4 + r4;
    t[row][col] = src[row * Cc + col];
  }
  __syncthreads();
  u16* dst = Wt + (size_t)(ct * 64) * R + rt * 64;
#pragma unroll
  for (int i = 0; i < 16; ++i) {
    int row = i * 4 + r4;
    dst[row * R + col] = f2bf(t[col][row]);
  }
}

// K' layout: [bh][kt][c][hi][lq][j]  (u16), flat = bh*131072 + kt*2048 + c*512 + hi*256 + lq*8 + j
//   holds K[key=kt*32+lq][d=c*16+hi*8+j]  -> attn chunk-c load is 1KB contiguous per wave
// V' layout: [bh][kt][dh][ks][lq][pos] (u16), flat = bh*131072 + kt*2048 + dh*1024 + ks*512 + lq*16 + pos
//   pos = ((key>>2)&1)*8 + ((key&3) | (((key>>3)&1)<<2)), key within 32-tile; d = dh*32+lq
//   -> attn (dh,ks) load is 1KB contiguous; element j of lane-half hi <-> key (j&3)+4hi+8(j>>2)+16ks

// ---------- GEMM1: A x WqkvT -> Q [bh][t][d] (scaled), K' , V' ----------
__global__ __launch_bounds__(256, 2) void gemm_qkv(
    const u16* __restrict__ A, const u16* __restrict__ Bt, const float* __restrict__ bias,
    u16* __restrict__ Qo, u16* __restrict__ Kp, u16* __restrict__ Vp) {
  const int nt = N1n / 128;  // 12
  int m0 = (blockIdx.x / nt) * 64;
  int n0 = (blockIdx.x % nt) * 128;
  __shared__ __align__(16) u16 As[64 * 64];
  __shared__ __align__(16) u16 Bs[128 * 64];
  int tid = threadIdx.x, lane = tid & 63, w = tid >> 6;
  int wr = w & 1, wc = w >> 1;
  int li = lane & 15, g = lane >> 4;
  int rsub = lane >> 3, slot = lane & 7;
  int srcslot = slot ^ rsub;  // pre-swizzled global source (LDS dest stays linear)
  f32x4 acc[2][4] = {};
  for (int k0 = 0; k0 < Kn; k0 += 64) {
    __syncthreads();
#pragma unroll
    for (int i = 0; i < 2; ++i) {
      int ci = w * 2 + i;
      int row = ci * 8 + rsub;
      gload16(A + (size_t)(m0 + row) * Kn + k0 + srcslot * 8, (char*)As + ci * 1024);
    }
#pragma unroll
    for (int i = 0; i < 4; ++i) {
      int ci = w * 4 + i;
      int row = ci * 8 + rsub;
      gload16(Bt + (size_t)(n0 + row) * Kn + k0 + srcslot * 8, (char*)Bs + ci * 1024);
    }
    __syncthreads();
#pragma unroll
    for (int kk = 0; kk < 2; ++kk) {
      bf16x8 af[2], bfr[4];
#pragma unroll
      for (int mi = 0; mi < 2; ++mi) {
        int row = wr * 32 + mi * 16 + li;
        int sw = ((kk * 4 + g) ^ (row & 7)) * 8;
        af[mi] = *(const bf16x8*)(As + row * 64 + sw);
      }
#pragma unroll
      for (int ni = 0; ni < 4; ++ni) {
        int row = wc * 64 + ni * 16 + li;
        int sw = ((kk * 4 + g) ^ (row & 7)) * 8;
        bfr[ni] = *(const bf16x8*)(Bs + row * 64 + sw);
      }
#pragma unroll
      for (int mi = 0; mi < 2; ++mi)
#pragma unroll
        for (int ni = 0; ni < 4; ++ni)
          acc[mi][ni] = __builtin_amdgcn_mfma_f32_16x16x32_bf16(af[mi], bfr[ni], acc[mi][ni], 0, 0, 0);
    }
  }
#pragma unroll
  for (int ni = 0; ni < 4; ++ni) {
    int n = n0 + wc * 64 + ni * 16 + li;
    float bn = bias[n];
    int sel = n >> 9, c = n & 511, hh = c >> 6, d = c & 63;
    if (sel == 0) {        // Q: [bh][t][d], scaled
#pragma unroll
      for (int mi = 0; mi < 2; ++mi) {
#pragma unroll
        for (int r = 0; r < 4; ++r) {
          int m = m0 + wr * 32 + mi * 16 + g * 4 + r;
          int bq = m >> 11, t = m & 2047;
          Qo[((size_t)((bq * NHn + hh) * Tn + t)) * HDn + d] = f2bf((acc[mi][ni][r] + bn) * QSC);
        }
      }
    } else if (sel == 1) {  // K': tiled fragment layout
      int kc = d >> 4, khi = (d >> 3) & 1, kj = d & 7;
#pragma unroll
      for (int mi = 0; mi < 2; ++mi) {
#pragma unroll
        for (int r = 0; r < 4; ++r) {
          int m = m0 + wr * 32 + mi * 16 + g * 4 + r;
          int bq = m >> 11, t = m & 2047;
          size_t off = (size_t)(bq * NHn + hh) * 131072 + (size_t)(t >> 5) * 2048 +
                       kc * 512 + khi * 256 + (t & 31) * 8 + kj;
          Kp[off] = f2bf(acc[mi][ni][r] + bn);
        }
      }
    } else {                // V': tiled slot layout, 4 consecutive keys pack to 8B
      int dh = d >> 5, lqd = d & 31;
#pragma unroll
      for (int mi = 0; mi < 2; ++mi) {
        int mb = m0 + wr * 32 + mi * 16 + g * 4;
        int bq = mb >> 11, t0 = mb & 2047;
        size_t off = (size_t)(bq * NHn + hh) * 131072 + (size_t)(t0 >> 5) * 2048 +
                     dh * 1024 + ((t0 >> 4) & 1) * 512 + lqd * 16 +
                     ((t0 >> 2) & 1) * 8 + ((t0 >> 3) & 1) * 4;
        u32x2 ov;
        ov.x = cvtpk(acc[mi][ni][0] + bn, acc[mi][ni][1] + bn);
        ov.y = cvtpk(acc[mi][ni][2] + bn, acc[mi][ni][3] + bn);
        *(u32x2*)(Vp + off) = ov;
      }
    }
  }
}

// ---------- flash attention, block-causal, 32x32 swapped MFMA ----------
// 4 waves/block = 4 key-split segments of one 32-query tile; LDS combine.
// XCD-pinned: bh = (idx&7) | ((idx>>3)&1)<<3 keeps 2 bh per XCD (1MB K+V in local L2).
__global__ __launch_bounds__(256, 4) void attn(
    const u16* __restrict__ Q, const u16* __restrict__ Kp, const u16* __restrict__ Vp,
    u16* __restrict__ Y) {
  int idx = blockIdx.x;            // 1024
  int bh = (idx & 7) | (((idx >> 3) & 1) << 3);
  int qt = 63 - (idx >> 4);        // heavy first
  int b = bh >> 3, h = bh & 7;
  int qrow0 = qt << 5;
  int nkeys = ((qt >> 3) + 1) << 8;
  int qtr = nkeys >> 2;            // per-wave key range, multiple of 64
  int tid = threadIdx.x;
  int w = tid >> 6;                // segment
  int kbeg = w * qtr, kend = kbeg + qtr;
  int lane = tid & 63;
  int lq = lane & 31;              // query col / K row / V d-row within tile
  int hi = lane >> 5;              // half select

  const u16* Qb = Q + ((size_t)(bh * Tn + qrow0)) * HDn;
  const u16* Kb = Kp + (size_t)bh * 131072;
  const u16* Vb = Vp + (size_t)bh * 131072;
  int kof = hi * 256 + lq * 8;     // K lane offset (u16)
  int vof = lq * 16 + hi * 8;      // V lane offset (u16)

  // Q^T B-frags: chunk c holds B[d=c*16+hi*8+j][q=lq]
  bf16x8 qf[4];
  {
    const u16* qp = Qb + (size_t)lq * HDn + hi * 8;
#pragma unroll
    for (int c = 0; c < 4; ++c) qf[c] = *(const bf16x8*)(qp + c * 16);
  }

  float mrun = -1e30f, lrun = 0.f;   // per-lane partials
  f32x16 oacc0 = {}, oacc1 = {};     // O^T d=0-31 / 32-63, col q=lq

  bf16x8 kc[4];
#pragma unroll
  for (int c = 0; c < 4; ++c)
    kc[c] = *(const bf16x8*)(Kb + (size_t)(kbeg >> 5) * 2048 + c * 512 + kof);

  for (int k0 = kbeg; k0 < kend; k0 += 32) {
    int kt = k0 >> 5;
    int ktn = (k0 + 32 < kend) ? (kt + 1) : kt;
    bf16x8 knf[4];
#pragma unroll
    for (int c = 0; c < 4; ++c)
      knf[c] = *(const bf16x8*)(Kb + (size_t)ktn * 2048 + c * 512 + kof);
    const u16* vt = Vb + (size_t)kt * 2048 + vof;
    bf16x8 va0 = *(const bf16x8*)(vt);           // dh0 ks0
    bf16x8 vb0 = *(const bf16x8*)(vt + 512);     // dh0 ks1
    bf16x8 va1 = *(const bf16x8*)(vt + 1024);    // dh1 ks0
    bf16x8 vb1 = *(const bf16x8*)(vt + 1536);    // dh1 ks1

    // S^T[key][q] in exp2 units: col=q=lq, row=key=(r&3)+8*(r>>2)+4*hi
    f32x16 s = {};
    __builtin_amdgcn_s_setprio(1);
#pragma unroll
    for (int c = 0; c < 4; ++c)
      s = __builtin_amdgcn_mfma_f32_32x32x16_bf16(kc[c], qf[c], s, 0, 0, 0);
    __builtin_amdgcn_s_setprio(0);

    // column max: 15-op in-lane tree + one cross-half shuffle
    float m0 = fmaxf(fmaxf(fmaxf(fmaxf(s[0], s[1]), fmaxf(s[2], s[3])),
                           fmaxf(fmaxf(s[4], s[5]), fmaxf(s[6], s[7]))),
                     fmaxf(fmaxf(fmaxf(s[8], s[9]), fmaxf(s[10], s[11])),
                           fmaxf(fmaxf(s[12], s[13]), fmaxf(s[14], s[15]))));
    float mall = fmaxf(m0, __shfl_xor(m0, 32));
    if (!__all(mall <= mrun + 8.0f)) {
      float mnew = fmaxf(mrun, mall);
      float fc = exp2f(mrun - mnew);
      mrun = mnew;
      lrun *= fc;
#pragma unroll
      for (int j = 0; j < 16; ++j) { oacc0[j] *= fc; oacc1[j] *= fc; }
    }
    float p[16];
#pragma unroll
    for (int j = 0; j < 16; ++j) p[j] = exp2f(s[j] - mrun);
    lrun += (((p[0] + p[1]) + (p[2] + p[3])) + ((p[4] + p[5]) + (p[6] + p[7]))) +
            (((p[8] + p[9]) + (p[10] + p[11])) + ((p[12] + p[13]) + (p[14] + p[15])));

    // P -> bf16 B-frags via packed cvt (in-lane only; C/D layout == our B/V convention)
    bf16x8 pfA, pfB;
    {
      __attribute__((ext_vector_type(4))) int pa = {
          (int)cvtpk(p[0], p[1]), (int)cvtpk(p[2], p[3]),
          (int)cvtpk(p[4], p[5]), (int)cvtpk(p[6], p[7])};
      __attribute__((ext_vector_type(4))) int pb = {
          (int)cvtpk(p[8], p[9]), (int)cvtpk(p[10], p[11]),
          (int)cvtpk(p[12], p[13]), (int)cvtpk(p[14], p[15])};
      pfA = __builtin_bit_cast(bf16x8, pa);
      pfB = __builtin_bit_cast(bf16x8, pb);
    }

    // O^T += V^T . P^T
    __builtin_amdgcn_s_setprio(1);
    oacc0 = __builtin_amdgcn_mfma_f32_32x32x16_bf16(va0, pfA, oacc0, 0, 0, 0);
    oacc0 = __builtin_amdgcn_mfma_f32_32x32x16_bf16(vb0, pfB, oacc0, 0, 0, 0);
    oacc1 = __builtin_amdgcn_mfma_f32_32x32x16_bf16(va1, pfA, oacc1, 0, 0, 0);
    oacc1 = __builtin_amdgcn_mfma_f32_32x32x16_bf16(vb1, pfB, oacc1, 0, 0, 0);
    __builtin_amdgcn_s_setprio(0);
#pragma unroll
    for (int c = 0; c < 4; ++c) kc[c] = knf[c];
  }

  // total l per query column (cross-half)
  lrun += __shfl_xor(lrun, 32);

  // partials -> LDS
  __shared__ float Ol[4][32][68];
  __shared__ float ml[2][4][32];
  {
    float* op = &Ol[w][lq][hi * 4];
#pragma unroll
    for (int a = 0; a < 4; ++a) {
      f32x4 v0 = {oacc0[4 * a], oacc0[4 * a + 1], oacc0[4 * a + 2], oacc0[4 * a + 3]};
      f32x4 v1 = {oacc1[4 * a], oacc1[4 * a + 1], oacc1[4 * a + 2], oacc1[4 * a + 3]};
      *(f32x4*)(op + a * 8) = v0;
      *(f32x4*)(op + 32 + a * 8) = v1;
    }
    if (lane < 32) { ml[0][w][lq] = mrun; ml[1][w][lq] = lrun; }
  }
  __syncthreads();

  // in-block combine of the 4 segments; write Y bf16 [b][t][c]
#pragma unroll
  for (int task = tid; task < 512; task += 256) {
    int q = task >> 4, quad = task & 15;
    float m0v = ml[0][0][q], m1v = ml[0][1][q], m2v = ml[0][2][q], m3v = ml[0][3][q];
    float mx = fmaxf(fmaxf(m0v, m1v), fmaxf(m2v, m3v));
    float w0 = exp2f(m0v - mx), w1 = exp2f(m1v - mx);
    float w2 = exp2f(m2v - mx), w3 = exp2f(m3v - mx);
    float l = ml[1][0][q] * w0 + ml[1][1][q] * w1 + ml[1][2][q] * w2 + ml[1][3][q] * w3;
    float inv = 1.0f / l;
    f32x4 o0 = *(const f32x4*)&Ol[0][q][quad * 4];
    f32x4 o1 = *(const f32x4*)&Ol[1][q][quad * 4];
    f32x4 o2 = *(const f32x4*)&Ol[2][q][quad * 4];
    f32x4 o3 = *(const f32x4*)&Ol[3][q][quad * 4];
    float y0 = (o0[0] * w0 + o1[0] * w1 + o2[0] * w2 + o3[0] * w3) * inv;
    float y1 = (o0[1] * w0 + o1[1] * w1 + o2[1] * w2 + o3[1] * w3) * inv;
    float y2 = (o0[2] * w0 + o1[2] * w1 + o2[2] * w2 + o3[2] * w3) * inv;
    float y3 = (o0[3] * w0 + o1[3] * w1 + o2[3] * w2 + o3[3] * w3) * inv;
    u32x2 yv;
    yv.x = cvtpk(y0, y1);
    yv.y = cvtpk(y2, y3);
    *(u32x2*)(Y + ((size_t)(b * Tn + qrow0 + q)) * CCn + h * HDn + quad * 4) = yv;
  }
}

// ---------- GEMM2: Y[4096][512] x WoT[512][512] + bias -> out (v,b,c,h,w) f32, fused transpose ----------
// 64x64 tile, grid 64*8=512, 2 blocks/CU
__global__ __launch_bounds__(256, 4) void gemm_out(
    const u16* __restrict__ A, const u16* __restrict__ Bt, const float* __restrict__ bias,
    float* __restrict__ out) {
  const int nt = 8;
  int m0 = (blockIdx.x / nt) * 64;
  int n0 = (blockIdx.x % nt) * 64;
  __shared__ __align__(16) u16 As[64 * 64];
  __shared__ __align__(16) u16 Bs[64 * 64];
  int tid = threadIdx.x, lane = tid & 63, w = tid >> 6;
  int wr = w & 1, wc = w >> 1;
  int li = lane & 15, g = lane >> 4;
  int rsub = lane >> 3, slot = lane & 7;
  int srcslot = slot ^ rsub;
  f32x4 acc[2][2] = {};
  for (int k0 = 0; k0 < Kn; k0 += 64) {
    __syncthreads();
#pragma unroll
    for (int i = 0; i < 2; ++i) {
      int ci = w * 2 + i;
      int row = ci * 8 + rsub;
      gload16(A  + (size_t)(m0 + row) * Kn + k0 + srcslot * 8, (char*)As + ci * 1024);
      gload16(Bt + (size_t)(n0 + row) * Kn + k0 + srcslot * 8, (char*)Bs + ci * 1024);
    }
    __syncthreads();
#pragma unroll
    for (int kk = 0; kk < 2; ++kk) {
      bf16x8 af[2], bfr[2];
#pragma unroll
      for (int mi = 0; mi < 2; ++mi) {
        int row = wr * 32 + mi * 16 + li;
        int sw = ((kk * 4 + g) ^ (row & 7)) * 8;
        af[mi] = *(const bf16x8*)(As + row * 64 + sw);
      }
#pragma unroll
      for (int ni = 0; ni < 2; ++ni) {
        int row = wc * 32 + ni * 16 + li;
        int sw = ((kk * 4 + g) ^ (row & 7)) * 8;
        bfr[ni] = *(const bf16x8*)(Bs + row * 64 + sw);
      }
#pragma unroll
      for (int mi = 0; mi < 2; ++mi)
#pragma unroll
        for (int ni = 0; ni < 2; ++ni)
          acc[mi][ni] = __builtin_amdgcn_mfma_f32_16x16x32_bf16(af[mi], bfr[ni], acc[mi][ni], 0, 0, 0);
    }
  }
  // epilogue: out[(v*2+b)*512 + n][hw], m = b*2048 + v*256 + hw; m0 64-aligned -> b,v fixed
  int b = m0 >> 11, v = (m0 >> 8) & 7, hw0 = m0 & 255;
  float* ob = out + (size_t)((v * 2 + b) * 512) * 256;
#pragma unroll
  for (int ni = 0; ni < 2; ++ni) {
    int n = n0 + wc * 32 + ni * 16 + li;
    float bn = bias[n];
#pragma unroll
    for (int mi = 0; mi < 2; ++mi) {
      int hw = hw0 + wr * 32 + mi * 16 + g * 4;
      f32x4 y;
#pragma unroll
      for (int r = 0; r < 4; ++r) y[r] = acc[mi][ni][r] + bn;
      *(f32x4*)(ob + (size_t)n * 256 + hw) = y;
    }
  }
}

extern "C" void kernel_launch(void* const* d_in, const int* in_sizes, int n_in,
                              void* d_out, int out_size, void* d_ws, size_t ws_size,
                              hipStream_t stream) {
  (void)in_sizes; (void)n_in; (void)out_size; (void)ws_size;
  const float* x    = (const float*)d_in[0];
  const float* Wqkv = (const float*)d_in[1];
  const float* bqkv = (const float*)d_in[2];
  const float* Wo   = (const float*)d_in[3];
  const float* bo   = (const float*)d_in[4];
  float* out = (float*)d_out;
  char* ws = (char*)d_ws;
  const size_t MB = 1ull << 20;
  u16*   Abf   = (u16*)(ws + 0);          // 4MB; reused as Y (bf16) after attn
  u16*   WqkvT = (u16*)(ws + 4 * MB);     // 1.5MB
  u16*   WoT   = (u16*)(ws + 5 * MB + 512 * 1024);  // 0.5MB
  u16*   Qb    = (u16*)(ws + 6 * MB);     // 4MB
  u16*   Kb    = (u16*)(ws + 10 * MB);    // 4MB (K' tiled)
  u16*   VTb   = (u16*)(ws + 14 * MB);    // 4MB (V' tiled)  -> peak 18MB

  conv_x<<<512, 256, 0, stream>>>(x, Abf);
  convw<<<192, 256, 0, stream>>>(Wqkv, WqkvT, Kn, N1n);
  convw<<<64, 256, 0, stream>>>(Wo, WoT, Kn, CCn);
  gemm_qkv<<<64 * 12, 256, 0, stream>>>(Abf, WqkvT, bqkv, Qb, Kb, VTb);
  attn<<<1024, 256, 0, stream>>>(Qb, Kb, VTb, Abf);
  gemm_out<<<64 * 8, 256, 0, stream>>>(Abf, WoT, bo, out);
}

// Round 9
// 60.536 us; speedup vs baseline: 2.3343x; 1.0278x over previous
//
#include <hip/hip_runtime.h>
#include <hip/hip_bf16.h>
#include <stdint.h>

#define VPn 8
#define BBn 2
#define CCn 512
#define NHn 8
#define HDn 64
#define Tn  2048
#define Mn  4096      // BBn*Tn
#define N1n 1536
#define Kn  512
#define QSC 0.180336880111120425f   // 0.125 * log2(e): softmax in exp2 domain

typedef __attribute__((ext_vector_type(8))) short bf16x8;
typedef __attribute__((ext_vector_type(4))) short s16x4;
typedef __attribute__((ext_vector_type(4))) float f32x4;
typedef __attribute__((ext_vector_type(16))) float f32x16;
typedef __attribute__((ext_vector_type(2))) unsigned int u32x2;
typedef unsigned short u16;
typedef unsigned int   u32;

__device__ __forceinline__ u16 f2bf(float f) {
  return __builtin_bit_cast(u16, __float2bfloat16(f));
}
// packed RNE f32x2 -> bf16x2 (same rounding as __float2bfloat16, 1 instr for 2 values)
__device__ __forceinline__ u32 cvtpk(float lo, float hi) {
  u32 r;
  asm("v_cvt_pk_bf16_f32 %0, %1, %2" : "=v"(r) : "v"(lo), "v"(hi));
  return r;
}
__device__ __forceinline__ void gload16(const void* g, void* l) {
  __builtin_amdgcn_global_load_lds(
      (const __attribute__((address_space(1))) u32*)g,
      (__attribute__((address_space(3))) u32*)l, 16, 0, 0);
}

// ---------- x (VP,B,C,H,W) f32 -> A_bf16 [4096][512], A[(b*2048+v*256+hw)][c] ----------
__global__ __launch_bounds__(256) void conv_x(const float* __restrict__ x, u16* __restrict__ A) {
  int bi = blockIdx.x;           // 16 vb * 8 ct * 4 ht = 512
  int vb = bi >> 5;
  int ct = (bi >> 2) & 7;
  int ht = bi & 3;
  int v = vb >> 1, b = vb & 1;
  __shared__ float t[64][65];
  int tid = threadIdx.x, col = tid & 63, r4 = tid >> 6;
  const float* src = x + ((size_t)vb * CCn + ct * 64) * 256 + ht * 64;
#pragma unroll
  for (int i = 0; i < 16; ++i) {
    int row = i * 4 + r4;                 // c within tile
    t[row][col] = src[row * 256 + col];   // col = hw within tile
  }
  __syncthreads();
  u16* dst = A + ((size_t)(b * Tn + v * 256 + ht * 64)) * Kn + ct * 64;
#pragma unroll
  for (int i = 0; i < 16; ++i) {
    int row = i * 4 + r4;                 // hw within tile
    dst[row * Kn + col] = f2bf(t[col][row]);
  }
}

// ---------- both W [R][C] f32 -> Wt [C][R] bf16 in one launch ----------
__global__ __launch_bounds__(256) void convw(const float* __restrict__ Wqkv, const float* __restrict__ Wo,
                                             u16* __restrict__ WqkvT, u16* __restrict__ WoT) {
  int bi = blockIdx.x;   // 0..191: Wqkv (tpr=24); 192..255: Wo (tpr=8)
  const float* Win; u16* Wt; int Cc, rt, ct;
  if (bi < 192) { Win = Wqkv; Wt = WqkvT; Cc = N1n; rt = bi / 24; ct = bi % 24; }
  else { bi -= 192; Win = Wo; Wt = WoT; Cc = CCn; rt = bi / 8; ct = bi % 8; }
  __shared__ float t[64][65];
  int tid = threadIdx.x, col = tid & 63, r4 = tid >> 6;
  const float* src = Win + (size_t)(rt * 64) * Cc + ct * 64;
#pragma unroll
  for (int i = 0; i < 16; ++i) {
    int row = i * 4 + r4;
    t[row][col] = src[row * Cc + col];
  }
  __syncthreads();
  u16* dst = Wt + (size_t)(ct * 64) * Kn + rt * 64;
#pragma unroll
  for (int i = 0; i < 16; ++i) {
    int row = i * 4 + r4;
    dst[row * Kn + col] = f2bf(t[col][row]);
  }
}

// K' layout: [bh][kt][c][hi][lq][j]  (u16), flat = bh*131072 + kt*2048 + c*512 + hi*256 + lq*8 + j
// V' layout: [bh][kt][dh][ks][lq][pos] (u16), flat = bh*131072 + kt*2048 + dh*1024 + ks*512 + lq*16 + pos

// ---------- GEMM1: A x WqkvT -> Q (scaled), K', V'; 2-phase double-buffered staging ----------
__global__ __launch_bounds__(256, 3) void gemm_qkv(
    const u16* __restrict__ A, const u16* __restrict__ Bt, const float* __restrict__ bias,
    u16* __restrict__ Qo, u16* __restrict__ Kp, u16* __restrict__ Vp) {
  const int nt = N1n / 128;  // 12
  int m0 = (blockIdx.x / nt) * 64;
  int n0 = (blockIdx.x % nt) * 128;
  __shared__ __align__(16) u16 As[2][64 * 64];
  __shared__ __align__(16) u16 Bs[2][128 * 64];
  int tid = threadIdx.x, lane = tid & 63, w = tid >> 6;
  int wr = w & 1, wc = w >> 1;
  int li = lane & 15, g = lane >> 4;
  int rsub = lane >> 3, slot = lane & 7;
  int srcslot = slot ^ rsub;  // pre-swizzled global source (LDS dest stays linear)
  f32x4 acc[2][4] = {};

#define QKV_STAGE(buf, kk0)                                                    \
  {                                                                            \
    _Pragma("unroll")                                                          \
    for (int i = 0; i < 2; ++i) {                                              \
      int ci = w * 2 + i;                                                      \
      int row = ci * 8 + rsub;                                                 \
      gload16(A + (size_t)(m0 + row) * Kn + (kk0) + srcslot * 8,               \
              (char*)&As[buf][0] + ci * 1024);                                 \
    }                                                                          \
    _Pragma("unroll")                                                          \
    for (int i = 0; i < 4; ++i) {                                              \
      int ci = w * 4 + i;                                                      \
      int row = ci * 8 + rsub;                                                 \
      gload16(Bt + (size_t)(n0 + row) * Kn + (kk0) + srcslot * 8,              \
              (char*)&Bs[buf][0] + ci * 1024);                                 \
    }                                                                          \
  }

  QKV_STAGE(0, 0);
#pragma unroll
  for (int step = 0; step < 8; ++step) {
    const int cur = step & 1;
    if (step < 7) {
      QKV_STAGE(cur ^ 1, (step + 1) * 64);
      asm volatile("s_waitcnt vmcnt(6)");   // 6 newest (next tile) may stay in flight
    } else {
      asm volatile("s_waitcnt vmcnt(0)");
    }
    __builtin_amdgcn_s_barrier();
#pragma unroll
    for (int kk = 0; kk < 2; ++kk) {
      bf16x8 af[2], bfr[4];
#pragma unroll
      for (int mi = 0; mi < 2; ++mi) {
        int row = wr * 32 + mi * 16 + li;
        int sw = ((kk * 4 + g) ^ (row & 7)) * 8;
        af[mi] = *(const bf16x8*)(&As[cur][0] + row * 64 + sw);
      }
#pragma unroll
      for (int ni = 0; ni < 4; ++ni) {
        int row = wc * 64 + ni * 16 + li;
        int sw = ((kk * 4 + g) ^ (row & 7)) * 8;
        bfr[ni] = *(const bf16x8*)(&Bs[cur][0] + row * 64 + sw);
      }
#pragma unroll
      for (int mi = 0; mi < 2; ++mi)
#pragma unroll
        for (int ni = 0; ni < 4; ++ni)
          acc[mi][ni] = __builtin_amdgcn_mfma_f32_16x16x32_bf16(af[mi], bfr[ni], acc[mi][ni], 0, 0, 0);
    }
    asm volatile("s_waitcnt lgkmcnt(0)");
    __builtin_amdgcn_sched_barrier(0);
    __builtin_amdgcn_s_barrier();
  }
#pragma unroll
  for (int ni = 0; ni < 4; ++ni) {
    int n = n0 + wc * 64 + ni * 16 + li;
    float bn = bias[n];
    int sel = n >> 9, c = n & 511, hh = c >> 6, d = c & 63;
    if (sel == 0) {        // Q: [bh][t][d], scaled
#pragma unroll
      for (int mi = 0; mi < 2; ++mi) {
#pragma unroll
        for (int r = 0; r < 4; ++r) {
          int m = m0 + wr * 32 + mi * 16 + g * 4 + r;
          int bq = m >> 11, t = m & 2047;
          Qo[((size_t)((bq * NHn + hh) * Tn + t)) * HDn + d] = f2bf((acc[mi][ni][r] + bn) * QSC);
        }
      }
    } else if (sel == 1) {  // K': tiled fragment layout
      int kc = d >> 4, khi = (d >> 3) & 1, kj = d & 7;
#pragma unroll
      for (int mi = 0; mi < 2; ++mi) {
#pragma unroll
        for (int r = 0; r < 4; ++r) {
          int m = m0 + wr * 32 + mi * 16 + g * 4 + r;
          int bq = m >> 11, t = m & 2047;
          size_t off = (size_t)(bq * NHn + hh) * 131072 + (size_t)(t >> 5) * 2048 +
                       kc * 512 + khi * 256 + (t & 31) * 8 + kj;
          Kp[off] = f2bf(acc[mi][ni][r] + bn);
        }
      }
    } else {                // V': tiled slot layout, 4 consecutive keys pack to 8B
      int dh = d >> 5, lqd = d & 31;
#pragma unroll
      for (int mi = 0; mi < 2; ++mi) {
        int mb = m0 + wr * 32 + mi * 16 + g * 4;
        int bq = mb >> 11, t0 = mb & 2047;
        size_t off = (size_t)(bq * NHn + hh) * 131072 + (size_t)(t0 >> 5) * 2048 +
                     dh * 1024 + ((t0 >> 4) & 1) * 512 + lqd * 16 +
                     ((t0 >> 2) & 1) * 8 + ((t0 >> 3) & 1) * 4;
        u32x2 ov;
        ov.x = cvtpk(acc[mi][ni][0] + bn, acc[mi][ni][1] + bn);
        ov.y = cvtpk(acc[mi][ni][2] + bn, acc[mi][ni][3] + bn);
        *(u32x2*)(Vp + off) = ov;
      }
    }
  }
}

// ---------- flash attention, block-causal, 32x32 swapped MFMA ----------
// 4 waves/block = 4 key-split segments of one 32-query tile; LDS combine.
// XCD-pinned: bh = (idx&7) | ((idx>>3)&1)<<3 keeps 2 bh per XCD (1MB K+V in local L2).
__global__ __launch_bounds__(256, 4) void attn(
    const u16* __restrict__ Q, const u16* __restrict__ Kp, const u16* __restrict__ Vp,
    u16* __restrict__ Y) {
  int idx = blockIdx.x;            // 1024
  int bh = (idx & 7) | (((idx >> 3) & 1) << 3);
  int qt = 63 - (idx >> 4);        // heavy first
  int b = bh >> 3, h = bh & 7;
  int qrow0 = qt << 5;
  int nkeys = ((qt >> 3) + 1) << 8;
  int qtr = nkeys >> 2;            // per-wave key range, multiple of 64
  int tid = threadIdx.x;
  int w = tid >> 6;                // segment
  int kbeg = w * qtr, kend = kbeg + qtr;
  int lane = tid & 63;
  int lq = lane & 31;              // query col / K row / V d-row within tile
  int hi = lane >> 5;              // half select

  const u16* Qb = Q + ((size_t)(bh * Tn + qrow0)) * HDn;
  const u16* Kb = Kp + (size_t)bh * 131072;
  const u16* Vb = Vp + (size_t)bh * 131072;
  int kof = hi * 256 + lq * 8;     // K lane offset (u16)
  int vof = lq * 16 + hi * 8;      // V lane offset (u16)

  // Q^T B-frags: chunk c holds B[d=c*16+hi*8+j][q=lq]
  bf16x8 qf[4];
  {
    const u16* qp = Qb + (size_t)lq * HDn + hi * 8;
#pragma unroll
    for (int c = 0; c < 4; ++c) qf[c] = *(const bf16x8*)(qp + c * 16);
  }

  float mrun = -1e30f, lrun = 0.f;   // per-lane partials
  f32x16 oacc0 = {}, oacc1 = {};     // O^T d=0-31 / 32-63, col q=lq

  bf16x8 kc[4];
#pragma unroll
  for (int c = 0; c < 4; ++c)
    kc[c] = *(const bf16x8*)(Kb + (size_t)(kbeg >> 5) * 2048 + c * 512 + kof);

  for (int k0 = kbeg; k0 < kend; k0 += 32) {
    int kt = k0 >> 5;
    int ktn = (k0 + 32 < kend) ? (kt + 1) : kt;
    bf16x8 knf[4];
#pragma unroll
    for (int c = 0; c < 4; ++c)
      knf[c] = *(const bf16x8*)(Kb + (size_t)ktn * 2048 + c * 512 + kof);
    const u16* vt = Vb + (size_t)kt * 2048 + vof;
    bf16x8 va0 = *(const bf16x8*)(vt);           // dh0 ks0
    bf16x8 vb0 = *(const bf16x8*)(vt + 512);     // dh0 ks1
    bf16x8 va1 = *(const bf16x8*)(vt + 1024);    // dh1 ks0
    bf16x8 vb1 = *(const bf16x8*)(vt + 1536);    // dh1 ks1

    // S^T[key][q] in exp2 units: col=q=lq, row=key=(r&3)+8*(r>>2)+4*hi
    f32x16 s = {};
    __builtin_amdgcn_s_setprio(1);
#pragma unroll
    for (int c = 0; c < 4; ++c)
      s = __builtin_amdgcn_mfma_f32_32x32x16_bf16(kc[c], qf[c], s, 0, 0, 0);
    __builtin_amdgcn_s_setprio(0);

    // column max: 15-op in-lane tree + one cross-half shuffle
    float m0 = fmaxf(fmaxf(fmaxf(fmaxf(s[0], s[1]), fmaxf(s[2], s[3])),
                           fmaxf(fmaxf(s[4], s[5]), fmaxf(s[6], s[7]))),
                     fmaxf(fmaxf(fmaxf(s[8], s[9]), fmaxf(s[10], s[11])),
                           fmaxf(fmaxf(s[12], s[13]), fmaxf(s[14], s[15]))));
    float mall = fmaxf(m0, __shfl_xor(m0, 32));
    if (!__all(mall <= mrun + 8.0f)) {
      float mnew = fmaxf(mrun, mall);
      float fc = exp2f(mrun - mnew);
      mrun = mnew;
      lrun *= fc;
#pragma unroll
      for (int j = 0; j < 16; ++j) { oacc0[j] *= fc; oacc1[j] *= fc; }
    }
    float p[16];
#pragma unroll
    for (int j = 0; j < 16; ++j) p[j] = exp2f(s[j] - mrun);
    lrun += (((p[0] + p[1]) + (p[2] + p[3])) + ((p[4] + p[5]) + (p[6] + p[7]))) +
            (((p[8] + p[9]) + (p[10] + p[11])) + ((p[12] + p[13]) + (p[14] + p[15])));

    // P -> bf16 B-frags via packed cvt (in-lane only; C/D layout == our B/V convention)
    bf16x8 pfA, pfB;
    {
      __attribute__((ext_vector_type(4))) int pa = {
          (int)cvtpk(p[0], p[1]), (int)cvtpk(p[2], p[3]),
          (int)cvtpk(p[4], p[5]), (int)cvtpk(p[6], p[7])};
      __attribute__((ext_vector_type(4))) int pb = {
          (int)cvtpk(p[8], p[9]), (int)cvtpk(p[10], p[11]),
          (int)cvtpk(p[12], p[13]), (int)cvtpk(p[14], p[15])};
      pfA = __builtin_bit_cast(bf16x8, pa);
      pfB = __builtin_bit_cast(bf16x8, pb);
    }

    // O^T += V^T . P^T
    __builtin_amdgcn_s_setprio(1);
    oacc0 = __builtin_amdgcn_mfma_f32_32x32x16_bf16(va0, pfA, oacc0, 0, 0, 0);
    oacc0 = __builtin_amdgcn_mfma_f32_32x32x16_bf16(vb0, pfB, oacc0, 0, 0, 0);
    oacc1 = __builtin_amdgcn_mfma_f32_32x32x16_bf16(va1, pfA, oacc1, 0, 0, 0);
    oacc1 = __builtin_amdgcn_mfma_f32_32x32x16_bf16(vb1, pfB, oacc1, 0, 0, 0);
    __builtin_amdgcn_s_setprio(0);
#pragma unroll
    for (int c = 0; c < 4; ++c) kc[c] = knf[c];
  }

  // total l per query column (cross-half)
  lrun += __shfl_xor(lrun, 32);

  // partials -> LDS
  __shared__ float Ol[4][32][68];
  __shared__ float ml[2][4][32];
  {
    float* op = &Ol[w][lq][hi * 4];
#pragma unroll
    for (int a = 0; a < 4; ++a) {
      f32x4 v0 = {oacc0[4 * a], oacc0[4 * a + 1], oacc0[4 * a + 2], oacc0[4 * a + 3]};
      f32x4 v1 = {oacc1[4 * a], oacc1[4 * a + 1], oacc1[4 * a + 2], oacc1[4 * a + 3]};
      *(f32x4*)(op + a * 8) = v0;
      *(f32x4*)(op + 32 + a * 8) = v1;
    }
    if (lane < 32) { ml[0][w][lq] = mrun; ml[1][w][lq] = lrun; }
  }
  __syncthreads();

  // in-block combine of the 4 segments; write Y bf16 [b][t][c]
#pragma unroll
  for (int task = tid; task < 512; task += 256) {
    int q = task >> 4, quad = task & 15;
    float m0v = ml[0][0][q], m1v = ml[0][1][q], m2v = ml[0][2][q], m3v = ml[0][3][q];
    float mx = fmaxf(fmaxf(m0v, m1v), fmaxf(m2v, m3v));
    float w0 = exp2f(m0v - mx), w1 = exp2f(m1v - mx);
    float w2 = exp2f(m2v - mx), w3 = exp2f(m3v - mx);
    float l = ml[1][0][q] * w0 + ml[1][1][q] * w1 + ml[1][2][q] * w2 + ml[1][3][q] * w3;
    float inv = 1.0f / l;
    f32x4 o0 = *(const f32x4*)&Ol[0][q][quad * 4];
    f32x4 o1 = *(const f32x4*)&Ol[1][q][quad * 4];
    f32x4 o2 = *(const f32x4*)&Ol[2][q][quad * 4];
    f32x4 o3 = *(const f32x4*)&Ol[3][q][quad * 4];
    float y0 = (o0[0] * w0 + o1[0] * w1 + o2[0] * w2 + o3[0] * w3) * inv;
    float y1 = (o0[1] * w0 + o1[1] * w1 + o2[1] * w2 + o3[1] * w3) * inv;
    float y2 = (o0[2] * w0 + o1[2] * w1 + o2[2] * w2 + o3[2] * w3) * inv;
    float y3 = (o0[3] * w0 + o1[3] * w1 + o2[3] * w2 + o3[3] * w3) * inv;
    u32x2 yv;
    yv.x = cvtpk(y0, y1);
    yv.y = cvtpk(y2, y3);
    *(u32x2*)(Y + ((size_t)(b * Tn + qrow0 + q)) * CCn + h * HDn + quad * 4) = yv;
  }
}

// ---------- GEMM2: Y x WoT + bias -> out (v,b,c,h,w) f32, fused transpose; 2-phase staging ----------
__global__ __launch_bounds__(256, 4) void gemm_out(
    const u16* __restrict__ A, const u16* __restrict__ Bt, const float* __restrict__ bias,
    float* __restrict__ out) {
  const int nt = 8;
  int m0 = (blockIdx.x / nt) * 64;
  int n0 = (blockIdx.x % nt) * 64;
  __shared__ __align__(16) u16 As[2][64 * 64];
  __shared__ __align__(16) u16 Bs[2][64 * 64];
  int tid = threadIdx.x, lane = tid & 63, w = tid >> 6;
  int wr = w & 1, wc = w >> 1;
  int li = lane & 15, g = lane >> 4;
  int rsub = lane >> 3, slot = lane & 7;
  int srcslot = slot ^ rsub;
  f32x4 acc[2][2] = {};

#define OUT_STAGE(buf, kk0)                                                    \
  {                                                                            \
    _Pragma("unroll")                                                          \
    for (int i = 0; i < 2; ++i) {                                              \
      int ci = w * 2 + i;                                                      \
      int row = ci * 8 + rsub;                                                 \
      gload16(A + (size_t)(m0 + row) * Kn + (kk0) + srcslot * 8,               \
              (char*)&As[buf][0] + ci * 1024);                                 \
      gload16(Bt + (size_t)(n0 + row) * Kn + (kk0) + srcslot * 8,              \
              (char*)&Bs[buf][0] + ci * 1024);                                 \
    }                                                                          \
  }

  OUT_STAGE(0, 0);
#pragma unroll
  for (int step = 0; step < 8; ++step) {
    const int cur = step & 1;
    if (step < 7) {
      OUT_STAGE(cur ^ 1, (step + 1) * 64);
      asm volatile("s_waitcnt vmcnt(4)");
    } else {
      asm volatile("s_waitcnt vmcnt(0)");
    }
    __builtin_amdgcn_s_barrier();
#pragma unroll
    for (int kk = 0; kk < 2; ++kk) {
      bf16x8 af[2], bfr[2];
#pragma unroll
      for (int mi = 0; mi < 2; ++mi) {
        int row = wr * 32 + mi * 16 + li;
        int sw = ((kk * 4 + g) ^ (row & 7)) * 8;
        af[mi] = *(const bf16x8*)(&As[cur][0] + row * 64 + sw);
      }
#pragma unroll
      for (int ni = 0; ni < 2; ++ni) {
        int row = wc * 32 + ni * 16 + li;
        int sw = ((kk * 4 + g) ^ (row & 7)) * 8;
        bfr[ni] = *(const bf16x8*)(&Bs[cur][0] + row * 64 + sw);
      }
#pragma unroll
      for (int mi = 0; mi < 2; ++mi)
#pragma unroll
        for (int ni = 0; ni < 2; ++ni)
          acc[mi][ni] = __builtin_amdgcn_mfma_f32_16x16x32_bf16(af[mi], bfr[ni], acc[mi][ni], 0, 0, 0);
    }
    asm volatile("s_waitcnt lgkmcnt(0)");
    __builtin_amdgcn_sched_barrier(0);
    __builtin_amdgcn_s_barrier();
  }
  // epilogue: out[(v*2+b)*512 + n][hw], m = b*2048 + v*256 + hw; m0 64-aligned -> b,v fixed
  int b = m0 >> 11, v = (m0 >> 8) & 7, hw0 = m0 & 255;
  float* ob = out + (size_t)((v * 2 + b) * 512) * 256;
#pragma unroll
  for (int ni = 0; ni < 2; ++ni) {
    int n = n0 + wc * 32 + ni * 16 + li;
    float bn = bias[n];
#pragma unroll
    for (int mi = 0; mi < 2; ++mi) {
      int hw = hw0 + wr * 32 + mi * 16 + g * 4;
      f32x4 y;
#pragma unroll
      for (int r = 0; r < 4; ++r) y[r] = acc[mi][ni][r] + bn;
      *(f32x4*)(ob + (size_t)n * 256 + hw) = y;
    }
  }
}

extern "C" void kernel_launch(void* const* d_in, const int* in_sizes, int n_in,
                              void* d_out, int out_size, void* d_ws, size_t ws_size,
                              hipStream_t stream) {
  (void)in_sizes; (void)n_in; (void)out_size; (void)ws_size;
  const float* x    = (const float*)d_in[0];
  const float* Wqkv = (const float*)d_in[1];
  const float* bqkv = (const float*)d_in[2];
  const float* Wo   = (const float*)d_in[3];
  const float* bo   = (const float*)d_in[4];
  float* out = (float*)d_out;
  char* ws = (char*)d_ws;
  const size_t MB = 1ull << 20;
  u16*   Abf   = (u16*)(ws + 0);          // 4MB; reused as Y (bf16) after attn
  u16*   WqkvT = (u16*)(ws + 4 * MB);     // 1.5MB
  u16*   WoT   = (u16*)(ws + 5 * MB + 512 * 1024);  // 0.5MB
  u16*   Qb    = (u16*)(ws + 6 * MB);     // 4MB
  u16*   Kb    = (u16*)(ws + 10 * MB);    // 4MB (K' tiled)
  u16*   VTb   = (u16*)(ws + 14 * MB);    // 4MB (V' tiled)  -> peak 18MB

  conv_x<<<512, 256, 0, stream>>>(x, Abf);
  convw<<<256, 256, 0, stream>>>(Wqkv, Wo, WqkvT, WoT);
  gemm_qkv<<<64 * 12, 256, 0, stream>>>(Abf, WqkvT, bqkv, Qb, Kb, VTb);
  attn<<<1024, 256, 0, stream>>>(Qb, Kb, VTb, Abf);
  gemm_out<<<64 * 8, 256, 0, stream>>>(Abf, WoT, bo, out);
}

// Round 10
// 57.556 us; speedup vs baseline: 2.4552x; 1.0518x over previous
//
#include <hip/hip_runtime.h>
#include <hip/hip_bf16.h>
#include <stdint.h>

#define VPn 8
#define BBn 2
#define CCn 512
#define NHn 8
#define HDn 64
#define Tn  2048
#define Mn  4096      // BBn*Tn
#define N1n 1536
#define Kn  512
#define QSC 0.180336880111120425f   // 0.125 * log2(e): softmax in exp2 domain

typedef __attribute__((ext_vector_type(8))) short bf16x8;
typedef __attribute__((ext_vector_type(4))) short s16x4;
typedef __attribute__((ext_vector_type(4))) float f32x4;
typedef __attribute__((ext_vector_type(16))) float f32x16;
typedef __attribute__((ext_vector_type(2))) unsigned int u32x2;
typedef unsigned short u16;
typedef unsigned int   u32;

__device__ __forceinline__ u16 f2bf(float f) {
  return __builtin_bit_cast(u16, __float2bfloat16(f));
}
// packed RNE f32x2 -> bf16x2 (same rounding as __float2bfloat16, 1 instr for 2 values)
__device__ __forceinline__ u32 cvtpk(float lo, float hi) {
  u32 r;
  asm("v_cvt_pk_bf16_f32 %0, %1, %2" : "=v"(r) : "v"(lo), "v"(hi));
  return r;
}
__device__ __forceinline__ void gload16(const void* g, void* l) {
  __builtin_amdgcn_global_load_lds(
      (const __attribute__((address_space(1))) u32*)g,
      (__attribute__((address_space(3))) u32*)l, 16, 0, 0);
}

// ---------- merged prologue: x transpose-convert + both W transposes ----------
__global__ __launch_bounds__(256) void prep(const float* __restrict__ x,
                                            const float* __restrict__ Wqkv,
                                            const float* __restrict__ Wo,
                                            u16* __restrict__ A,
                                            u16* __restrict__ WqkvT,
                                            u16* __restrict__ WoT) {
  int bi = blockIdx.x;   // 0..511 x ; 512..703 Wqkv ; 704..767 Wo
  __shared__ float t[64][65];
  int tid = threadIdx.x, col = tid & 63, r4 = tid >> 6;
  if (bi < 512) {
    int vb = bi >> 5;
    int ct = (bi >> 2) & 7;
    int ht = bi & 3;
    int v = vb >> 1, b = vb & 1;
    const float* src = x + ((size_t)vb * CCn + ct * 64) * 256 + ht * 64;
#pragma unroll
    for (int i = 0; i < 16; ++i) {
      int row = i * 4 + r4;                 // c within tile
      t[row][col] = src[row * 256 + col];   // col = hw within tile
    }
    __syncthreads();
    u16* dst = A + ((size_t)(b * Tn + v * 256 + ht * 64)) * Kn + ct * 64;
#pragma unroll
    for (int i = 0; i < 16; ++i) {
      int row = i * 4 + r4;                 // hw within tile
      dst[row * Kn + col] = f2bf(t[col][row]);
    }
  } else {
    const float* Win; u16* Wt; int Cc, rt, ct;
    if (bi < 704) { int k = bi - 512; Win = Wqkv; Wt = WqkvT; Cc = N1n; rt = k / 24; ct = k % 24; }
    else          { int k = bi - 704; Win = Wo;   Wt = WoT;   Cc = CCn; rt = k / 8;  ct = k % 8;  }
    const float* src = Win + (size_t)(rt * 64) * Cc + ct * 64;
#pragma unroll
    for (int i = 0; i < 16; ++i) {
      int row = i * 4 + r4;
      t[row][col] = src[row * Cc + col];
    }
    __syncthreads();
    u16* dst = Wt + (size_t)(ct * 64) * Kn + rt * 64;
#pragma unroll
    for (int i = 0; i < 16; ++i) {
      int row = i * 4 + r4;
      dst[row * Kn + col] = f2bf(t[col][row]);
    }
  }
}

// K' layout: [bh][kt][c][hi][lq][j]  (u16), flat = bh*131072 + kt*2048 + c*512 + hi*256 + lq*8 + j
// V' layout: [bh][kt][dh][ks][lq][pos] (u16), flat = bh*131072 + kt*2048 + dh*1024 + ks*512 + lq*16 + pos

// ---------- GEMM1: A x WqkvT -> Q (scaled), K', V'; 2-phase double-buffered staging ----------
__global__ __launch_bounds__(256, 3) void gemm_qkv(
    const u16* __restrict__ A, const u16* __restrict__ Bt, const float* __restrict__ bias,
    u16* __restrict__ Qo, u16* __restrict__ Kp, u16* __restrict__ Vp) {
  const int nt = N1n / 128;  // 12
  int m0 = (blockIdx.x / nt) * 64;
  int n0 = (blockIdx.x % nt) * 128;
  __shared__ __align__(16) u16 As[2][64 * 64];
  __shared__ __align__(16) u16 Bs[2][128 * 64];
  int tid = threadIdx.x, lane = tid & 63, w = tid >> 6;
  int wr = w & 1, wc = w >> 1;
  int li = lane & 15, g = lane >> 4;
  int rsub = lane >> 3, slot = lane & 7;
  int srcslot = slot ^ rsub;  // pre-swizzled global source (LDS dest stays linear)
  f32x4 acc[2][4] = {};

#define QKV_STAGE(buf, kk0)                                                    \
  {                                                                            \
    _Pragma("unroll")                                                          \
    for (int i = 0; i < 2; ++i) {                                              \
      int ci = w * 2 + i;                                                      \
      int row = ci * 8 + rsub;                                                 \
      gload16(A + (size_t)(m0 + row) * Kn + (kk0) + srcslot * 8,               \
              (char*)&As[buf][0] + ci * 1024);                                 \
    }                                                                          \
    _Pragma("unroll")                                                          \
    for (int i = 0; i < 4; ++i) {                                              \
      int ci = w * 4 + i;                                                      \
      int row = ci * 8 + rsub;                                                 \
      gload16(Bt + (size_t)(n0 + row) * Kn + (kk0) + srcslot * 8,              \
              (char*)&Bs[buf][0] + ci * 1024);                                 \
    }                                                                          \
  }

  QKV_STAGE(0, 0);
#pragma unroll
  for (int step = 0; step < 8; ++step) {
    const int cur = step & 1;
    if (step < 7) {
      QKV_STAGE(cur ^ 1, (step + 1) * 64);
      asm volatile("s_waitcnt vmcnt(6)");   // 6 newest (next tile) may stay in flight
    } else {
      asm volatile("s_waitcnt vmcnt(0)");
    }
    __builtin_amdgcn_s_barrier();
#pragma unroll
    for (int kk = 0; kk < 2; ++kk) {
      bf16x8 af[2], bfr[4];
#pragma unroll
      for (int mi = 0; mi < 2; ++mi) {
        int row = wr * 32 + mi * 16 + li;
        int sw = ((kk * 4 + g) ^ (row & 7)) * 8;
        af[mi] = *(const bf16x8*)(&As[cur][0] + row * 64 + sw);
      }
#pragma unroll
      for (int ni = 0; ni < 4; ++ni) {
        int row = wc * 64 + ni * 16 + li;
        int sw = ((kk * 4 + g) ^ (row & 7)) * 8;
        bfr[ni] = *(const bf16x8*)(&Bs[cur][0] + row * 64 + sw);
      }
#pragma unroll
      for (int mi = 0; mi < 2; ++mi)
#pragma unroll
        for (int ni = 0; ni < 4; ++ni)
          acc[mi][ni] = __builtin_amdgcn_mfma_f32_16x16x32_bf16(af[mi], bfr[ni], acc[mi][ni], 0, 0, 0);
    }
    asm volatile("s_waitcnt lgkmcnt(0)");
    __builtin_amdgcn_sched_barrier(0);
    __builtin_amdgcn_s_barrier();
  }
#pragma unroll
  for (int ni = 0; ni < 4; ++ni) {
    int n = n0 + wc * 64 + ni * 16 + li;
    float bn = bias[n];
    int sel = n >> 9, c = n & 511, hh = c >> 6, d = c & 63;
    if (sel == 0) {        // Q: [bh][t][d], scaled
#pragma unroll
      for (int mi = 0; mi < 2; ++mi) {
#pragma unroll
        for (int r = 0; r < 4; ++r) {
          int m = m0 + wr * 32 + mi * 16 + g * 4 + r;
          int bq = m >> 11, t = m & 2047;
          Qo[((size_t)((bq * NHn + hh) * Tn + t)) * HDn + d] = f2bf((acc[mi][ni][r] + bn) * QSC);
        }
      }
    } else if (sel == 1) {  // K': tiled fragment layout
      int kc = d >> 4, khi = (d >> 3) & 1, kj = d & 7;
#pragma unroll
      for (int mi = 0; mi < 2; ++mi) {
#pragma unroll
        for (int r = 0; r < 4; ++r) {
          int m = m0 + wr * 32 + mi * 16 + g * 4 + r;
          int bq = m >> 11, t = m & 2047;
          size_t off = (size_t)(bq * NHn + hh) * 131072 + (size_t)(t >> 5) * 2048 +
                       kc * 512 + khi * 256 + (t & 31) * 8 + kj;
          Kp[off] = f2bf(acc[mi][ni][r] + bn);
        }
      }
    } else {                // V': tiled slot layout, 4 consecutive keys pack to 8B
      int dh = d >> 5, lqd = d & 31;
#pragma unroll
      for (int mi = 0; mi < 2; ++mi) {
        int mb = m0 + wr * 32 + mi * 16 + g * 4;
        int bq = mb >> 11, t0 = mb & 2047;
        size_t off = (size_t)(bq * NHn + hh) * 131072 + (size_t)(t0 >> 5) * 2048 +
                     dh * 1024 + ((t0 >> 4) & 1) * 512 + lqd * 16 +
                     ((t0 >> 2) & 1) * 8 + ((t0 >> 3) & 1) * 4;
        u32x2 ov;
        ov.x = cvtpk(acc[mi][ni][0] + bn, acc[mi][ni][1] + bn);
        ov.y = cvtpk(acc[mi][ni][2] + bn, acc[mi][ni][3] + bn);
        *(u32x2*)(Vp + off) = ov;
      }
    }
  }
}

// ---------- flash attention, block-causal, 32x32 swapped MFMA, 2-stage in-wave pipeline ----------
// 4 waves/block = 4 key-split segments of one 32-query tile; LDS combine.
// XCD-pinned: bh = (idx&7) | ((idx>>3)&1)<<3 keeps 2 bh per XCD (1MB K+V in local L2).
// Pipeline: per iter t: issue loads(K(t+1),V(t)) -> S(t) MFMAs -> PV(t-1) MFMAs -> softmax(t).
// PV(t-1) is independent of S(t): 8 MFMAs stream; softmax VALU overlaps the MFMA pipe.
__global__ __launch_bounds__(256, 3) void attn(
    const u16* __restrict__ Q, const u16* __restrict__ Kp, const u16* __restrict__ Vp,
    u16* __restrict__ Y) {
  int idx = blockIdx.x;            // 1024
  int bh = (idx & 7) | (((idx >> 3) & 1) << 3);
  int qt = 63 - (idx >> 4);        // heavy first
  int b = bh >> 3, h = bh & 7;
  int qrow0 = qt << 5;
  int nkeys = ((qt >> 3) + 1) << 8;
  int qtr = nkeys >> 2;            // per-wave key range, multiple of 64
  int tid = threadIdx.x;
  int w = tid >> 6;                // segment
  int ktb = (w * qtr) >> 5;        // first 32-key tile of this segment
  int ntile = qtr >> 5;            // >= 2
  int lane = tid & 63;
  int lq = lane & 31;              // query col / K row / V d-row within tile
  int hi = lane >> 5;              // half select

  const u16* Qb = Q + ((size_t)(bh * Tn + qrow0)) * HDn;
  const u16* Kb = Kp + (size_t)bh * 131072;
  const u16* Vb = Vp + (size_t)bh * 131072;
  int kof = hi * 256 + lq * 8;     // K lane offset (u16)
  int vof = lq * 16 + hi * 8;      // V lane offset (u16)

  // Q^T B-frags: chunk c holds B[d=c*16+hi*8+j][q=lq]
  bf16x8 qf[4];
  {
    const u16* qp = Qb + (size_t)lq * HDn + hi * 8;
#pragma unroll
    for (int c = 0; c < 4; ++c) qf[c] = *(const bf16x8*)(qp + c * 16);
  }

  float mrun = -1e30f, lrun = 0.f;   // per-lane partials
  f32x16 oacc0 = {}, oacc1 = {};     // O^T d=0-31 / 32-63, col q=lq
  bf16x8 kc[4], knf[4], vc[4], vn[4];
  bf16x8 pfA, pfB;

#define KLD(dst, kt)                                                           \
  _Pragma("unroll")                                                            \
  for (int c = 0; c < 4; ++c)                                                  \
    dst[c] = *(const bf16x8*)(Kb + (size_t)(kt) * 2048 + c * 512 + kof);
#define VLD(dst, kt)                                                           \
  {                                                                            \
    const u16* vt_ = Vb + (size_t)(kt) * 2048 + vof;                           \
    _Pragma("unroll")                                                          \
    for (int c = 0; c < 4; ++c) dst[c] = *(const bf16x8*)(vt_ + c * 512);      \
  }
#define SQK()                                                                  \
  __builtin_amdgcn_s_setprio(1);                                               \
  _Pragma("unroll")                                                            \
  for (int c = 0; c < 4; ++c)                                                  \
    s = __builtin_amdgcn_mfma_f32_32x32x16_bf16(kc[c], qf[c], s, 0, 0, 0);     \
  __builtin_amdgcn_s_setprio(0);
#define PVB()                                                                  \
  __builtin_amdgcn_s_setprio(1);                                               \
  oacc0 = __builtin_amdgcn_mfma_f32_32x32x16_bf16(vc[0], pfA, oacc0, 0, 0, 0); \
  oacc0 = __builtin_amdgcn_mfma_f32_32x32x16_bf16(vc[1], pfB, oacc0, 0, 0, 0); \
  oacc1 = __builtin_amdgcn_mfma_f32_32x32x16_bf16(vc[2], pfA, oacc1, 0, 0, 0); \
  oacc1 = __builtin_amdgcn_mfma_f32_32x32x16_bf16(vc[3], pfB, oacc1, 0, 0, 0); \
  __builtin_amdgcn_s_setprio(0);
#define SMB()                                                                  \
  {                                                                            \
    float m0_ = fmaxf(fmaxf(fmaxf(fmaxf(s[0], s[1]), fmaxf(s[2], s[3])),       \
                            fmaxf(fmaxf(s[4], s[5]), fmaxf(s[6], s[7]))),      \
                      fmaxf(fmaxf(fmaxf(s[8], s[9]), fmaxf(s[10], s[11])),     \
                            fmaxf(fmaxf(s[12], s[13]), fmaxf(s[14], s[15])))); \
    float mall_ = fmaxf(m0_, __shfl_xor(m0_, 32));                             \
    if (!__all(mall_ <= mrun + 8.0f)) {                                        \
      float mnew_ = fmaxf(mrun, mall_);                                        \
      float fc_ = exp2f(mrun - mnew_);                                         \
      mrun = mnew_; lrun *= fc_;                                               \
      _Pragma("unroll")                                                        \
      for (int j = 0; j < 16; ++j) { oacc0[j] *= fc_; oacc1[j] *= fc_; }       \
    }                                                                          \
    float p[16];                                                               \
    _Pragma("unroll")                                                          \
    for (int j = 0; j < 16; ++j) p[j] = exp2f(s[j] - mrun);                    \
    lrun += (((p[0] + p[1]) + (p[2] + p[3])) + ((p[4] + p[5]) + (p[6] + p[7]))) + \
            (((p[8] + p[9]) + (p[10] + p[11])) + ((p[12] + p[13]) + (p[14] + p[15]))); \
    __attribute__((ext_vector_type(4))) int pa_ = {                            \
        (int)cvtpk(p[0], p[1]), (int)cvtpk(p[2], p[3]),                        \
        (int)cvtpk(p[4], p[5]), (int)cvtpk(p[6], p[7])};                       \
    __attribute__((ext_vector_type(4))) int pb_ = {                            \
        (int)cvtpk(p[8], p[9]), (int)cvtpk(p[10], p[11]),                      \
        (int)cvtpk(p[12], p[13]), (int)cvtpk(p[14], p[15])};                   \
    pfA = __builtin_bit_cast(bf16x8, pa_);                                     \
    pfB = __builtin_bit_cast(bf16x8, pb_);                                     \
  }

  // ---- peel t = 0 ----
  KLD(kc, ktb);
  VLD(vc, ktb);
  KLD(knf, ktb + 1);               // ntile >= 2 always
  {
    f32x16 s = {};
    SQK();
    SMB();
  }
#pragma unroll
  for (int c = 0; c < 4; ++c) kc[c] = knf[c];

  // ---- main loop t = 1 .. ntile-1 ----
  for (int t = 1; t < ntile; ++t) {
    int ktn = ktb + ((t + 1 < ntile) ? t + 1 : t);
    KLD(knf, ktn);                 // K(t+1)
    VLD(vn, ktb + t);              // V(t), used by PV(t) next iter
    f32x16 s = {};
    SQK();                         // S(t) with kc = K(t)
    PVB();                         // PV(t-1) with vc = V(t-1), pf = P(t-1)
    SMB();                         // softmax(t) -> pf; rescale lands after PV(t-1)
#pragma unroll
    for (int c = 0; c < 4; ++c) { kc[c] = knf[c]; vc[c] = vn[c]; }
  }
  // ---- epilogue: PV(ntile-1) ----
  PVB();

  // total l per query column (cross-half)
  lrun += __shfl_xor(lrun, 32);

  // partials -> LDS
  __shared__ float Ol[4][32][68];
  __shared__ float ml[2][4][32];
  {
    float* op = &Ol[w][lq][hi * 4];
#pragma unroll
    for (int a = 0; a < 4; ++a) {
      f32x4 v0 = {oacc0[4 * a], oacc0[4 * a + 1], oacc0[4 * a + 2], oacc0[4 * a + 3]};
      f32x4 v1 = {oacc1[4 * a], oacc1[4 * a + 1], oacc1[4 * a + 2], oacc1[4 * a + 3]};
      *(f32x4*)(op + a * 8) = v0;
      *(f32x4*)(op + 32 + a * 8) = v1;
    }
    if (lane < 32) { ml[0][w][lq] = mrun; ml[1][w][lq] = lrun; }
  }
  __syncthreads();

  // in-block combine of the 4 segments; write Y bf16 [b][t][c]
#pragma unroll
  for (int task = tid; task < 512; task += 256) {
    int q = task >> 4, quad = task & 15;
    float m0v = ml[0][0][q], m1v = ml[0][1][q], m2v = ml[0][2][q], m3v = ml[0][3][q];
    float mx = fmaxf(fmaxf(m0v, m1v), fmaxf(m2v, m3v));
    float w0 = exp2f(m0v - mx), w1 = exp2f(m1v - mx);
    float w2 = exp2f(m2v - mx), w3 = exp2f(m3v - mx);
    float l = ml[1][0][q] * w0 + ml[1][1][q] * w1 + ml[1][2][q] * w2 + ml[1][3][q] * w3;
    float inv = 1.0f / l;
    f32x4 o0 = *(const f32x4*)&Ol[0][q][quad * 4];
    f32x4 o1 = *(const f32x4*)&Ol[1][q][quad * 4];
    f32x4 o2 = *(const f32x4*)&Ol[2][q][quad * 4];
    f32x4 o3 = *(const f32x4*)&Ol[3][q][quad * 4];
    float y0 = (o0[0] * w0 + o1[0] * w1 + o2[0] * w2 + o3[0] * w3) * inv;
    float y1 = (o0[1] * w0 + o1[1] * w1 + o2[1] * w2 + o3[1] * w3) * inv;
    float y2 = (o0[2] * w0 + o1[2] * w1 + o2[2] * w2 + o3[2] * w3) * inv;
    float y3 = (o0[3] * w0 + o1[3] * w1 + o2[3] * w2 + o3[3] * w3) * inv;
    u32x2 yv;
    yv.x = cvtpk(y0, y1);
    yv.y = cvtpk(y2, y3);
    *(u32x2*)(Y + ((size_t)(b * Tn + qrow0 + q)) * CCn + h * HDn + quad * 4) = yv;
  }
}

// ---------- GEMM2: Y x WoT + bias -> out (v,b,c,h,w) f32, fused transpose; 2-phase staging ----------
__global__ __launch_bounds__(256, 4) void gemm_out(
    const u16* __restrict__ A, const u16* __restrict__ Bt, const float* __restrict__ bias,
    float* __restrict__ out) {
  const int nt = 8;
  int m0 = (blockIdx.x / nt) * 64;
  int n0 = (blockIdx.x % nt) * 64;
  __shared__ __align__(16) u16 As[2][64 * 64];
  __shared__ __align__(16) u16 Bs[2][64 * 64];
  int tid = threadIdx.x, lane = tid & 63, w = tid >> 6;
  int wr = w & 1, wc = w >> 1;
  int li = lane & 15, g = lane >> 4;
  int rsub = lane >> 3, slot = lane & 7;
  int srcslot = slot ^ rsub;
  f32x4 acc[2][2] = {};

#define OUT_STAGE(buf, kk0)                                                    \
  {                                                                            \
    _Pragma("unroll")                                                          \
    for (int i = 0; i < 2; ++i) {                                              \
      int ci = w * 2 + i;                                                      \
      int row = ci * 8 + rsub;                                                 \
      gload16(A + (size_t)(m0 + row) * Kn + (kk0) + srcslot * 8,               \
              (char*)&As[buf][0] + ci * 1024);                                 \
      gload16(Bt + (size_t)(n0 + row) * Kn + (kk0) + srcslot * 8,              \
              (char*)&Bs[buf][0] + ci * 1024);                                 \
    }                                                                          \
  }

  OUT_STAGE(0, 0);
#pragma unroll
  for (int step = 0; step < 8; ++step) {
    const int cur = step & 1;
    if (step < 7) {
      OUT_STAGE(cur ^ 1, (step + 1) * 64);
      asm volatile("s_waitcnt vmcnt(4)");
    } else {
      asm volatile("s_waitcnt vmcnt(0)");
    }
    __builtin_amdgcn_s_barrier();
#pragma unroll
    for (int kk = 0; kk < 2; ++kk) {
      bf16x8 af[2], bfr[2];
#pragma unroll
      for (int mi = 0; mi < 2; ++mi) {
        int row = wr * 32 + mi * 16 + li;
        int sw = ((kk * 4 + g) ^ (row & 7)) * 8;
        af[mi] = *(const bf16x8*)(&As[cur][0] + row * 64 + sw);
      }
#pragma unroll
      for (int ni = 0; ni < 2; ++ni) {
        int row = wc * 32 + ni * 16 + li;
        int sw = ((kk * 4 + g) ^ (row & 7)) * 8;
        bfr[ni] = *(const bf16x8*)(&Bs[cur][0] + row * 64 + sw);
      }
#pragma unroll
      for (int mi = 0; mi < 2; ++mi)
#pragma unroll
        for (int ni = 0; ni < 2; ++ni)
          acc[mi][ni] = __builtin_amdgcn_mfma_f32_16x16x32_bf16(af[mi], bfr[ni], acc[mi][ni], 0, 0, 0);
    }
    asm volatile("s_waitcnt lgkmcnt(0)");
    __builtin_amdgcn_sched_barrier(0);
    __builtin_amdgcn_s_barrier();
  }
  // epilogue: out[(v*2+b)*512 + n][hw], m = b*2048 + v*256 + hw; m0 64-aligned -> b,v fixed
  int b = m0 >> 11, v = (m0 >> 8) & 7, hw0 = m0 & 255;
  float* ob = out + (size_t)((v * 2 + b) * 512) * 256;
#pragma unroll
  for (int ni = 0; ni < 2; ++ni) {
    int n = n0 + wc * 32 + ni * 16 + li;
    float bn = bias[n];
#pragma unroll
    for (int mi = 0; mi < 2; ++mi) {
      int hw = hw0 + wr * 32 + mi * 16 + g * 4;
      f32x4 y;
#pragma unroll
      for (int r = 0; r < 4; ++r) y[r] = acc[mi][ni][r] + bn;
      *(f32x4*)(ob + (size_t)n * 256 + hw) = y;
    }
  }
}

extern "C" void kernel_launch(void* const* d_in, const int* in_sizes, int n_in,
                              void* d_out, int out_size, void* d_ws, size_t ws_size,
                              hipStream_t stream) {
  (void)in_sizes; (void)n_in; (void)out_size; (void)ws_size;
  const float* x    = (const float*)d_in[0];
  const float* Wqkv = (const float*)d_in[1];
  const float* bqkv = (const float*)d_in[2];
  const float* Wo   = (const float*)d_in[3];
  const float* bo   = (const float*)d_in[4];
  float* out = (float*)d_out;
  char* ws = (char*)d_ws;
  const size_t MB = 1ull << 20;
  u16*   Abf   = (u16*)(ws + 0);          // 4MB; reused as Y (bf16) after attn
  u16*   WqkvT = (u16*)(ws + 4 * MB);     // 1.5MB
  u16*   WoT   = (u16*)(ws + 5 * MB + 512 * 1024);  // 0.5MB
  u16*   Qb    = (u16*)(ws + 6 * MB);     // 4MB
  u16*   Kb    = (u16*)(ws + 10 * MB);    // 4MB (K' tiled)
  u16*   VTb   = (u16*)(ws + 14 * MB);    // 4MB (V' tiled)  -> peak 18MB

  prep<<<768, 256, 0, stream>>>(x, Wqkv, Wo, Abf, WqkvT, WoT);
  gemm_qkv<<<64 * 12, 256, 0, stream>>>(Abf, WqkvT, bqkv, Qb, Kb, VTb);
  attn<<<1024, 256, 0, stream>>>(Qb, Kb, VTb, Abf);
  gemm_out<<<64 * 8, 256, 0, stream>>>(Abf, WoT, bo, out);
}